// Round 1
// baseline (2552.496 us; speedup 1.0000x reference)
//
#include <hip/hip_runtime.h>
#include <hip/hip_bf16.h>
#include <cstdint>
#include <cstddef>

#define LL 4096
#define BB 4
#define DD 1024
#define HH 16
#define PP 256
#define HDD 64

constexpr float kScaling = 0.125f;   // HD^-0.5
constexpr float kEps = 1e-5f;

#define LC 4
#define LCHUNK (LL / LC)             // 1024

// ---------------------------------------------------------------------------
// Compress: for each (b,h): pkv = relu(s * E_h @ kvh), kv += pkv @ kvh^T
// grid (B*H=64, LC), block 256 (thread t <-> p=t). Partial kv per L-chunk.
// ---------------------------------------------------------------------------
__global__ __launch_bounds__(256, 2) void k_compress(
    const float* __restrict__ query, const float* __restrict__ ew,
    float* __restrict__ parts) {
  const int bh = blockIdx.x;
  const int lc = blockIdx.y;
  const int b = bh / HH, h = bh % HH;
  const int tid = threadIdx.x;

  __shared__ float tile[HDD][68];    // [d][l], pad 68 -> (4d+l)%32 banks, 16B-aligned rows

  float Erow[HDD];
  const float* ep = ew + (size_t)(h * PP + tid) * HDD;
#pragma unroll
  for (int d = 0; d < HDD; d += 4) {
    float4 t = *(const float4*)(ep + d);
    Erow[d] = t.x; Erow[d + 1] = t.y; Erow[d + 2] = t.z; Erow[d + 3] = t.w;
  }
  float kvacc[HDD];
#pragma unroll
  for (int d = 0; d < HDD; ++d) kvacc[d] = 0.f;

  const int l0 = lc * LCHUNK;
  for (int lt = 0; lt < LCHUNK; lt += 64) {
    __syncthreads();
#pragma unroll
    for (int j = 0; j < 16; ++j) {
      int i = tid + j * 256;
      int d = i & 63, l = i >> 6;   // consecutive lanes -> consecutive d: coalesced
      tile[d][l] = query[(size_t)(l0 + lt + l) * (BB * DD) + b * DD + h * HDD + d];
    }
    __syncthreads();
    for (int l4 = 0; l4 < 64; l4 += 4) {
      float ax = 0, ay = 0, az = 0, aw = 0;
#pragma unroll
      for (int d = 0; d < HDD; ++d) {
        float4 kv4 = *(const float4*)&tile[d][l4];   // broadcast read
        ax += Erow[d] * kv4.x; ay += Erow[d] * kv4.y;
        az += Erow[d] * kv4.z; aw += Erow[d] * kv4.w;
      }
      float px = fmaxf(ax * kScaling, 0.f);
      float py = fmaxf(ay * kScaling, 0.f);
      float pz = fmaxf(az * kScaling, 0.f);
      float pw = fmaxf(aw * kScaling, 0.f);
#pragma unroll
      for (int d = 0; d < HDD; ++d) {
        float4 kv4 = *(const float4*)&tile[d][l4];
        kvacc[d] += px * kv4.x + py * kv4.y + pz * kv4.z + pw * kv4.w;
      }
    }
  }
  float* op = parts + ((size_t)(lc * 64 + bh) * PP + tid) * HDD;
#pragma unroll
  for (int d = 0; d < HDD; d += 4) {
    float4 t = {kvacc[d], kvacc[d + 1], kvacc[d + 2], kvacc[d + 3]};
    *(float4*)(op + d) = t;
  }
}

// Sum LC partials, store as (P,B,D):  kv_raw[(p*B+b)*D + h*64 + d]
__global__ __launch_bounds__(256) void k_reduce(const float* __restrict__ parts,
                                                float* __restrict__ kv_raw) {
  int i = blockIdx.x * 256 + threadIdx.x;     // over 64*256*64 = 1,048,576
  float s = 0.f;
#pragma unroll
  for (int lc = 0; lc < LC; ++lc) s += parts[(size_t)lc * (64 * PP * HDD) + i];
  int d = i & 63, p = (i >> 6) & 255, bh = i >> 14;
  int b = bh >> 4, h = bh & 15;
  kv_raw[(size_t)(p * BB + b) * DD + h * HDD + d] = s;
}

// ---------------------------------------------------------------------------
// C[M,1024] = A[M,1024] @ W[1024,1024]^T + bias, with epilogue MODE:
//   0: +bias    1: (+bias)*scaling (q-proj)    2: +bias + e_weight residual
// BM=128, BN=64, BK=16; 256 threads; 8x4 per thread.
// ---------------------------------------------------------------------------
template <int MODE>
__global__ __launch_bounds__(256) void k_gemm(
    const float* __restrict__ A, const float* __restrict__ W,
    const float* __restrict__ bias, const float* __restrict__ ew,
    float* __restrict__ C) {
  __shared__ float As[16][132];
  __shared__ float Bs[16][68];
  const int tid = threadIdx.x;
  const int m0 = blockIdx.x * 128;
  const int n0 = blockIdx.y * 64;
  const int tx = tid & 15, ty = tid >> 4;

  float acc[8][4] = {};

  for (int k0 = 0; k0 < DD; k0 += 16) {
    __syncthreads();
#pragma unroll
    for (int j = 0; j < 8; ++j) {
      int i = tid + j * 256;
      int k = i & 15, m = i >> 4;
      As[k][m] = A[(size_t)(m0 + m) * DD + k0 + k];
    }
#pragma unroll
    for (int j = 0; j < 4; ++j) {
      int i = tid + j * 256;
      int k = i & 15, n = i >> 4;
      Bs[k][n] = W[(size_t)(n0 + n) * DD + k0 + k];
    }
    __syncthreads();
#pragma unroll
    for (int k = 0; k < 16; ++k) {
      float4 b4 = *(const float4*)&Bs[k][tx * 4];
      float4 a0 = *(const float4*)&As[k][ty * 8];
      float4 a1 = *(const float4*)&As[k][ty * 8 + 4];
      float av[8] = {a0.x, a0.y, a0.z, a0.w, a1.x, a1.y, a1.z, a1.w};
      float bv[4] = {b4.x, b4.y, b4.z, b4.w};
#pragma unroll
      for (int ii = 0; ii < 8; ++ii)
#pragma unroll
        for (int jj = 0; jj < 4; ++jj) acc[ii][jj] += av[ii] * bv[jj];
    }
  }

#pragma unroll
  for (int ii = 0; ii < 8; ++ii) {
    int m = m0 + ty * 8 + ii;
    int nb = n0 + tx * 4;
    float4 c;
    float* cp = (float*)&c;
#pragma unroll
    for (int jj = 0; jj < 4; ++jj) {
      int n = nb + jj;
      float v = acc[ii][jj] + bias[n];
      if (MODE == 1) v *= kScaling;
      if (MODE == 2) {
        int p = m >> 2, hh = n >> 6, d2 = n & 63;
        v += ew[(size_t)((hh << 8) + p) * HDD + d2];
      }
      cp[jj] = v;
    }
    *(float4*)&C[(size_t)m * DD + nb] = c;
  }
}

// LayerNorm over D=1024; one block (256 thr) per row; 1024 rows.
__global__ __launch_bounds__(256) void k_ln(const float* __restrict__ x,
                                            const float* __restrict__ g,
                                            const float* __restrict__ bb,
                                            float* __restrict__ y) {
  const int r = blockIdx.x;
  const int tid = threadIdx.x;
  const float* xr = x + (size_t)r * DD;
  float4 v = *(const float4*)(xr + tid * 4);
  float s1 = v.x + v.y + v.z + v.w;
  float s2 = v.x * v.x + v.y * v.y + v.z * v.z + v.w * v.w;
#pragma unroll
  for (int off = 32; off > 0; off >>= 1) {
    s1 += __shfl_down(s1, off);
    s2 += __shfl_down(s2, off);
  }
  __shared__ float w1[4], w2[4];
  if ((tid & 63) == 0) { w1[tid >> 6] = s1; w2[tid >> 6] = s2; }
  __syncthreads();
  float S1 = w1[0] + w1[1] + w1[2] + w1[3];
  float S2 = w2[0] + w2[1] + w2[2] + w2[3];
  float mean = S1 * (1.f / DD);
  float var = S2 * (1.f / DD) - mean * mean;
  float rstd = rsqrtf(var + kEps);
  float4 gv = *(const float4*)(g + tid * 4);
  float4 bv = *(const float4*)(bb + tid * 4);
  float4 o;
  o.x = (v.x - mean) * rstd * gv.x + bv.x;
  o.y = (v.y - mean) * rstd * gv.y + bv.y;
  o.z = (v.z - mean) * rstd * gv.z + bv.z;
  o.w = (v.w - mean) * rstd * gv.w + bv.w;
  *(float4*)(y + (size_t)r * DD + tid * 4) = o;
}

// ---------------------------------------------------------------------------
// Attention: per (b,h), thread = one l-row. K/V staged in LDS (two 128-row
// halves). Streaming softmax WITHOUT max-subtraction (logits bounded ~|3|).
// grid (64, 8), block 512.
// ---------------------------------------------------------------------------
__global__ __launch_bounds__(512, 2) void k_attn(
    const float* __restrict__ q, const float* __restrict__ kbuf,
    const float* __restrict__ vbuf, float* __restrict__ attn) {
  const int bh = blockIdx.x;
  const int b = bh / HH, h = bh % HH;
  const int tid = threadIdx.x;
  const int l = blockIdx.y * 512 + tid;

  __shared__ float Kt[128][64];
  __shared__ float Vt[128][64];

  float qr[HDD];
  const float* qp = q + ((size_t)l * BB + b) * DD + h * HDD;
#pragma unroll
  for (int d = 0; d < HDD; d += 4) {
    float4 t = *(const float4*)(qp + d);
    qr[d] = t.x; qr[d + 1] = t.y; qr[d + 2] = t.z; qr[d + 3] = t.w;
  }
  float o[HDD];
#pragma unroll
  for (int d = 0; d < HDD; ++d) o[d] = 0.f;
  float s = 0.f;

  for (int pt = 0; pt < 2; ++pt) {
    __syncthreads();
    for (int i = tid; i < 128 * 64; i += 512) {
      int d = i & 63, p = i >> 6;
      size_t src = ((size_t)(pt * 128 + p) * BB + b) * DD + h * HDD + d;
      Kt[p][d] = kbuf[src];
      Vt[p][d] = vbuf[src];
    }
    __syncthreads();
    for (int p = 0; p < 128; ++p) {
      float x0 = 0, x1 = 0, x2 = 0, x3 = 0;
#pragma unroll
      for (int d = 0; d < HDD; d += 4) {
        float4 kv = *(const float4*)&Kt[p][d];    // broadcast
        x0 += qr[d] * kv.x; x1 += qr[d + 1] * kv.y;
        x2 += qr[d + 2] * kv.z; x3 += qr[d + 3] * kv.w;
      }
      float e = __expf(x0 + x1 + x2 + x3);
      s += e;
#pragma unroll
      for (int d = 0; d < HDD; d += 4) {
        float4 vv = *(const float4*)&Vt[p][d];
        o[d] += e * vv.x; o[d + 1] += e * vv.y;
        o[d + 2] += e * vv.z; o[d + 3] += e * vv.w;
      }
    }
  }
  float inv = 1.f / s;
  float* op = attn + ((size_t)l * BB + b) * DD + h * HDD;
#pragma unroll
  for (int d = 0; d < HDD; d += 4) {
    float4 t = {o[d] * inv, o[d + 1] * inv, o[d + 2] * inv, o[d + 3] * inv};
    *(float4*)(op + d) = t;
  }
}

extern "C" void kernel_launch(void* const* d_in, const int* in_sizes, int n_in,
                              void* d_out, int out_size, void* d_ws, size_t ws_size,
                              hipStream_t stream) {
  const float* query   = (const float*)d_in[0];
  const float* q_w     = (const float*)d_in[1];
  const float* q_b     = (const float*)d_in[2];
  const float* k_w     = (const float*)d_in[3];
  const float* k_b     = (const float*)d_in[4];
  const float* v_w     = (const float*)d_in[5];
  const float* v_b     = (const float*)d_in[6];
  const float* e_weight= (const float*)d_in[7];
  const float* e_out_w = (const float*)d_in[8];
  const float* e_out_b = (const float*)d_in[9];
  const float* ln_g    = (const float*)d_in[10];
  const float* ln_b    = (const float*)d_in[11];
  const float* out_w   = (const float*)d_in[12];
  const float* out_b   = (const float*)d_in[13];
  float* out = (float*)d_out;

  float* ws = (float*)d_ws;
  const size_t NQ = (size_t)LL * BB * DD;    // 16,777,216
  const size_t NKV = (size_t)PP * BB * DD;   // 1,048,576
  float* q_buf    = ws;
  float* attn_buf = q_buf + NQ;
  float* parts    = attn_buf;                // alias: dead before attn is written
  float* kv_raw   = attn_buf + NQ;
  float* kv_eo    = kv_raw + NKV;
  float* kv_ln    = kv_eo + NKV;
  float* k_buf    = kv_ln + NKV;
  float* v_buf    = k_buf + NKV;
  // total ws usage: 2*NQ + 5*NKV floats = ~148 MiB

  k_compress<<<dim3(64, LC), 256, 0, stream>>>(query, e_weight, parts);
  k_reduce<<<4096, 256, 0, stream>>>(parts, kv_raw);
  k_gemm<2><<<dim3(8, 16), 256, 0, stream>>>(kv_raw, e_out_w, e_out_b, e_weight, kv_eo);
  k_ln<<<PP * BB, 256, 0, stream>>>(kv_eo, ln_g, ln_b, kv_ln);
  k_gemm<1><<<dim3(128, 16), 256, 0, stream>>>(query, q_w, q_b, nullptr, q_buf);
  k_gemm<0><<<dim3(8, 16), 256, 0, stream>>>(kv_ln, k_w, k_b, nullptr, k_buf);
  k_gemm<0><<<dim3(8, 16), 256, 0, stream>>>(kv_ln, v_w, v_b, nullptr, v_buf);
  k_attn<<<dim3(64, 8), 512, 0, stream>>>(q_buf, k_buf, v_buf, attn_buf);
  k_gemm<0><<<dim3(128, 16), 256, 0, stream>>>(attn_buf, out_w, out_b, nullptr, out);
}

// Round 2
// 2077.752 us; speedup vs baseline: 1.2285x; 1.2285x over previous
//
#include <hip/hip_runtime.h>
#include <hip/hip_bf16.h>
#include <cstdint>
#include <cstddef>

#define LL 4096
#define BB 4
#define DD 1024
#define HH 16
#define PP 256
#define HDD 64

constexpr float kScaling = 0.125f;   // HD^-0.5
constexpr float kEps = 1e-5f;

#define LC 16
#define LCHUNK (LL / LC)             // 256

// ---------------------------------------------------------------------------
// Compress: for each (b,h): pkv = relu(s * E_h @ kvh), kv += pkv @ kvh^T
// grid (B*H=64, LC=16) = 1024 blocks -> 4 blocks/CU, block 256 (thread t <-> p=t).
// Partial kv per L-chunk; reduced in k_reduce.
// ---------------------------------------------------------------------------
__global__ __launch_bounds__(256, 2) void k_compress(
    const float* __restrict__ query, const float* __restrict__ ew,
    float* __restrict__ parts) {
  const int bh = blockIdx.x;
  const int lc = blockIdx.y;
  const int b = bh / HH, h = bh % HH;
  const int tid = threadIdx.x;

  __shared__ float tile[HDD][68];    // [d][l], pad 68: 16B-aligned rows

  float Erow[HDD];
  const float* ep = ew + (size_t)(h * PP + tid) * HDD;
#pragma unroll
  for (int d = 0; d < HDD; d += 4) {
    float4 t = *(const float4*)(ep + d);
    Erow[d] = t.x; Erow[d + 1] = t.y; Erow[d + 2] = t.z; Erow[d + 3] = t.w;
  }
  float kvacc[HDD];
#pragma unroll
  for (int d = 0; d < HDD; ++d) kvacc[d] = 0.f;

  const int l0 = lc * LCHUNK;
  for (int lt = 0; lt < LCHUNK; lt += 64) {
    __syncthreads();
#pragma unroll
    for (int j = 0; j < 16; ++j) {
      int i = tid + j * 256;
      int d = i & 63, l = i >> 6;   // consecutive lanes -> consecutive d: coalesced
      tile[d][l] = query[(size_t)(l0 + lt + l) * (BB * DD) + b * DD + h * HDD + d];
    }
    __syncthreads();
    for (int l4 = 0; l4 < 64; l4 += 4) {
      float ax = 0, ay = 0, az = 0, aw = 0;
#pragma unroll
      for (int d = 0; d < HDD; ++d) {
        float4 kv4 = *(const float4*)&tile[d][l4];   // broadcast read
        ax += Erow[d] * kv4.x; ay += Erow[d] * kv4.y;
        az += Erow[d] * kv4.z; aw += Erow[d] * kv4.w;
      }
      float px = fmaxf(ax * kScaling, 0.f);
      float py = fmaxf(ay * kScaling, 0.f);
      float pz = fmaxf(az * kScaling, 0.f);
      float pw = fmaxf(aw * kScaling, 0.f);
#pragma unroll
      for (int d = 0; d < HDD; ++d) {
        float4 kv4 = *(const float4*)&tile[d][l4];
        kvacc[d] += px * kv4.x + py * kv4.y + pz * kv4.z + pw * kv4.w;
      }
    }
  }
  float* op = parts + ((size_t)(lc * 64 + bh) * PP + tid) * HDD;
#pragma unroll
  for (int d = 0; d < HDD; d += 4) {
    float4 t = {kvacc[d], kvacc[d + 1], kvacc[d + 2], kvacc[d + 3]};
    *(float4*)(op + d) = t;
  }
}

// Sum LC partials, store as (P,B,D):  kv_raw[(p*B+b)*D + h*64 + d]
__global__ __launch_bounds__(256) void k_reduce(const float* __restrict__ parts,
                                                float* __restrict__ kv_raw) {
  int i = blockIdx.x * 256 + threadIdx.x;     // over 64*256*64 = 1,048,576
  float s = 0.f;
#pragma unroll
  for (int lc = 0; lc < LC; ++lc) s += parts[(size_t)lc * (64 * PP * HDD) + i];
  int d = i & 63, p = (i >> 6) & 255, bh = i >> 14;
  int b = bh >> 4, h = bh & 15;
  kv_raw[(size_t)(p * BB + b) * DD + h * HDD + d] = s;
}

// ---------------------------------------------------------------------------
// C[M,1024] = A[M,1024] @ W[1024,1024]^T + bias, with epilogue MODE:
//   0: +bias    1: (+bias)*scaling (q-proj)    2: +bias + e_weight residual
// BM=128, BN=64, BK=16; 256 threads; 8x4 per thread.
// ---------------------------------------------------------------------------
template <int MODE>
__global__ __launch_bounds__(256) void k_gemm(
    const float* __restrict__ A, const float* __restrict__ W,
    const float* __restrict__ bias, const float* __restrict__ ew,
    float* __restrict__ C) {
  __shared__ float As[16][132];
  __shared__ float Bs[16][68];
  const int tid = threadIdx.x;
  const int m0 = blockIdx.x * 128;
  const int n0 = blockIdx.y * 64;
  const int tx = tid & 15, ty = tid >> 4;

  float acc[8][4] = {};

  for (int k0 = 0; k0 < DD; k0 += 16) {
    __syncthreads();
#pragma unroll
    for (int j = 0; j < 8; ++j) {
      int i = tid + j * 256;
      int k = i & 15, m = i >> 4;
      As[k][m] = A[(size_t)(m0 + m) * DD + k0 + k];
    }
#pragma unroll
    for (int j = 0; j < 4; ++j) {
      int i = tid + j * 256;
      int k = i & 15, n = i >> 4;
      Bs[k][n] = W[(size_t)(n0 + n) * DD + k0 + k];
    }
    __syncthreads();
#pragma unroll
    for (int k = 0; k < 16; ++k) {
      float4 b4 = *(const float4*)&Bs[k][tx * 4];
      float4 a0 = *(const float4*)&As[k][ty * 8];
      float4 a1 = *(const float4*)&As[k][ty * 8 + 4];
      float av[8] = {a0.x, a0.y, a0.z, a0.w, a1.x, a1.y, a1.z, a1.w};
      float bv[4] = {b4.x, b4.y, b4.z, b4.w};
#pragma unroll
      for (int ii = 0; ii < 8; ++ii)
#pragma unroll
        for (int jj = 0; jj < 4; ++jj) acc[ii][jj] += av[ii] * bv[jj];
    }
  }

#pragma unroll
  for (int ii = 0; ii < 8; ++ii) {
    int m = m0 + ty * 8 + ii;
    int nb = n0 + tx * 4;
    float4 c;
    float* cp = (float*)&c;
#pragma unroll
    for (int jj = 0; jj < 4; ++jj) {
      int n = nb + jj;
      float v = acc[ii][jj] + bias[n];
      if (MODE == 1) v *= kScaling;
      if (MODE == 2) {
        int p = m >> 2, hh = n >> 6, d2 = n & 63;
        v += ew[(size_t)((hh << 8) + p) * HDD + d2];
      }
      cp[jj] = v;
    }
    *(float4*)&C[(size_t)m * DD + nb] = c;
  }
}

// LayerNorm over D=1024; one block (256 thr) per row; 1024 rows.
__global__ __launch_bounds__(256) void k_ln(const float* __restrict__ x,
                                            const float* __restrict__ g,
                                            const float* __restrict__ bb,
                                            float* __restrict__ y) {
  const int r = blockIdx.x;
  const int tid = threadIdx.x;
  const float* xr = x + (size_t)r * DD;
  float4 v = *(const float4*)(xr + tid * 4);
  float s1 = v.x + v.y + v.z + v.w;
  float s2 = v.x * v.x + v.y * v.y + v.z * v.z + v.w * v.w;
#pragma unroll
  for (int off = 32; off > 0; off >>= 1) {
    s1 += __shfl_down(s1, off);
    s2 += __shfl_down(s2, off);
  }
  __shared__ float w1[4], w2[4];
  if ((tid & 63) == 0) { w1[tid >> 6] = s1; w2[tid >> 6] = s2; }
  __syncthreads();
  float S1 = w1[0] + w1[1] + w1[2] + w1[3];
  float S2 = w2[0] + w2[1] + w2[2] + w2[3];
  float mean = S1 * (1.f / DD);
  float var = S2 * (1.f / DD) - mean * mean;
  float rstd = rsqrtf(var + kEps);
  float4 gv = *(const float4*)(g + tid * 4);
  float4 bv = *(const float4*)(bb + tid * 4);
  float4 o;
  o.x = (v.x - mean) * rstd * gv.x + bv.x;
  o.y = (v.y - mean) * rstd * gv.y + bv.y;
  o.z = (v.z - mean) * rstd * gv.z + bv.z;
  o.w = (v.w - mean) * rstd * gv.w + bv.w;
  *(float4*)(y + (size_t)r * DD + tid * 4) = o;
}

// ---------------------------------------------------------------------------
// Attention: per (b,h), thread = one l-row. K/V staged in LDS (two 128-row
// halves). Streaming softmax WITHOUT max-subtraction (logits bounded ~|3|).
// grid (64, 8), block 512.
// ---------------------------------------------------------------------------
__global__ __launch_bounds__(512, 2) void k_attn(
    const float* __restrict__ q, const float* __restrict__ kbuf,
    const float* __restrict__ vbuf, float* __restrict__ attn) {
  const int bh = blockIdx.x;
  const int b = bh / HH, h = bh % HH;
  const int tid = threadIdx.x;
  const int l = blockIdx.y * 512 + tid;

  __shared__ float Kt[128][64];
  __shared__ float Vt[128][64];

  float qr[HDD];
  const float* qp = q + ((size_t)l * BB + b) * DD + h * HDD;
#pragma unroll
  for (int d = 0; d < HDD; d += 4) {
    float4 t = *(const float4*)(qp + d);
    qr[d] = t.x; qr[d + 1] = t.y; qr[d + 2] = t.z; qr[d + 3] = t.w;
  }
  float o[HDD];
#pragma unroll
  for (int d = 0; d < HDD; ++d) o[d] = 0.f;
  float s = 0.f;

  for (int pt = 0; pt < 2; ++pt) {
    __syncthreads();
    for (int i = tid; i < 128 * 64; i += 512) {
      int d = i & 63, p = i >> 6;
      size_t src = ((size_t)(pt * 128 + p) * BB + b) * DD + h * HDD + d;
      Kt[p][d] = kbuf[src];
      Vt[p][d] = vbuf[src];
    }
    __syncthreads();
    for (int p = 0; p < 128; ++p) {
      float x0 = 0, x1 = 0, x2 = 0, x3 = 0;
#pragma unroll
      for (int d = 0; d < HDD; d += 4) {
        float4 kv = *(const float4*)&Kt[p][d];    // broadcast
        x0 += qr[d] * kv.x; x1 += qr[d + 1] * kv.y;
        x2 += qr[d + 2] * kv.z; x3 += qr[d + 3] * kv.w;
      }
      float e = __expf(x0 + x1 + x2 + x3);
      s += e;
#pragma unroll
      for (int d = 0; d < HDD; d += 4) {
        float4 vv = *(const float4*)&Vt[p][d];
        o[d] += e * vv.x; o[d + 1] += e * vv.y;
        o[d + 2] += e * vv.z; o[d + 3] += e * vv.w;
      }
    }
  }
  float inv = 1.f / s;
  float* op = attn + ((size_t)l * BB + b) * DD + h * HDD;
#pragma unroll
  for (int d = 0; d < HDD; d += 4) {
    float4 t = {o[d] * inv, o[d + 1] * inv, o[d + 2] * inv, o[d + 3] * inv};
    *(float4*)(op + d) = t;
  }
}

extern "C" void kernel_launch(void* const* d_in, const int* in_sizes, int n_in,
                              void* d_out, int out_size, void* d_ws, size_t ws_size,
                              hipStream_t stream) {
  const float* query   = (const float*)d_in[0];
  const float* q_w     = (const float*)d_in[1];
  const float* q_b     = (const float*)d_in[2];
  const float* k_w     = (const float*)d_in[3];
  const float* k_b     = (const float*)d_in[4];
  const float* v_w     = (const float*)d_in[5];
  const float* v_b     = (const float*)d_in[6];
  const float* e_weight= (const float*)d_in[7];
  const float* e_out_w = (const float*)d_in[8];
  const float* e_out_b = (const float*)d_in[9];
  const float* ln_g    = (const float*)d_in[10];
  const float* ln_b    = (const float*)d_in[11];
  const float* out_w   = (const float*)d_in[12];
  const float* out_b   = (const float*)d_in[13];
  float* out = (float*)d_out;

  float* ws = (float*)d_ws;
  const size_t NQ = (size_t)LL * BB * DD;    // 16,777,216
  const size_t NKV = (size_t)PP * BB * DD;   // 1,048,576
  float* q_buf    = ws;
  float* attn_buf = q_buf + NQ;
  // parts: LC*64*256*64 = 16*1,048,576 = NQ floats exactly -> alias q_buf region.
  // parts is dead after k_reduce, which runs before q_buf/attn_buf are written.
  float* parts    = ws;
  float* kv_raw   = attn_buf + NQ;
  float* kv_eo    = kv_raw + NKV;
  float* kv_ln    = kv_eo + NKV;
  float* k_buf    = kv_ln + NKV;
  float* v_buf    = k_buf + NKV;
  // total ws usage: 2*NQ + 5*NKV floats = ~148 MiB (unchanged)

  k_compress<<<dim3(64, LC), 256, 0, stream>>>(query, e_weight, parts);
  k_reduce<<<4096, 256, 0, stream>>>(parts, kv_raw);
  k_gemm<2><<<dim3(8, 16), 256, 0, stream>>>(kv_raw, e_out_w, e_out_b, e_weight, kv_eo);
  k_ln<<<PP * BB, 256, 0, stream>>>(kv_eo, ln_g, ln_b, kv_ln);
  k_gemm<1><<<dim3(128, 16), 256, 0, stream>>>(query, q_w, q_b, nullptr, q_buf);
  k_gemm<0><<<dim3(8, 16), 256, 0, stream>>>(kv_ln, k_w, k_b, nullptr, k_buf);
  k_gemm<0><<<dim3(8, 16), 256, 0, stream>>>(kv_ln, v_w, v_b, nullptr, v_buf);
  k_attn<<<dim3(64, 8), 512, 0, stream>>>(q_buf, k_buf, v_buf, attn_buf);
  k_gemm<0><<<dim3(128, 16), 256, 0, stream>>>(attn_buf, out_w, out_b, nullptr, out);
}

// Round 3
// 538.991 us; speedup vs baseline: 4.7357x; 3.8549x over previous
//
#include <hip/hip_runtime.h>
#include <hip/hip_bf16.h>
#include <cstdint>
#include <cstddef>

#define LL 4096
#define BB 4
#define DD 1024
#define HH 16
#define PP 256
#define HDD 64
#define LC 16
#define LCHUNK 256

constexpr float kScaling = 0.125f;   // HD^-0.5
constexpr float kEps = 1e-5f;

typedef __attribute__((ext_vector_type(8))) short bf16x8;   // 8 bf16 = 4 VGPR
typedef __attribute__((ext_vector_type(4))) short short4v;
typedef __attribute__((ext_vector_type(4))) float f32x4;

#define MFMA16(a, b, c) __builtin_amdgcn_mfma_f32_16x16x32_bf16((a), (b), (c), 0, 0, 0)

__device__ __forceinline__ unsigned short f2bf(float f) {
  unsigned int u = __builtin_bit_cast(unsigned int, f);
  u += 0x7FFFu + ((u >> 16) & 1u);           // round-to-nearest-even
  return (unsigned short)(u >> 16);
}

__device__ __forceinline__ void gll16(const void* g, void* l) {
  __builtin_amdgcn_global_load_lds(
      (const __attribute__((address_space(1))) unsigned int*)g,
      (__attribute__((address_space(3))) unsigned int*)l, 16, 0, 0);
}

// ---------------------------------------------------------------------------
// fp32 -> bf16 bulk convert; each thread does 8 elems.
// ---------------------------------------------------------------------------
__global__ __launch_bounds__(256) void k_cvt(const float* __restrict__ src,
                                             unsigned short* __restrict__ dst,
                                             int n8) {
  int i = blockIdx.x * 256 + threadIdx.x;
  if (i >= n8) return;
  const float4* s = (const float4*)(src + (size_t)i * 8);
  float4 a = s[0], b = s[1];
  bf16x8 o;
  o[0] = f2bf(a.x); o[1] = f2bf(a.y); o[2] = f2bf(a.z); o[3] = f2bf(a.w);
  o[4] = f2bf(b.x); o[5] = f2bf(b.y); o[6] = f2bf(b.z); o[7] = f2bf(b.w);
  *(bf16x8*)(dst + (size_t)i * 8) = o;
}

// ---------------------------------------------------------------------------
// Compress (MFMA): per (b,h,lc): over 4 tiles of LT=64 rows l:
//   GEMM1: S^T[l][p] = X[l][d] @ E[p][d]^T ; relu(scale*S) -> P_lds[p][l] (bf16)
//   GEMM2: kv[p][dd] += P[p][l] @ Xt[dd][l]^T      (fp32 partials to parts)
// LDS: X[64][64]bf16 (8KB) + Xt[64][64] (8KB) + P[256][64] (32KB) = 48KB.
// All three XOR-swizzled: byte slot ^= (row&7).
// ---------------------------------------------------------------------------
__global__ __launch_bounds__(256) void k_compress_mfma(
    const unsigned short* __restrict__ qbf, const unsigned short* __restrict__ ewbf,
    float* __restrict__ parts) {
  const int bh = blockIdx.x, lc = blockIdx.y;
  const int b = bh >> 4, h = bh & 15;
  const int tid = threadIdx.x, wv = tid >> 6, lane = tid & 63;
  const int fr = lane & 15, fg = lane >> 4;

  __shared__ __align__(16) char Xl[8192];    // [l][d] rows of 128B
  __shared__ __align__(16) char Xtl[8192];   // [d][l]
  __shared__ __align__(16) char Pl[32768];   // [p][l] rows of 128B

  // E b-frags (B[n=p][k=d] form): p = wv*64 + pt*16 + fr, d = kc*32 + fg*8
  bf16x8 ef[4][2];
#pragma unroll
  for (int pt = 0; pt < 4; ++pt)
#pragma unroll
    for (int kc = 0; kc < 2; ++kc)
      ef[pt][kc] = *(const bf16x8*)(ewbf +
          (size_t)((h * PP + wv * 64 + pt * 16 + fr) * HDD) + kc * 32 + fg * 8);

  f32x4 acc[4][4];
#pragma unroll
  for (int i = 0; i < 4; ++i)
#pragma unroll
    for (int j = 0; j < 4; ++j) acc[i][j] = (f32x4){0.f, 0.f, 0.f, 0.f};

  const int l0 = lc * LCHUNK;
  for (int t = 0; t < 4; ++t) {
    __syncthreads();
    // stage X and Xt: 512 units of 8 bf16; unit u: l=u>>3, slot c8=u&7
#pragma unroll
    for (int j = 0; j < 2; ++j) {
      int u = tid + j * 256;
      int l = u >> 3, c8 = u & 7;
      bf16x8 val = *(const bf16x8*)(qbf +
          ((size_t)(l0 + t * 64 + l) * BB + b) * DD + h * HDD + c8 * 8);
      *(bf16x8*)(Xl + l * 128 + ((c8 ^ (l & 7)) << 4)) = val;
#pragma unroll
      for (int i = 0; i < 8; ++i) {
        int dd = c8 * 8 + i;
        *(short*)(Xtl + dd * 128 + (((l >> 3) ^ (dd & 7)) << 4) + ((l & 7) << 1)) = val[i];
      }
    }
    __syncthreads();
    // GEMM1 + relu + pack into P_lds (each wave owns p rows wv*64..+63)
#pragma unroll
    for (int lt = 0; lt < 4; ++lt) {
      int rl = lt * 16 + fr;
      bf16x8 xa0 = *(const bf16x8*)(Xl + rl * 128 + (((0 + fg) ^ (rl & 7)) << 4));
      bf16x8 xa1 = *(const bf16x8*)(Xl + rl * 128 + (((4 + fg) ^ (rl & 7)) << 4));
#pragma unroll
      for (int pt = 0; pt < 4; ++pt) {
        f32x4 s = (f32x4){0.f, 0.f, 0.f, 0.f};
        s = MFMA16(xa0, ef[pt][0], s);
        s = MFMA16(xa1, ef[pt][1], s);
        short4v pk;
#pragma unroll
        for (int r = 0; r < 4; ++r)
          pk[r] = (short)f2bf(fmaxf(s[r] * kScaling, 0.f));
        int p = wv * 64 + pt * 16 + fr;
        int lbase = lt * 16 + fg * 4;
        int slot = lbase >> 3;
        *(short4v*)(Pl + p * 128 + ((slot ^ (p & 7)) << 4) + ((lbase & 7) << 1)) = pk;
      }
    }
    asm volatile("s_waitcnt lgkmcnt(0)" ::: "memory");  // P writes visible to own reads
    // GEMM2: acc[pt][dt] += P[p][l] @ Xt[dd][l]^T, K = 64 l's
#pragma unroll
    for (int kc = 0; kc < 2; ++kc) {
      bf16x8 pa[4], xb[4];
#pragma unroll
      for (int pt = 0; pt < 4; ++pt) {
        int p = wv * 64 + pt * 16 + fr;
        pa[pt] = *(const bf16x8*)(Pl + p * 128 + (((kc * 4 + fg) ^ (p & 7)) << 4));
      }
#pragma unroll
      for (int dt = 0; dt < 4; ++dt) {
        int dd = dt * 16 + fr;
        xb[dt] = *(const bf16x8*)(Xtl + dd * 128 + (((kc * 4 + fg) ^ (dd & 7)) << 4));
      }
#pragma unroll
      for (int pt = 0; pt < 4; ++pt)
#pragma unroll
        for (int dt = 0; dt < 4; ++dt)
          acc[pt][dt] = MFMA16(pa[pt], xb[dt], acc[pt][dt]);
    }
  }
  float* op = parts + (size_t)(lc * 64 + bh) * PP * HDD;
#pragma unroll
  for (int pt = 0; pt < 4; ++pt)
#pragma unroll
    for (int dt = 0; dt < 4; ++dt)
#pragma unroll
      for (int r = 0; r < 4; ++r) {
        int p = wv * 64 + pt * 16 + fg * 4 + r;
        int dd = dt * 16 + fr;
        op[(size_t)p * HDD + dd] = acc[pt][dt][r];
      }
}

// Sum LC partials -> kv_raw bf16 as (P,B,D)
__global__ __launch_bounds__(256) void k_reduce(const float* __restrict__ parts,
                                                unsigned short* __restrict__ kv_raw_bf) {
  int i = blockIdx.x * 256 + threadIdx.x;     // over 64*256*64 = 1,048,576
  float s = 0.f;
#pragma unroll
  for (int lcc = 0; lcc < LC; ++lcc) s += parts[(size_t)lcc * (64 * PP * HDD) + i];
  int d = i & 63, p = (i >> 6) & 255, bh = i >> 14;
  int b = bh >> 4, h = bh & 15;
  kv_raw_bf[(size_t)(p * BB + b) * DD + h * HDD + d] = f2bf(s);
}

// ---------------------------------------------------------------------------
// C[M,1024] = A_bf16 @ W_bf16^T + bias (fp32 out). MODE 0:+bias 1:*scale 2:+E res
// 128x128 tile, BK=64, 4 waves x (64x64). global_load_lds w/ pre-swizzled src.
// ---------------------------------------------------------------------------
template <int MODE>
__global__ __launch_bounds__(256) void k_gemm_mfma(
    const unsigned short* __restrict__ A, const unsigned short* __restrict__ W,
    const float* __restrict__ bias, const float* __restrict__ ew,
    float* __restrict__ C) {
  __shared__ __align__(16) char Al[16384];   // [128][64] bf16, 128B rows
  __shared__ __align__(16) char Bl[16384];
  const int tid = threadIdx.x;
  const int wv = tid >> 6, lane = tid & 63;
  const int fr = lane & 15, fg = lane >> 4;
  const int wr = wv >> 1, wc = wv & 1;
  const int m0 = blockIdx.x * 128, n0 = blockIdx.y * 128;

  f32x4 acc[4][4];
#pragma unroll
  for (int i = 0; i < 4; ++i)
#pragma unroll
    for (int j = 0; j < 4; ++j) acc[i][j] = (f32x4){0.f, 0.f, 0.f, 0.f};

  for (int k0 = 0; k0 < DD; k0 += 64) {
    __syncthreads();
#pragma unroll
    for (int j = 0; j < 4; ++j) {
      int u = tid + j * 256;
      int row = u >> 3, slot = u & 7;
      size_t gcol = (size_t)(k0 + 8 * (slot ^ (row & 7)));   // pre-swizzled source
      gll16(A + (size_t)(m0 + row) * DD + gcol, Al + u * 16);
      gll16(W + (size_t)(n0 + row) * DD + gcol, Bl + u * 16);
    }
    __syncthreads();
#pragma unroll
    for (int kc = 0; kc < 2; ++kc) {
      bf16x8 af[4], bfr[4];
#pragma unroll
      for (int mt = 0; mt < 4; ++mt) {
        int r = wr * 64 + mt * 16 + fr;
        af[mt] = *(const bf16x8*)(Al + r * 128 + (((kc * 4 + fg) ^ (r & 7)) << 4));
      }
#pragma unroll
      for (int nt = 0; nt < 4; ++nt) {
        int r = wc * 64 + nt * 16 + fr;
        bfr[nt] = *(const bf16x8*)(Bl + r * 128 + (((kc * 4 + fg) ^ (r & 7)) << 4));
      }
#pragma unroll
      for (int mt = 0; mt < 4; ++mt)
#pragma unroll
        for (int nt = 0; nt < 4; ++nt)
          acc[mt][nt] = MFMA16(af[mt], bfr[nt], acc[mt][nt]);
    }
  }

  float bs[4];
#pragma unroll
  for (int nt = 0; nt < 4; ++nt) bs[nt] = bias[n0 + wc * 64 + nt * 16 + fr];
#pragma unroll
  for (int mt = 0; mt < 4; ++mt)
#pragma unroll
    for (int nt = 0; nt < 4; ++nt) {
      int n = n0 + wc * 64 + nt * 16 + fr;
#pragma unroll
      for (int r = 0; r < 4; ++r) {
        int m = m0 + wr * 64 + mt * 16 + fg * 4 + r;
        float v = acc[mt][nt][r] + bs[nt];
        if (MODE == 1) v *= kScaling;
        if (MODE == 2) {
          int p = m >> 2, hh = n >> 6, d2 = n & 63;
          v += ew[(size_t)((hh << 8) + p) * HDD + d2];
        }
        C[(size_t)m * DD + n] = v;
      }
    }
}

// LayerNorm over D=1024; fp32 in -> bf16 out. One block per row.
__global__ __launch_bounds__(256) void k_ln(const float* __restrict__ x,
                                            const float* __restrict__ g,
                                            const float* __restrict__ bb,
                                            unsigned short* __restrict__ y) {
  const int r = blockIdx.x;
  const int tid = threadIdx.x;
  const float* xr = x + (size_t)r * DD;
  float4 v = *(const float4*)(xr + tid * 4);
  float s1 = v.x + v.y + v.z + v.w;
  float s2 = v.x * v.x + v.y * v.y + v.z * v.z + v.w * v.w;
#pragma unroll
  for (int off = 32; off > 0; off >>= 1) {
    s1 += __shfl_down(s1, off);
    s2 += __shfl_down(s2, off);
  }
  __shared__ float w1[4], w2[4];
  if ((tid & 63) == 0) { w1[tid >> 6] = s1; w2[tid >> 6] = s2; }
  __syncthreads();
  float S1 = w1[0] + w1[1] + w1[2] + w1[3];
  float S2 = w2[0] + w2[1] + w2[2] + w2[3];
  float mean = S1 * (1.f / DD);
  float var = S2 * (1.f / DD) - mean * mean;
  float rstd = rsqrtf(var + kEps);
  float4 gv = *(const float4*)(g + tid * 4);
  float4 bv = *(const float4*)(bb + tid * 4);
  short4v o;
  o[0] = (short)f2bf((v.x - mean) * rstd * gv.x + bv.x);
  o[1] = (short)f2bf((v.y - mean) * rstd * gv.y + bv.y);
  o[2] = (short)f2bf((v.z - mean) * rstd * gv.z + bv.z);
  o[3] = (short)f2bf((v.w - mean) * rstd * gv.w + bv.w);
  *(short4v*)(y + (size_t)r * DD + tid * 4) = o;
}

// ---------------------------------------------------------------------------
// Attention (fp32 compute, bf16 store). grid (64, 8), block 512.
// ---------------------------------------------------------------------------
__global__ __launch_bounds__(512, 2) void k_attn(
    const float* __restrict__ q, const float* __restrict__ kbuf,
    const float* __restrict__ vbuf, unsigned short* __restrict__ attn) {
  const int bh = blockIdx.x;
  const int b = bh / HH, h = bh % HH;
  const int tid = threadIdx.x;
  const int l = blockIdx.y * 512 + tid;

  __shared__ float Kt[128][64];
  __shared__ float Vt[128][64];

  float qr[HDD];
  const float* qp = q + ((size_t)l * BB + b) * DD + h * HDD;
#pragma unroll
  for (int d = 0; d < HDD; d += 4) {
    float4 t = *(const float4*)(qp + d);
    qr[d] = t.x; qr[d + 1] = t.y; qr[d + 2] = t.z; qr[d + 3] = t.w;
  }
  float o[HDD];
#pragma unroll
  for (int d = 0; d < HDD; ++d) o[d] = 0.f;
  float s = 0.f;

  for (int pt = 0; pt < 2; ++pt) {
    __syncthreads();
    for (int i = tid; i < 128 * 64; i += 512) {
      int d = i & 63, p = i >> 6;
      size_t src = ((size_t)(pt * 128 + p) * BB + b) * DD + h * HDD + d;
      Kt[p][d] = kbuf[src];
      Vt[p][d] = vbuf[src];
    }
    __syncthreads();
    for (int p = 0; p < 128; ++p) {
      float x0 = 0, x1 = 0, x2 = 0, x3 = 0;
#pragma unroll
      for (int d = 0; d < HDD; d += 4) {
        float4 kv = *(const float4*)&Kt[p][d];
        x0 += qr[d] * kv.x; x1 += qr[d + 1] * kv.y;
        x2 += qr[d + 2] * kv.z; x3 += qr[d + 3] * kv.w;
      }
      float e = __expf(x0 + x1 + x2 + x3);
      s += e;
#pragma unroll
      for (int d = 0; d < HDD; d += 4) {
        float4 vv = *(const float4*)&Vt[p][d];
        o[d] += e * vv.x; o[d + 1] += e * vv.y;
        o[d + 2] += e * vv.z; o[d + 3] += e * vv.w;
      }
    }
  }
  float inv = 1.f / s;
  unsigned short* op = attn + ((size_t)l * BB + b) * DD + h * HDD;
#pragma unroll
  for (int d = 0; d < HDD; d += 8) {
    bf16x8 t;
#pragma unroll
    for (int i = 0; i < 8; ++i) t[i] = (short)f2bf(o[d + i] * inv);
    *(bf16x8*)(op + d) = t;
  }
}

extern "C" void kernel_launch(void* const* d_in, const int* in_sizes, int n_in,
                              void* d_out, int out_size, void* d_ws, size_t ws_size,
                              hipStream_t stream) {
  const float* query   = (const float*)d_in[0];
  const float* q_w     = (const float*)d_in[1];
  const float* q_b     = (const float*)d_in[2];
  const float* k_w     = (const float*)d_in[3];
  const float* k_b     = (const float*)d_in[4];
  const float* v_w     = (const float*)d_in[5];
  const float* v_b     = (const float*)d_in[6];
  const float* e_weight= (const float*)d_in[7];
  const float* e_out_w = (const float*)d_in[8];
  const float* e_out_b = (const float*)d_in[9];
  const float* ln_g    = (const float*)d_in[10];
  const float* ln_b    = (const float*)d_in[11];
  const float* out_w   = (const float*)d_in[12];
  const float* out_b   = (const float*)d_in[13];
  float* out = (float*)d_out;

  char* w = (char*)d_ws;
  float* q_buf            = (float*)w;                          // 64 MB
  float* parts            = (float*)w;                          // alias (dead early)
  unsigned short* attn_bf = (unsigned short*)(w + (64u << 20)); // 32 MB
  unsigned short* query_bf= (unsigned short*)(w + (96u << 20)); // 32 MB
  unsigned short* kv_raw  = (unsigned short*)(w + (128u << 20));// 2 MB
  float* kv_eo            = (float*)(w + (130u << 20));         // 4 MB
  unsigned short* kv_ln   = (unsigned short*)(w + (134u << 20));// 2 MB
  float* k_buf            = (float*)(w + (136u << 20));         // 4 MB
  float* v_buf            = (float*)(w + (140u << 20));         // 4 MB
  unsigned short* wq  = (unsigned short*)(w + (144u << 20));
  unsigned short* wk  = (unsigned short*)(w + (146u << 20));
  unsigned short* wv_ = (unsigned short*)(w + (148u << 20));
  unsigned short* weo = (unsigned short*)(w + (150u << 20));
  unsigned short* wo  = (unsigned short*)(w + (152u << 20));
  unsigned short* ewb = (unsigned short*)(w + (154u << 20));    // 0.5 MB

  k_cvt<<<8192, 256, 0, stream>>>(query, query_bf, 2097152);
  k_cvt<<<512, 256, 0, stream>>>(q_w, wq, 131072);
  k_cvt<<<512, 256, 0, stream>>>(k_w, wk, 131072);
  k_cvt<<<512, 256, 0, stream>>>(v_w, wv_, 131072);
  k_cvt<<<512, 256, 0, stream>>>(e_out_w, weo, 131072);
  k_cvt<<<512, 256, 0, stream>>>(out_w, wo, 131072);
  k_cvt<<<128, 256, 0, stream>>>(e_weight, ewb, 32768);

  k_compress_mfma<<<dim3(64, LC), 256, 0, stream>>>(query_bf, ewb, parts);
  k_reduce<<<4096, 256, 0, stream>>>(parts, kv_raw);
  k_gemm_mfma<2><<<dim3(8, 8), 256, 0, stream>>>(kv_raw, weo, e_out_b, e_weight, kv_eo);
  k_ln<<<PP * BB, 256, 0, stream>>>(kv_eo, ln_g, ln_b, kv_ln);
  k_gemm_mfma<1><<<dim3(128, 8), 256, 0, stream>>>(query_bf, wq, q_b, nullptr, q_buf);
  k_gemm_mfma<0><<<dim3(8, 8), 256, 0, stream>>>(kv_ln, wk, k_b, nullptr, k_buf);
  k_gemm_mfma<0><<<dim3(8, 8), 256, 0, stream>>>(kv_ln, wv_, v_b, nullptr, v_buf);
  k_attn<<<dim3(64, 8), 512, 0, stream>>>(q_buf, k_buf, v_buf, attn_bf);
  k_gemm_mfma<0><<<dim3(128, 8), 256, 0, stream>>>(attn_bf, wo, out_b, nullptr, out);
}

// Round 5
// 286.694 us; speedup vs baseline: 8.9032x; 1.8800x over previous
//
#include <hip/hip_runtime.h>
#include <hip/hip_bf16.h>
#include <cstdint>
#include <cstddef>

#define LL 4096
#define BB 4
#define DD 1024
#define HH 16
#define PP 256
#define HDD 64
#define LC 16
#define LCHUNK 256

constexpr float kScaling = 0.125f;   // HD^-0.5
constexpr float kEps = 1e-5f;

typedef __attribute__((ext_vector_type(8))) short bf16x8;   // 8 bf16 = 4 VGPR
typedef __attribute__((ext_vector_type(4))) short short4v;
typedef __attribute__((ext_vector_type(4))) float f32x4;

#define MFMA16(a, b, c) __builtin_amdgcn_mfma_f32_16x16x32_bf16((a), (b), (c), 0, 0, 0)

__device__ __forceinline__ unsigned short f2bf(float f) {
  unsigned int u = __builtin_bit_cast(unsigned int, f);
  u += 0x7FFFu + ((u >> 16) & 1u);           // round-to-nearest-even
  return (unsigned short)(u >> 16);
}

__device__ __forceinline__ void gll16(const void* g, void* l) {
  __builtin_amdgcn_global_load_lds(
      (const __attribute__((address_space(1))) unsigned int*)g,
      (__attribute__((address_space(3))) unsigned int*)l, 16, 0, 0);
}

// ---------------------------------------------------------------------------
// fp32 -> bf16 bulk convert; each thread does 8 elems.
// ---------------------------------------------------------------------------
__global__ __launch_bounds__(256) void k_cvt(const float* __restrict__ src,
                                             unsigned short* __restrict__ dst,
                                             int n8) {
  int i = blockIdx.x * 256 + threadIdx.x;
  if (i >= n8) return;
  const float4* s = (const float4*)(src + (size_t)i * 8);
  float4 a = s[0], b = s[1];
  bf16x8 o;
  o[0] = f2bf(a.x); o[1] = f2bf(a.y); o[2] = f2bf(a.z); o[3] = f2bf(a.w);
  o[4] = f2bf(b.x); o[5] = f2bf(b.y); o[6] = f2bf(b.z); o[7] = f2bf(b.w);
  *(bf16x8*)(dst + (size_t)i * 8) = o;
}

// ---------------------------------------------------------------------------
// Compress (MFMA): per (b,h,lc): over 4 tiles of LT=64 rows l:
//   GEMM1: S^T[l][p] = X[l][d] @ E[p][d]^T ; relu(scale*S) -> P_lds[p][l] (bf16)
//   GEMM2: kv[p][dd] += P[p][l] @ Xt[dd][l]^T      (fp32 partials to parts)
// ---------------------------------------------------------------------------
__global__ __launch_bounds__(256) void k_compress_mfma(
    const unsigned short* __restrict__ qbf, const unsigned short* __restrict__ ewbf,
    float* __restrict__ parts) {
  const int bh = blockIdx.x, lc = blockIdx.y;
  const int b = bh >> 4, h = bh & 15;
  const int tid = threadIdx.x, wv = tid >> 6, lane = tid & 63;
  const int fr = lane & 15, fg = lane >> 4;

  __shared__ __align__(16) char Xl[8192];    // [l][d] rows of 128B
  __shared__ __align__(16) char Xtl[8192];   // [d][l]
  __shared__ __align__(16) char Pl[32768];   // [p][l] rows of 128B

  bf16x8 ef[4][2];
#pragma unroll
  for (int pt = 0; pt < 4; ++pt)
#pragma unroll
    for (int kc = 0; kc < 2; ++kc)
      ef[pt][kc] = *(const bf16x8*)(ewbf +
          (size_t)((h * PP + wv * 64 + pt * 16 + fr) * HDD) + kc * 32 + fg * 8);

  f32x4 acc[4][4];
#pragma unroll
  for (int i = 0; i < 4; ++i)
#pragma unroll
    for (int j = 0; j < 4; ++j) acc[i][j] = (f32x4){0.f, 0.f, 0.f, 0.f};

  const int l0 = lc * LCHUNK;
  for (int t = 0; t < 4; ++t) {
    __syncthreads();
#pragma unroll
    for (int j = 0; j < 2; ++j) {
      int u = tid + j * 256;
      int l = u >> 3, c8 = u & 7;
      bf16x8 val = *(const bf16x8*)(qbf +
          ((size_t)(l0 + t * 64 + l) * BB + b) * DD + h * HDD + c8 * 8);
      *(bf16x8*)(Xl + l * 128 + ((c8 ^ (l & 7)) << 4)) = val;
#pragma unroll
      for (int i = 0; i < 8; ++i) {
        int dd = c8 * 8 + i;
        *(short*)(Xtl + dd * 128 + (((l >> 3) ^ (dd & 7)) << 4) + ((l & 7) << 1)) = val[i];
      }
    }
    __syncthreads();
#pragma unroll
    for (int lt = 0; lt < 4; ++lt) {
      int rl = lt * 16 + fr;
      bf16x8 xa0 = *(const bf16x8*)(Xl + rl * 128 + (((0 + fg) ^ (rl & 7)) << 4));
      bf16x8 xa1 = *(const bf16x8*)(Xl + rl * 128 + (((4 + fg) ^ (rl & 7)) << 4));
#pragma unroll
      for (int pt = 0; pt < 4; ++pt) {
        f32x4 s = (f32x4){0.f, 0.f, 0.f, 0.f};
        s = MFMA16(xa0, ef[pt][0], s);
        s = MFMA16(xa1, ef[pt][1], s);
        short4v pk;
#pragma unroll
        for (int r = 0; r < 4; ++r)
          pk[r] = (short)f2bf(fmaxf(s[r] * kScaling, 0.f));
        int p = wv * 64 + pt * 16 + fr;
        int lbase = lt * 16 + fg * 4;
        int slot = lbase >> 3;
        *(short4v*)(Pl + p * 128 + ((slot ^ (p & 7)) << 4) + ((lbase & 7) << 1)) = pk;
      }
    }
    asm volatile("s_waitcnt lgkmcnt(0)" ::: "memory");
    __builtin_amdgcn_sched_barrier(0);
#pragma unroll
    for (int kc = 0; kc < 2; ++kc) {
      bf16x8 pa[4], xb[4];
#pragma unroll
      for (int pt = 0; pt < 4; ++pt) {
        int p = wv * 64 + pt * 16 + fr;
        pa[pt] = *(const bf16x8*)(Pl + p * 128 + (((kc * 4 + fg) ^ (p & 7)) << 4));
      }
#pragma unroll
      for (int dt = 0; dt < 4; ++dt) {
        int dd = dt * 16 + fr;
        xb[dt] = *(const bf16x8*)(Xtl + dd * 128 + (((kc * 4 + fg) ^ (dd & 7)) << 4));
      }
#pragma unroll
      for (int pt = 0; pt < 4; ++pt)
#pragma unroll
        for (int dt = 0; dt < 4; ++dt)
          acc[pt][dt] = MFMA16(pa[pt], xb[dt], acc[pt][dt]);
    }
  }
  float* op = parts + (size_t)(lc * 64 + bh) * PP * HDD;
#pragma unroll
  for (int pt = 0; pt < 4; ++pt)
#pragma unroll
    for (int dt = 0; dt < 4; ++dt)
#pragma unroll
      for (int r = 0; r < 4; ++r) {
        int p = wv * 64 + pt * 16 + fg * 4 + r;
        int dd = dt * 16 + fr;
        op[(size_t)p * HDD + dd] = acc[pt][dt][r];
      }
}

// Sum LC partials -> kv_raw bf16 as (P,B,D)
__global__ __launch_bounds__(256) void k_reduce(const float* __restrict__ parts,
                                                unsigned short* __restrict__ kv_raw_bf) {
  int i = blockIdx.x * 256 + threadIdx.x;
  float s = 0.f;
#pragma unroll
  for (int lcc = 0; lcc < LC; ++lcc) s += parts[(size_t)lcc * (64 * PP * HDD) + i];
  int d = i & 63, p = (i >> 6) & 255, bh = i >> 14;
  int b = bh >> 4, h = bh & 15;
  kv_raw_bf[(size_t)(p * BB + b) * DD + h * HDD + d] = f2bf(s);
}

// ---------------------------------------------------------------------------
// C[M,1024] = A_bf16 @ W_bf16^T + bias. MODE 0:+bias 1:*scale 2:+E residual.
// OUTT = float or unsigned short (bf16 store).
// ---------------------------------------------------------------------------
template <int MODE, typename OUTT>
__global__ __launch_bounds__(256) void k_gemm_mfma(
    const unsigned short* __restrict__ A, const unsigned short* __restrict__ W,
    const float* __restrict__ bias, const float* __restrict__ ew,
    OUTT* __restrict__ C) {
  __shared__ __align__(16) char Al[16384];   // [128][64] bf16, 128B rows
  __shared__ __align__(16) char Bl[16384];
  const int tid = threadIdx.x;
  const int wv = tid >> 6, lane = tid & 63;
  const int fr = lane & 15, fg = lane >> 4;
  const int wr = wv >> 1, wc = wv & 1;
  const int m0 = blockIdx.x * 128, n0 = blockIdx.y * 128;

  f32x4 acc[4][4];
#pragma unroll
  for (int i = 0; i < 4; ++i)
#pragma unroll
    for (int j = 0; j < 4; ++j) acc[i][j] = (f32x4){0.f, 0.f, 0.f, 0.f};

  for (int k0 = 0; k0 < DD; k0 += 64) {
    __syncthreads();
#pragma unroll
    for (int j = 0; j < 4; ++j) {
      int u = tid + j * 256;
      int row = u >> 3, slot = u & 7;
      size_t gcol = (size_t)(k0 + 8 * (slot ^ (row & 7)));
      gll16(A + (size_t)(m0 + row) * DD + gcol, Al + u * 16);
      gll16(W + (size_t)(n0 + row) * DD + gcol, Bl + u * 16);
    }
    __syncthreads();
#pragma unroll
    for (int kc = 0; kc < 2; ++kc) {
      bf16x8 af[4], bfr[4];
#pragma unroll
      for (int mt = 0; mt < 4; ++mt) {
        int r = wr * 64 + mt * 16 + fr;
        af[mt] = *(const bf16x8*)(Al + r * 128 + (((kc * 4 + fg) ^ (r & 7)) << 4));
      }
#pragma unroll
      for (int nt = 0; nt < 4; ++nt) {
        int r = wc * 64 + nt * 16 + fr;
        bfr[nt] = *(const bf16x8*)(Bl + r * 128 + (((kc * 4 + fg) ^ (r & 7)) << 4));
      }
#pragma unroll
      for (int mt = 0; mt < 4; ++mt)
#pragma unroll
        for (int nt = 0; nt < 4; ++nt)
          acc[mt][nt] = MFMA16(af[mt], bfr[nt], acc[mt][nt]);
    }
  }

  float bs[4];
#pragma unroll
  for (int nt = 0; nt < 4; ++nt) bs[nt] = bias[n0 + wc * 64 + nt * 16 + fr];
#pragma unroll
  for (int mt = 0; mt < 4; ++mt)
#pragma unroll
    for (int nt = 0; nt < 4; ++nt) {
      int n = n0 + wc * 64 + nt * 16 + fr;
#pragma unroll
      for (int r = 0; r < 4; ++r) {
        int m = m0 + wr * 64 + mt * 16 + fg * 4 + r;
        float v = acc[mt][nt][r] + bs[nt];
        if (MODE == 1) v *= kScaling;
        if (MODE == 2) {
          int p = m >> 2, hh = n >> 6, d2 = n & 63;
          v += ew[(size_t)((hh << 8) + p) * HDD + d2];
        }
        if constexpr (sizeof(OUTT) == 2)
          C[(size_t)m * DD + n] = (OUTT)f2bf(v);
        else
          C[(size_t)m * DD + n] = v;
      }
    }
}

// LayerNorm over D=1024; fp32 in -> bf16 out. One block per row.
__global__ __launch_bounds__(256) void k_ln(const float* __restrict__ x,
                                            const float* __restrict__ g,
                                            const float* __restrict__ bb,
                                            unsigned short* __restrict__ y) {
  const int r = blockIdx.x;
  const int tid = threadIdx.x;
  const float* xr = x + (size_t)r * DD;
  float4 v = *(const float4*)(xr + tid * 4);
  float s1 = v.x + v.y + v.z + v.w;
  float s2 = v.x * v.x + v.y * v.y + v.z * v.z + v.w * v.w;
#pragma unroll
  for (int off = 32; off > 0; off >>= 1) {
    s1 += __shfl_down(s1, off);
    s2 += __shfl_down(s2, off);
  }
  __shared__ float w1[4], w2[4];
  if ((tid & 63) == 0) { w1[tid >> 6] = s1; w2[tid >> 6] = s2; }
  __syncthreads();
  float S1 = w1[0] + w1[1] + w1[2] + w1[3];
  float S2 = w2[0] + w2[1] + w2[2] + w2[3];
  float mean = S1 * (1.f / DD);
  float var = S2 * (1.f / DD) - mean * mean;
  float rstd = rsqrtf(var + kEps);
  float4 gv = *(const float4*)(g + tid * 4);
  float4 bv = *(const float4*)(bb + tid * 4);
  short4v o;
  o[0] = (short)f2bf((v.x - mean) * rstd * gv.x + bv.x);
  o[1] = (short)f2bf((v.y - mean) * rstd * gv.y + bv.y);
  o[2] = (short)f2bf((v.z - mean) * rstd * gv.z + bv.z);
  o[3] = (short)f2bf((v.w - mean) * rstd * gv.w + bv.w);
  *(short4v*)(y + (size_t)r * DD + tid * 4) = o;
}

// ---------------------------------------------------------------------------
// Attention (MFMA, flash-style, no max-subtraction -- logits bounded ~|3|).
// Block = 512 thr (8 waves) x 128 q-rows for one (b,h); wave owns 16 rows.
// LDS: K 32KB + Vt 32KB + P 64KB = 128KB.
// ---------------------------------------------------------------------------
__global__ __launch_bounds__(512, 2) void k_attn_mfma(
    const unsigned short* __restrict__ qbf, const unsigned short* __restrict__ kbf,
    const unsigned short* __restrict__ vbf, unsigned short* __restrict__ attn) {
  const int bh = blockIdx.y;
  const int b = bh >> 4, h = bh & 15;
  const int tid = threadIdx.x, wv = tid >> 6, lane = tid & 63;
  const int fr = lane & 15, fg = lane >> 4;
  const int bl0 = blockIdx.x * 128;

  __shared__ __align__(16) char Kl[32768];    // [p][d] 128B rows, XOR swz
  __shared__ __align__(16) char Vt[32768];    // 4 chunks of [64 dd][64 p]
  __shared__ __align__(16) char Pl[65536];    // 8 waves x [16 l][256 p]

#pragma unroll
  for (int j = 0; j < 4; ++j) {
    int u = tid + j * 512;
    int p = u >> 3, slot = u & 7;
    gll16(kbf + ((size_t)(p * BB + b)) * DD + h * HDD + 8 * (slot ^ (p & 7)),
          Kl + u * 16);
  }
#pragma unroll
  for (int j = 0; j < 4; ++j) {
    int u = tid + j * 512;
    int p = u >> 3, c8 = u & 7;
    bf16x8 val = *(const bf16x8*)(vbf + ((size_t)(p * BB + b)) * DD + h * HDD + c8 * 8);
    int pc = p >> 6, pl = p & 63;
#pragma unroll
    for (int i = 0; i < 8; ++i) {
      int dd = c8 * 8 + i;
      *(short*)(Vt + pc * 8192 + dd * 128 + ((((pl >> 3) ^ (dd & 7)) << 4)) +
                ((pl & 7) << 1)) = val[i];
    }
  }
  __syncthreads();

  const size_t qrow = ((size_t)(bl0 + wv * 16 + fr) * BB + b) * DD + h * HDD;
  bf16x8 qf0 = *(const bf16x8*)(qbf + qrow + fg * 8);
  bf16x8 qf1 = *(const bf16x8*)(qbf + qrow + 32 + fg * 8);

  // S^T = K @ Q^T : 16 p-tiles
  f32x4 s[16];
#pragma unroll
  for (int pt = 0; pt < 16; ++pt) {
    int pr = pt * 16 + fr;
    bf16x8 a0 = *(const bf16x8*)(Kl + pr * 128 + ((fg ^ (pr & 7)) << 4));
    bf16x8 a1 = *(const bf16x8*)(Kl + pr * 128 + (((4 + fg) ^ (pr & 7)) << 4));
    f32x4 acc = (f32x4){0.f, 0.f, 0.f, 0.f};
    acc = MFMA16(a0, qf0, acc);
    acc = MFMA16(a1, qf1, acc);
    s[pt] = acc;
  }

  // exp + unnormalized P -> LDS (own-wave region); fp32 row sum
  float psum = 0.f;
  char* Pw = Pl + wv * 8192;
#pragma unroll
  for (int pt = 0; pt < 16; ++pt) {
    float e0 = __expf(s[pt][0]), e1 = __expf(s[pt][1]);
    float e2 = __expf(s[pt][2]), e3 = __expf(s[pt][3]);
    psum += (e0 + e1) + (e2 + e3);
    short4v pk;
    pk[0] = (short)f2bf(e0); pk[1] = (short)f2bf(e1);
    pk[2] = (short)f2bf(e2); pk[3] = (short)f2bf(e3);
    int pbyte = (pt * 16 + fg * 4) * 2;
    int slot = pbyte >> 4, rem = pbyte & 15;
    *(short4v*)(Pw + fr * 512 + ((slot ^ (fr & 7)) << 4) + rem) = pk;
  }
  psum += __shfl_xor(psum, 16);
  psum += __shfl_xor(psum, 32);
  asm volatile("s_waitcnt lgkmcnt(0)" ::: "memory");
  __builtin_amdgcn_sched_barrier(0);

  // O = P @ V^T : 4 dd-tiles, K = 256 p in 8 chunks
  f32x4 o[4];
#pragma unroll
  for (int dt = 0; dt < 4; ++dt) o[dt] = (f32x4){0.f, 0.f, 0.f, 0.f};
#pragma unroll
  for (int kc = 0; kc < 8; ++kc) {
    int slot = kc * 4 + fg;
    bf16x8 pa = *(const bf16x8*)(Pw + fr * 512 + ((slot ^ (fr & 7)) << 4));
    int sl2 = (kc & 1) * 4 + fg;
#pragma unroll
    for (int dt = 0; dt < 4; ++dt) {
      int dd = dt * 16 + fr;
      bf16x8 vb = *(const bf16x8*)(Vt + (kc >> 1) * 8192 + dd * 128 +
                                   ((sl2 ^ (dd & 7)) << 4));
      o[dt] = MFMA16(pa, vb, o[dt]);
    }
  }

  // normalize + store: lane holds O[l=fg*4+r][dd=dt*16+fr]
#pragma unroll
  for (int r = 0; r < 4; ++r) {
    int lloc = fg * 4 + r;
    float inv = 1.f / __shfl(psum, lloc);
    unsigned short* op = attn +
        ((size_t)(bl0 + wv * 16 + lloc) * BB + b) * DD + h * HDD;
#pragma unroll
    for (int dt = 0; dt < 4; ++dt)
      op[dt * 16 + fr] = f2bf(o[dt][r] * inv);
  }
}

extern "C" void kernel_launch(void* const* d_in, const int* in_sizes, int n_in,
                              void* d_out, int out_size, void* d_ws, size_t ws_size,
                              hipStream_t stream) {
  const float* query   = (const float*)d_in[0];
  const float* q_w     = (const float*)d_in[1];
  const float* q_b     = (const float*)d_in[2];
  const float* k_w     = (const float*)d_in[3];
  const float* k_b     = (const float*)d_in[4];
  const float* v_w     = (const float*)d_in[5];
  const float* v_b     = (const float*)d_in[6];
  const float* e_weight= (const float*)d_in[7];
  const float* e_out_w = (const float*)d_in[8];
  const float* e_out_b = (const float*)d_in[9];
  const float* ln_g    = (const float*)d_in[10];
  const float* ln_b    = (const float*)d_in[11];
  const float* out_w   = (const float*)d_in[12];
  const float* out_b   = (const float*)d_in[13];
  float* out = (float*)d_out;

  char* w = (char*)d_ws;
  float* parts            = (float*)w;                          // 64 MB, dead after reduce
  unsigned short* q_bf    = (unsigned short*)w;                 // 32 MB (alias, after reduce)
  unsigned short* attn_bf = (unsigned short*)(w + (32u << 20)); // 32 MB (alias, after reduce)
  unsigned short* query_bf= (unsigned short*)(w + (64u << 20)); // 32 MB
  unsigned short* kv_raw  = (unsigned short*)(w + (96u << 20)); // 2 MB
  float* kv_eo            = (float*)(w + (98u << 20));          // 4 MB
  unsigned short* kv_ln   = (unsigned short*)(w + (102u << 20));// 2 MB
  unsigned short* k_buf   = (unsigned short*)(w + (104u << 20));// 2 MB
  unsigned short* v_buf   = (unsigned short*)(w + (106u << 20));// 2 MB
  unsigned short* wq  = (unsigned short*)(w + (108u << 20));
  unsigned short* wk  = (unsigned short*)(w + (110u << 20));
  unsigned short* wv_ = (unsigned short*)(w + (112u << 20));
  unsigned short* weo = (unsigned short*)(w + (114u << 20));
  unsigned short* wo  = (unsigned short*)(w + (116u << 20));
  unsigned short* ewb = (unsigned short*)(w + (118u << 20));    // 0.5 MB

  k_cvt<<<8192, 256, 0, stream>>>(query, query_bf, 2097152);
  k_cvt<<<512, 256, 0, stream>>>(q_w, wq, 131072);
  k_cvt<<<512, 256, 0, stream>>>(k_w, wk, 131072);
  k_cvt<<<512, 256, 0, stream>>>(v_w, wv_, 131072);
  k_cvt<<<512, 256, 0, stream>>>(e_out_w, weo, 131072);
  k_cvt<<<512, 256, 0, stream>>>(out_w, wo, 131072);
  k_cvt<<<128, 256, 0, stream>>>(e_weight, ewb, 32768);

  k_compress_mfma<<<dim3(64, LC), 256, 0, stream>>>(query_bf, ewb, parts);
  k_reduce<<<4096, 256, 0, stream>>>(parts, kv_raw);
  k_gemm_mfma<2, float><<<dim3(8, 8), 256, 0, stream>>>(kv_raw, weo, e_out_b, e_weight, kv_eo);
  k_ln<<<PP * BB, 256, 0, stream>>>(kv_eo, ln_g, ln_b, kv_ln);
  k_gemm_mfma<1, unsigned short><<<dim3(128, 8), 256, 0, stream>>>(query_bf, wq, q_b, nullptr, q_bf);
  k_gemm_mfma<0, unsigned short><<<dim3(8, 8), 256, 0, stream>>>(kv_ln, wk, k_b, nullptr, k_buf);
  k_gemm_mfma<0, unsigned short><<<dim3(8, 8), 256, 0, stream>>>(kv_ln, wv_, v_b, nullptr, v_buf);
  k_attn_mfma<<<dim3(32, 64), 512, 0, stream>>>(q_bf, k_buf, v_buf, attn_bf);
  k_gemm_mfma<0, float><<<dim3(128, 8), 256, 0, stream>>>(attn_bf, wo, out_b, nullptr, out);
}

// Round 6
// 247.880 us; speedup vs baseline: 10.2973x; 1.1566x over previous
//
#include <hip/hip_runtime.h>
#include <hip/hip_bf16.h>
#include <cstdint>
#include <cstddef>

#define LL 4096
#define BB 4
#define DD 1024
#define HH 16
#define PP 256
#define HDD 64
#define LC 16
#define LCHUNK 256

constexpr float kScaling = 0.125f;   // HD^-0.5
constexpr float kEps = 1e-5f;

typedef __attribute__((ext_vector_type(8))) short bf16x8;   // 8 bf16 = 4 VGPR
typedef __attribute__((ext_vector_type(4))) short short4v;
typedef __attribute__((ext_vector_type(4))) float f32x4;

#define MFMA16(a, b, c) __builtin_amdgcn_mfma_f32_16x16x32_bf16((a), (b), (c), 0, 0, 0)

__device__ __forceinline__ unsigned short f2bf(float f) {
  unsigned int u = __builtin_bit_cast(unsigned int, f);
  u += 0x7FFFu + ((u >> 16) & 1u);           // round-to-nearest-even
  return (unsigned short)(u >> 16);
}

__device__ __forceinline__ void gll16(const void* g, void* l) {
  __builtin_amdgcn_global_load_lds(
      (const __attribute__((address_space(1))) unsigned int*)g,
      (__attribute__((address_space(3))) unsigned int*)l, 16, 0, 0);
}

// ---------------------------------------------------------------------------
// fp32 -> bf16 bulk convert; each thread does 8 elems.
// ---------------------------------------------------------------------------
__global__ __launch_bounds__(256) void k_cvt(const float* __restrict__ src,
                                             unsigned short* __restrict__ dst,
                                             int n8) {
  int i = blockIdx.x * 256 + threadIdx.x;
  if (i >= n8) return;
  const float4* s = (const float4*)(src + (size_t)i * 8);
  float4 a = s[0], b = s[1];
  bf16x8 o;
  o[0] = f2bf(a.x); o[1] = f2bf(a.y); o[2] = f2bf(a.z); o[3] = f2bf(a.w);
  o[4] = f2bf(b.x); o[5] = f2bf(b.y); o[6] = f2bf(b.z); o[7] = f2bf(b.w);
  *(bf16x8*)(dst + (size_t)i * 8) = o;
}

// ---------------------------------------------------------------------------
// Compress (MFMA): per (b,h,lc): over 4 tiles of LT=64 rows l:
//   GEMM1: S^T[l][p] = X[l][d] @ E[p][d]^T ; relu(scale*S) -> P_lds[p][l] (bf16)
//   GEMM2: kv[p][dd] += P[p][l] @ Xt[dd][l]^T      (fp32 partials to parts)
// Xtl swizzle includes ^(dd>>3) so the 8 c8-lanes of a group hit 8 banks.
// ---------------------------------------------------------------------------
__global__ __launch_bounds__(256) void k_compress_mfma(
    const unsigned short* __restrict__ qbf, const unsigned short* __restrict__ ewbf,
    float* __restrict__ parts) {
  const int bh = blockIdx.x, lc = blockIdx.y;
  const int b = bh >> 4, h = bh & 15;
  const int tid = threadIdx.x, wv = tid >> 6, lane = tid & 63;
  const int fr = lane & 15, fg = lane >> 4;

  __shared__ __align__(16) char Xl[8192];    // [l][d] rows of 128B
  __shared__ __align__(16) char Xtl[8192];   // [d][l]
  __shared__ __align__(16) char Pl[32768];   // [p][l] rows of 128B

  bf16x8 ef[4][2];
#pragma unroll
  for (int pt = 0; pt < 4; ++pt)
#pragma unroll
    for (int kc = 0; kc < 2; ++kc)
      ef[pt][kc] = *(const bf16x8*)(ewbf +
          (size_t)((h * PP + wv * 64 + pt * 16 + fr) * HDD) + kc * 32 + fg * 8);

  f32x4 acc[4][4];
#pragma unroll
  for (int i = 0; i < 4; ++i)
#pragma unroll
    for (int j = 0; j < 4; ++j) acc[i][j] = (f32x4){0.f, 0.f, 0.f, 0.f};

  const int l0 = lc * LCHUNK;
  for (int t = 0; t < 4; ++t) {
    __syncthreads();
#pragma unroll
    for (int j = 0; j < 2; ++j) {
      int u = tid + j * 256;
      int l = u >> 3, c8 = u & 7;
      bf16x8 val = *(const bf16x8*)(qbf +
          ((size_t)(l0 + t * 64 + l) * BB + b) * DD + h * HDD + c8 * 8);
      *(bf16x8*)(Xl + l * 128 + ((c8 ^ (l & 7)) << 4)) = val;
#pragma unroll
      for (int i = 0; i < 8; ++i) {
        int dd = c8 * 8 + i;
        *(short*)(Xtl + dd * 128 + ((((l >> 3) ^ (dd & 7) ^ (dd >> 3)) & 7) << 4) +
                  ((l & 7) << 1)) = val[i];
      }
    }
    __syncthreads();
#pragma unroll
    for (int lt = 0; lt < 4; ++lt) {
      int rl = lt * 16 + fr;
      bf16x8 xa0 = *(const bf16x8*)(Xl + rl * 128 + (((0 + fg) ^ (rl & 7)) << 4));
      bf16x8 xa1 = *(const bf16x8*)(Xl + rl * 128 + (((4 + fg) ^ (rl & 7)) << 4));
#pragma unroll
      for (int pt = 0; pt < 4; ++pt) {
        f32x4 s = (f32x4){0.f, 0.f, 0.f, 0.f};
        s = MFMA16(xa0, ef[pt][0], s);
        s = MFMA16(xa1, ef[pt][1], s);
        short4v pk;
#pragma unroll
        for (int r = 0; r < 4; ++r)
          pk[r] = (short)f2bf(fmaxf(s[r] * kScaling, 0.f));
        int p = wv * 64 + pt * 16 + fr;
        int lbase = lt * 16 + fg * 4;
        int slot = lbase >> 3;
        *(short4v*)(Pl + p * 128 + ((slot ^ (p & 7)) << 4) + ((lbase & 7) << 1)) = pk;
      }
    }
    asm volatile("s_waitcnt lgkmcnt(0)" ::: "memory");
    __builtin_amdgcn_sched_barrier(0);
#pragma unroll
    for (int kc = 0; kc < 2; ++kc) {
      bf16x8 pa[4], xb[4];
#pragma unroll
      for (int pt = 0; pt < 4; ++pt) {
        int p = wv * 64 + pt * 16 + fr;
        pa[pt] = *(const bf16x8*)(Pl + p * 128 + (((kc * 4 + fg) ^ (p & 7)) << 4));
      }
#pragma unroll
      for (int dt = 0; dt < 4; ++dt) {
        int dd = dt * 16 + fr;
        xb[dt] = *(const bf16x8*)(Xtl + dd * 128 +
                  ((((kc * 4 + fg) ^ (dd & 7) ^ (dd >> 3)) & 7) << 4));
      }
#pragma unroll
      for (int pt = 0; pt < 4; ++pt)
#pragma unroll
        for (int dt = 0; dt < 4; ++dt)
          acc[pt][dt] = MFMA16(pa[pt], xb[dt], acc[pt][dt]);
    }
  }
  float* op = parts + (size_t)(lc * 64 + bh) * PP * HDD;
#pragma unroll
  for (int pt = 0; pt < 4; ++pt)
#pragma unroll
    for (int dt = 0; dt < 4; ++dt)
#pragma unroll
      for (int r = 0; r < 4; ++r) {
        int p = wv * 64 + pt * 16 + fg * 4 + r;
        int dd = dt * 16 + fr;
        op[(size_t)p * HDD + dd] = acc[pt][dt][r];
      }
}

// Sum LC partials -> kv_raw bf16 as (P,B,D)
__global__ __launch_bounds__(256) void k_reduce(const float* __restrict__ parts,
                                                unsigned short* __restrict__ kv_raw_bf) {
  int i = blockIdx.x * 256 + threadIdx.x;
  float s = 0.f;
#pragma unroll
  for (int lcc = 0; lcc < LC; ++lcc) s += parts[(size_t)lcc * (64 * PP * HDD) + i];
  int d = i & 63, p = (i >> 6) & 255, bh = i >> 14;
  int b = bh >> 4, h = bh & 15;
  kv_raw_bf[(size_t)(p * BB + b) * DD + h * HDD + d] = f2bf(s);
}

// ---------------------------------------------------------------------------
// Shared GEMM body: C[M,1024] = A_bf16 @ W_bf16^T + bias.
// MODE 0:+bias 1:*scale 2:+E residual. OUTT = float | ushort(bf16).
// ---------------------------------------------------------------------------
template <int MODE, typename OUTT>
__device__ __forceinline__ void gemm_body(
    const unsigned short* __restrict__ A, const unsigned short* __restrict__ W,
    const float* __restrict__ bias, const float* __restrict__ ew,
    OUTT* __restrict__ C, int m0, int n0, char* Al, char* Bl) {
  const int tid = threadIdx.x;
  const int wv = tid >> 6, lane = tid & 63;
  const int fr = lane & 15, fg = lane >> 4;
  const int wr = wv >> 1, wc = wv & 1;

  f32x4 acc[4][4];
#pragma unroll
  for (int i = 0; i < 4; ++i)
#pragma unroll
    for (int j = 0; j < 4; ++j) acc[i][j] = (f32x4){0.f, 0.f, 0.f, 0.f};

  for (int k0 = 0; k0 < DD; k0 += 64) {
    __syncthreads();
#pragma unroll
    for (int j = 0; j < 4; ++j) {
      int u = tid + j * 256;
      int row = u >> 3, slot = u & 7;
      size_t gcol = (size_t)(k0 + 8 * (slot ^ (row & 7)));
      gll16(A + (size_t)(m0 + row) * DD + gcol, Al + u * 16);
      gll16(W + (size_t)(n0 + row) * DD + gcol, Bl + u * 16);
    }
    __syncthreads();
#pragma unroll
    for (int kc = 0; kc < 2; ++kc) {
      bf16x8 af[4], bfr[4];
#pragma unroll
      for (int mt = 0; mt < 4; ++mt) {
        int r = wr * 64 + mt * 16 + fr;
        af[mt] = *(const bf16x8*)(Al + r * 128 + (((kc * 4 + fg) ^ (r & 7)) << 4));
      }
#pragma unroll
      for (int nt = 0; nt < 4; ++nt) {
        int r = wc * 64 + nt * 16 + fr;
        bfr[nt] = *(const bf16x8*)(Bl + r * 128 + (((kc * 4 + fg) ^ (r & 7)) << 4));
      }
#pragma unroll
      for (int mt = 0; mt < 4; ++mt)
#pragma unroll
        for (int nt = 0; nt < 4; ++nt)
          acc[mt][nt] = MFMA16(af[mt], bfr[nt], acc[mt][nt]);
    }
  }

  float bs[4];
#pragma unroll
  for (int nt = 0; nt < 4; ++nt) bs[nt] = bias[n0 + wc * 64 + nt * 16 + fr];
#pragma unroll
  for (int mt = 0; mt < 4; ++mt)
#pragma unroll
    for (int nt = 0; nt < 4; ++nt) {
      int n = n0 + wc * 64 + nt * 16 + fr;
#pragma unroll
      for (int r = 0; r < 4; ++r) {
        int m = m0 + wr * 64 + mt * 16 + fg * 4 + r;
        float v = acc[mt][nt][r] + bs[nt];
        if (MODE == 1) v *= kScaling;
        if (MODE == 2) {
          int p = m >> 2, hh = n >> 6, d2 = n & 63;
          v += ew[(size_t)((hh << 8) + p) * HDD + d2];
        }
        if constexpr (sizeof(OUTT) == 2)
          C[(size_t)m * DD + n] = (OUTT)f2bf(v);
        else
          C[(size_t)m * DD + n] = v;
      }
    }
}

template <int MODE, typename OUTT>
__global__ __launch_bounds__(256) void k_gemm_mfma(
    const unsigned short* __restrict__ A, const unsigned short* __restrict__ W,
    const float* __restrict__ bias, const float* __restrict__ ew,
    OUTT* __restrict__ C) {
  __shared__ __align__(16) char Al[16384];
  __shared__ __align__(16) char Bl[16384];
  gemm_body<MODE, OUTT>(A, W, bias, ew, C, blockIdx.x * 128, blockIdx.y * 128, Al, Bl);
}

// K and V projections in one launch (blockIdx.z selects).
__global__ __launch_bounds__(256) void k_gemm_kv(
    const unsigned short* __restrict__ A,
    const unsigned short* __restrict__ Wk, const unsigned short* __restrict__ Wv,
    const float* __restrict__ kb, const float* __restrict__ vb,
    unsigned short* __restrict__ Ck, unsigned short* __restrict__ Cv) {
  __shared__ __align__(16) char Al[16384];
  __shared__ __align__(16) char Bl[16384];
  if (blockIdx.z == 0)
    gemm_body<0, unsigned short>(A, Wk, kb, nullptr, Ck,
                                 blockIdx.x * 128, blockIdx.y * 128, Al, Bl);
  else
    gemm_body<0, unsigned short>(A, Wv, vb, nullptr, Cv,
                                 blockIdx.x * 128, blockIdx.y * 128, Al, Bl);
}

// LayerNorm over D=1024; fp32 in -> bf16 out. One block per row.
__global__ __launch_bounds__(256) void k_ln(const float* __restrict__ x,
                                            const float* __restrict__ g,
                                            const float* __restrict__ bb,
                                            unsigned short* __restrict__ y) {
  const int r = blockIdx.x;
  const int tid = threadIdx.x;
  const float* xr = x + (size_t)r * DD;
  float4 v = *(const float4*)(xr + tid * 4);
  float s1 = v.x + v.y + v.z + v.w;
  float s2 = v.x * v.x + v.y * v.y + v.z * v.z + v.w * v.w;
#pragma unroll
  for (int off = 32; off > 0; off >>= 1) {
    s1 += __shfl_down(s1, off);
    s2 += __shfl_down(s2, off);
  }
  __shared__ float w1[4], w2[4];
  if ((tid & 63) == 0) { w1[tid >> 6] = s1; w2[tid >> 6] = s2; }
  __syncthreads();
  float S1 = w1[0] + w1[1] + w1[2] + w1[3];
  float S2 = w2[0] + w2[1] + w2[2] + w2[3];
  float mean = S1 * (1.f / DD);
  float var = S2 * (1.f / DD) - mean * mean;
  float rstd = rsqrtf(var + kEps);
  float4 gv = *(const float4*)(g + tid * 4);
  float4 bv = *(const float4*)(bb + tid * 4);
  short4v o;
  o[0] = (short)f2bf((v.x - mean) * rstd * gv.x + bv.x);
  o[1] = (short)f2bf((v.y - mean) * rstd * gv.y + bv.y);
  o[2] = (short)f2bf((v.z - mean) * rstd * gv.z + bv.z);
  o[3] = (short)f2bf((v.w - mean) * rstd * gv.w + bv.w);
  *(short4v*)(y + (size_t)r * DD + tid * 4) = o;
}

// ---------------------------------------------------------------------------
// Attention (MFMA, flash-style, no max-subtraction -- logits bounded ~|3|).
// Two KV halves of 128 p -> LDS 64KB -> 2 blocks/CU. 8 waves x 16 q-rows.
// Vt swizzle includes ^(dd>>3): kills the 8-way transpose-write conflict.
// ---------------------------------------------------------------------------
__global__ __launch_bounds__(512, 2) void k_attn_mfma(
    const unsigned short* __restrict__ qbf, const unsigned short* __restrict__ kbf,
    const unsigned short* __restrict__ vbf, unsigned short* __restrict__ attn) {
  const int bh = blockIdx.y;
  const int b = bh >> 4, h = bh & 15;
  const int tid = threadIdx.x, wv = tid >> 6, lane = tid & 63;
  const int fr = lane & 15, fg = lane >> 4;
  const int bl0 = blockIdx.x * 128;

  __shared__ __align__(16) char Kl[16384];    // [128p][64d] swz rows of 128B
  __shared__ __align__(16) char Vt[16384];    // 2 chunks of [64 dd][64 p]
  __shared__ __align__(16) char Pl[32768];    // 8 waves x [16 l][128 p] (256B rows)

  const size_t qrow = ((size_t)(bl0 + wv * 16 + fr) * BB + b) * DD + h * HDD;
  bf16x8 qf0 = *(const bf16x8*)(qbf + qrow + fg * 8);
  bf16x8 qf1 = *(const bf16x8*)(qbf + qrow + 32 + fg * 8);

  f32x4 o[4];
#pragma unroll
  for (int dt = 0; dt < 4; ++dt) o[dt] = (f32x4){0.f, 0.f, 0.f, 0.f};
  float psum = 0.f;
  char* Pw = Pl + wv * 4096;

  for (int ph = 0; ph < 2; ++ph) {
    __syncthreads();    // prev PV reads done; LDS safe to overwrite
    // stage K half (gll16, pre-swizzled source): 1024 units
#pragma unroll
    for (int j = 0; j < 2; ++j) {
      int u = tid + j * 512;
      int p = u >> 3, slot = u & 7;
      gll16(kbf + ((size_t)((ph * 128 + p) * BB + b)) * DD + h * HDD +
                8 * (slot ^ (p & 7)),
            Kl + u * 16);
    }
    // stage V^T half (reg transpose)
#pragma unroll
    for (int j = 0; j < 2; ++j) {
      int u = tid + j * 512;
      int p = u >> 3, c8 = u & 7;
      bf16x8 val = *(const bf16x8*)(vbf +
          ((size_t)((ph * 128 + p) * BB + b)) * DD + h * HDD + c8 * 8);
      int pc = p >> 6, pl = p & 63;
#pragma unroll
      for (int i = 0; i < 8; ++i) {
        int dd = c8 * 8 + i;
        *(short*)(Vt + pc * 8192 + dd * 128 +
                  ((((pl >> 3) ^ (dd & 7) ^ (dd >> 3)) & 7) << 4) +
                  ((pl & 7) << 1)) = val[i];
      }
    }
    __syncthreads();    // includes vmcnt(0) drain of gll16

    // S^T = K @ Q^T : 8 p-tiles this half
    f32x4 s[8];
    __builtin_amdgcn_s_setprio(1);
#pragma unroll
    for (int pt = 0; pt < 8; ++pt) {
      int pr = pt * 16 + fr;
      bf16x8 a0 = *(const bf16x8*)(Kl + pr * 128 + ((fg ^ (pr & 7)) << 4));
      bf16x8 a1 = *(const bf16x8*)(Kl + pr * 128 + (((4 + fg) ^ (pr & 7)) << 4));
      f32x4 acc = (f32x4){0.f, 0.f, 0.f, 0.f};
      acc = MFMA16(a0, qf0, acc);
      acc = MFMA16(a1, qf1, acc);
      s[pt] = acc;
    }
    __builtin_amdgcn_s_setprio(0);

    // exp + unnormalized P -> own-wave LDS; fp32 row-sum accumulates
#pragma unroll
    for (int pt = 0; pt < 8; ++pt) {
      float e0 = __expf(s[pt][0]), e1 = __expf(s[pt][1]);
      float e2 = __expf(s[pt][2]), e3 = __expf(s[pt][3]);
      psum += (e0 + e1) + (e2 + e3);
      short4v pk;
      pk[0] = (short)f2bf(e0); pk[1] = (short)f2bf(e1);
      pk[2] = (short)f2bf(e2); pk[3] = (short)f2bf(e3);
      int pbyte = (pt * 16 + fg * 4) * 2;
      int slot = pbyte >> 4, rem = pbyte & 15;
      *(short4v*)(Pw + fr * 256 + ((slot ^ (fr & 7)) << 4) + rem) = pk;
    }
    asm volatile("s_waitcnt lgkmcnt(0)" ::: "memory");
    __builtin_amdgcn_sched_barrier(0);

    // O += P @ V^T : K = 128 p in 4 chunks
    __builtin_amdgcn_s_setprio(1);
#pragma unroll
    for (int kc = 0; kc < 4; ++kc) {
      int slot = kc * 4 + fg;
      bf16x8 pa = *(const bf16x8*)(Pw + fr * 256 + ((slot ^ (fr & 7)) << 4));
      int sl2 = (kc & 1) * 4 + fg;
#pragma unroll
      for (int dt = 0; dt < 4; ++dt) {
        int dd = dt * 16 + fr;
        bf16x8 vb = *(const bf16x8*)(Vt + (kc >> 1) * 8192 + dd * 128 +
                     (((sl2 ^ (dd & 7) ^ (dd >> 3)) & 7) << 4));
        o[dt] = MFMA16(pa, vb, o[dt]);
      }
    }
    __builtin_amdgcn_s_setprio(0);
  }

  psum += __shfl_xor(psum, 16);
  psum += __shfl_xor(psum, 32);

  // normalize + store: lane holds O[l=fg*4+r][dd=dt*16+fr]
#pragma unroll
  for (int r = 0; r < 4; ++r) {
    int lloc = fg * 4 + r;
    float inv = 1.f / __shfl(psum, lloc);
    unsigned short* op = attn +
        ((size_t)(bl0 + wv * 16 + lloc) * BB + b) * DD + h * HDD;
#pragma unroll
    for (int dt = 0; dt < 4; ++dt)
      op[dt * 16 + fr] = f2bf(o[dt][r] * inv);
  }
}

extern "C" void kernel_launch(void* const* d_in, const int* in_sizes, int n_in,
                              void* d_out, int out_size, void* d_ws, size_t ws_size,
                              hipStream_t stream) {
  const float* query   = (const float*)d_in[0];
  const float* q_w     = (const float*)d_in[1];
  const float* q_b     = (const float*)d_in[2];
  const float* k_w     = (const float*)d_in[3];
  const float* k_b     = (const float*)d_in[4];
  const float* v_w     = (const float*)d_in[5];
  const float* v_b     = (const float*)d_in[6];
  const float* e_weight= (const float*)d_in[7];
  const float* e_out_w = (const float*)d_in[8];
  const float* e_out_b = (const float*)d_in[9];
  const float* ln_g    = (const float*)d_in[10];
  const float* ln_b    = (const float*)d_in[11];
  const float* out_w   = (const float*)d_in[12];
  const float* out_b   = (const float*)d_in[13];
  float* out = (float*)d_out;

  char* w = (char*)d_ws;
  float* parts            = (float*)w;                          // 64 MB, dead after reduce
  unsigned short* q_bf    = (unsigned short*)w;                 // 32 MB (alias, after reduce)
  unsigned short* attn_bf = (unsigned short*)(w + (32u << 20)); // 32 MB (alias, after reduce)
  unsigned short* query_bf= (unsigned short*)(w + (64u << 20)); // 32 MB
  unsigned short* kv_raw  = (unsigned short*)(w + (96u << 20)); // 2 MB
  float* kv_eo            = (float*)(w + (98u << 20));          // 4 MB
  unsigned short* kv_ln   = (unsigned short*)(w + (102u << 20));// 2 MB
  unsigned short* k_buf   = (unsigned short*)(w + (104u << 20));// 2 MB
  unsigned short* v_buf   = (unsigned short*)(w + (106u << 20));// 2 MB
  unsigned short* wq  = (unsigned short*)(w + (108u << 20));
  unsigned short* wk  = (unsigned short*)(w + (110u << 20));
  unsigned short* wv_ = (unsigned short*)(w + (112u << 20));
  unsigned short* weo = (unsigned short*)(w + (114u << 20));
  unsigned short* wo  = (unsigned short*)(w + (116u << 20));
  unsigned short* ewb = (unsigned short*)(w + (118u << 20));    // 0.5 MB

  k_cvt<<<8192, 256, 0, stream>>>(query, query_bf, 2097152);
  k_cvt<<<512, 256, 0, stream>>>(q_w, wq, 131072);
  k_cvt<<<512, 256, 0, stream>>>(k_w, wk, 131072);
  k_cvt<<<512, 256, 0, stream>>>(v_w, wv_, 131072);
  k_cvt<<<512, 256, 0, stream>>>(e_out_w, weo, 131072);
  k_cvt<<<512, 256, 0, stream>>>(out_w, wo, 131072);
  k_cvt<<<128, 256, 0, stream>>>(e_weight, ewb, 32768);

  k_compress_mfma<<<dim3(64, LC), 256, 0, stream>>>(query_bf, ewb, parts);
  k_reduce<<<4096, 256, 0, stream>>>(parts, kv_raw);
  k_gemm_mfma<2, float><<<dim3(8, 8), 256, 0, stream>>>(kv_raw, weo, e_out_b, e_weight, kv_eo);
  k_ln<<<PP * BB, 256, 0, stream>>>(kv_eo, ln_g, ln_b, kv_ln);
  k_gemm_mfma<1, unsigned short><<<dim3(128, 8), 256, 0, stream>>>(query_bf, wq, q_b, nullptr, q_bf);
  k_gemm_kv<<<dim3(8, 8, 2), 256, 0, stream>>>(kv_ln, wk, wv_, k_b, v_b, k_buf, v_buf);
  k_attn_mfma<<<dim3(32, 64), 512, 0, stream>>>(q_bf, k_buf, v_buf, attn_bf);
  k_gemm_mfma<0, float><<<dim3(128, 8), 256, 0, stream>>>(attn_bf, wo, out_b, nullptr, out);
}

// Round 7
// 238.060 us; speedup vs baseline: 10.7221x; 1.0412x over previous
//
#include <hip/hip_runtime.h>
#include <hip/hip_bf16.h>
#include <cstdint>
#include <cstddef>

#define LL 4096
#define BB 4
#define DD 1024
#define HH 16
#define PP 256
#define HDD 64
#define LC 16
#define LCHUNK 256

constexpr float kScaling = 0.125f;   // HD^-0.5
constexpr float kEps = 1e-5f;

typedef __attribute__((ext_vector_type(8))) short bf16x8;   // 8 bf16 = 4 VGPR
typedef __attribute__((ext_vector_type(4))) short short4v;
typedef __attribute__((ext_vector_type(4))) float f32x4;

#define MFMA16(a, b, c) __builtin_amdgcn_mfma_f32_16x16x32_bf16((a), (b), (c), 0, 0, 0)

__device__ __forceinline__ unsigned short f2bf(float f) {
  unsigned int u = __builtin_bit_cast(unsigned int, f);
  u += 0x7FFFu + ((u >> 16) & 1u);           // round-to-nearest-even
  return (unsigned short)(u >> 16);
}

__device__ __forceinline__ void gll16(const void* g, void* l) {
  __builtin_amdgcn_global_load_lds(
      (const __attribute__((address_space(1))) unsigned int*)g,
      (__attribute__((address_space(3))) unsigned int*)l, 16, 0, 0);
}

// ---------------------------------------------------------------------------
// fp32 -> bf16 bulk convert; each thread does 8 elems.
// ---------------------------------------------------------------------------
__global__ __launch_bounds__(256) void k_cvt(const float* __restrict__ src,
                                             unsigned short* __restrict__ dst,
                                             int n8) {
  int i = blockIdx.x * 256 + threadIdx.x;
  if (i >= n8) return;
  const float4* s = (const float4*)(src + (size_t)i * 8);
  float4 a = s[0], b = s[1];
  bf16x8 o;
  o[0] = f2bf(a.x); o[1] = f2bf(a.y); o[2] = f2bf(a.z); o[3] = f2bf(a.w);
  o[4] = f2bf(b.x); o[5] = f2bf(b.y); o[6] = f2bf(b.z); o[7] = f2bf(b.w);
  *(bf16x8*)(dst + (size_t)i * 8) = o;
}

// ---------------------------------------------------------------------------
// Compress (MFMA): per (b,h,lc): over 4 tiles of LT=64 rows l:
//   GEMM1: S^T[l][p] = X[l][d] @ E[p][d]^T ; relu(scale*S) -> P_lds[p][l] (bf16)
//   GEMM2: kv[p][dd] += P[p][l] @ Xt[dd][l]^T      (fp32 partials to parts)
// ---------------------------------------------------------------------------
__global__ __launch_bounds__(256) void k_compress_mfma(
    const unsigned short* __restrict__ qbf, const unsigned short* __restrict__ ewbf,
    float* __restrict__ parts) {
  const int bh = blockIdx.x, lc = blockIdx.y;
  const int b = bh >> 4, h = bh & 15;
  const int tid = threadIdx.x, wv = tid >> 6, lane = tid & 63;
  const int fr = lane & 15, fg = lane >> 4;

  __shared__ __align__(16) char Xl[8192];    // [l][d] rows of 128B
  __shared__ __align__(16) char Xtl[8192];   // [d][l]
  __shared__ __align__(16) char Pl[32768];   // [p][l] rows of 128B

  bf16x8 ef[4][2];
#pragma unroll
  for (int pt = 0; pt < 4; ++pt)
#pragma unroll
    for (int kc = 0; kc < 2; ++kc)
      ef[pt][kc] = *(const bf16x8*)(ewbf +
          (size_t)((h * PP + wv * 64 + pt * 16 + fr) * HDD) + kc * 32 + fg * 8);

  f32x4 acc[4][4];
#pragma unroll
  for (int i = 0; i < 4; ++i)
#pragma unroll
    for (int j = 0; j < 4; ++j) acc[i][j] = (f32x4){0.f, 0.f, 0.f, 0.f};

  const int l0 = lc * LCHUNK;
  for (int t = 0; t < 4; ++t) {
    __syncthreads();
#pragma unroll
    for (int j = 0; j < 2; ++j) {
      int u = tid + j * 256;
      int l = u >> 3, c8 = u & 7;
      bf16x8 val = *(const bf16x8*)(qbf +
          ((size_t)(l0 + t * 64 + l) * BB + b) * DD + h * HDD + c8 * 8);
      *(bf16x8*)(Xl + l * 128 + ((c8 ^ (l & 7)) << 4)) = val;
#pragma unroll
      for (int i = 0; i < 8; ++i) {
        int dd = c8 * 8 + i;
        *(short*)(Xtl + dd * 128 + ((((l >> 3) ^ (dd & 7) ^ (dd >> 3)) & 7) << 4) +
                  ((l & 7) << 1)) = val[i];
      }
    }
    __syncthreads();
#pragma unroll
    for (int lt = 0; lt < 4; ++lt) {
      int rl = lt * 16 + fr;
      bf16x8 xa0 = *(const bf16x8*)(Xl + rl * 128 + (((0 + fg) ^ (rl & 7)) << 4));
      bf16x8 xa1 = *(const bf16x8*)(Xl + rl * 128 + (((4 + fg) ^ (rl & 7)) << 4));
#pragma unroll
      for (int pt = 0; pt < 4; ++pt) {
        f32x4 s = (f32x4){0.f, 0.f, 0.f, 0.f};
        s = MFMA16(xa0, ef[pt][0], s);
        s = MFMA16(xa1, ef[pt][1], s);
        short4v pk;
#pragma unroll
        for (int r = 0; r < 4; ++r)
          pk[r] = (short)f2bf(fmaxf(s[r] * kScaling, 0.f));
        int p = wv * 64 + pt * 16 + fr;
        int lbase = lt * 16 + fg * 4;
        int slot = lbase >> 3;
        *(short4v*)(Pl + p * 128 + ((slot ^ (p & 7)) << 4) + ((lbase & 7) << 1)) = pk;
      }
    }
    asm volatile("s_waitcnt lgkmcnt(0)" ::: "memory");
    __builtin_amdgcn_sched_barrier(0);
#pragma unroll
    for (int kc = 0; kc < 2; ++kc) {
      bf16x8 pa[4], xb[4];
#pragma unroll
      for (int pt = 0; pt < 4; ++pt) {
        int p = wv * 64 + pt * 16 + fr;
        pa[pt] = *(const bf16x8*)(Pl + p * 128 + (((kc * 4 + fg) ^ (p & 7)) << 4));
      }
#pragma unroll
      for (int dt = 0; dt < 4; ++dt) {
        int dd = dt * 16 + fr;
        xb[dt] = *(const bf16x8*)(Xtl + dd * 128 +
                  ((((kc * 4 + fg) ^ (dd & 7) ^ (dd >> 3)) & 7) << 4));
      }
#pragma unroll
      for (int pt = 0; pt < 4; ++pt)
#pragma unroll
        for (int dt = 0; dt < 4; ++dt)
          acc[pt][dt] = MFMA16(pa[pt], xb[dt], acc[pt][dt]);
    }
  }
  float* op = parts + (size_t)(lc * 64 + bh) * PP * HDD;
#pragma unroll
  for (int pt = 0; pt < 4; ++pt)
#pragma unroll
    for (int dt = 0; dt < 4; ++dt)
#pragma unroll
      for (int r = 0; r < 4; ++r) {
        int p = wv * 64 + pt * 16 + fg * 4 + r;
        int dd = dt * 16 + fr;
        op[(size_t)p * HDD + dd] = acc[pt][dt][r];
      }
}

// Sum LC partials -> kv_raw bf16 as (P,B,D)
__global__ __launch_bounds__(256) void k_reduce(const float* __restrict__ parts,
                                                unsigned short* __restrict__ kv_raw_bf) {
  int i = blockIdx.x * 256 + threadIdx.x;
  float s = 0.f;
#pragma unroll
  for (int lcc = 0; lcc < LC; ++lcc) s += parts[(size_t)lcc * (64 * PP * HDD) + i];
  int d = i & 63, p = (i >> 6) & 255, bh = i >> 14;
  int b = bh >> 4, h = bh & 15;
  kv_raw_bf[(size_t)(p * BB + b) * DD + h * HDD + d] = f2bf(s);
}

// ---------------------------------------------------------------------------
// 128x128 GEMM body (kept for the small P=1024-row GEMMs).
// ---------------------------------------------------------------------------
template <int MODE, typename OUTT>
__device__ __forceinline__ void gemm_body(
    const unsigned short* __restrict__ A, const unsigned short* __restrict__ W,
    const float* __restrict__ bias, const float* __restrict__ ew,
    OUTT* __restrict__ C, int m0, int n0, char* Al, char* Bl) {
  const int tid = threadIdx.x;
  const int wv = tid >> 6, lane = tid & 63;
  const int fr = lane & 15, fg = lane >> 4;
  const int wr = wv >> 1, wc = wv & 1;

  f32x4 acc[4][4];
#pragma unroll
  for (int i = 0; i < 4; ++i)
#pragma unroll
    for (int j = 0; j < 4; ++j) acc[i][j] = (f32x4){0.f, 0.f, 0.f, 0.f};

  for (int k0 = 0; k0 < DD; k0 += 64) {
    __syncthreads();
#pragma unroll
    for (int j = 0; j < 4; ++j) {
      int u = tid + j * 256;
      int row = u >> 3, slot = u & 7;
      size_t gcol = (size_t)(k0 + 8 * (slot ^ (row & 7)));
      gll16(A + (size_t)(m0 + row) * DD + gcol, Al + u * 16);
      gll16(W + (size_t)(n0 + row) * DD + gcol, Bl + u * 16);
    }
    __syncthreads();
#pragma unroll
    for (int kc = 0; kc < 2; ++kc) {
      bf16x8 af[4], bfr[4];
#pragma unroll
      for (int mt = 0; mt < 4; ++mt) {
        int r = wr * 64 + mt * 16 + fr;
        af[mt] = *(const bf16x8*)(Al + r * 128 + (((kc * 4 + fg) ^ (r & 7)) << 4));
      }
#pragma unroll
      for (int nt = 0; nt < 4; ++nt) {
        int r = wc * 64 + nt * 16 + fr;
        bfr[nt] = *(const bf16x8*)(Bl + r * 128 + (((kc * 4 + fg) ^ (r & 7)) << 4));
      }
#pragma unroll
      for (int mt = 0; mt < 4; ++mt)
#pragma unroll
        for (int nt = 0; nt < 4; ++nt)
          acc[mt][nt] = MFMA16(af[mt], bfr[nt], acc[mt][nt]);
    }
  }

  float bs[4];
#pragma unroll
  for (int nt = 0; nt < 4; ++nt) bs[nt] = bias[n0 + wc * 64 + nt * 16 + fr];
#pragma unroll
  for (int mt = 0; mt < 4; ++mt)
#pragma unroll
    for (int nt = 0; nt < 4; ++nt) {
      int n = n0 + wc * 64 + nt * 16 + fr;
#pragma unroll
      for (int r = 0; r < 4; ++r) {
        int m = m0 + wr * 64 + mt * 16 + fg * 4 + r;
        float v = acc[mt][nt][r] + bs[nt];
        if (MODE == 1) v *= kScaling;
        if (MODE == 2) {
          int p = m >> 2, hh = n >> 6, d2 = n & 63;
          v += ew[(size_t)((hh << 8) + p) * HDD + d2];
        }
        if constexpr (sizeof(OUTT) == 2)
          C[(size_t)m * DD + n] = (OUTT)f2bf(v);
        else
          C[(size_t)m * DD + n] = v;
      }
    }
}

template <int MODE, typename OUTT>
__global__ __launch_bounds__(256) void k_gemm_mfma(
    const unsigned short* __restrict__ A, const unsigned short* __restrict__ W,
    const float* __restrict__ bias, const float* __restrict__ ew,
    OUTT* __restrict__ C) {
  __shared__ __align__(16) char Al[16384];
  __shared__ __align__(16) char Bl[16384];
  gemm_body<MODE, OUTT>(A, W, bias, ew, C, blockIdx.x * 128, blockIdx.y * 128, Al, Bl);
}

// K and V projections in one launch (blockIdx.z selects).
__global__ __launch_bounds__(256) void k_gemm_kv(
    const unsigned short* __restrict__ A,
    const unsigned short* __restrict__ Wk, const unsigned short* __restrict__ Wv,
    const float* __restrict__ kb, const float* __restrict__ vb,
    unsigned short* __restrict__ Ck, unsigned short* __restrict__ Cv) {
  __shared__ __align__(16) char Al[16384];
  __shared__ __align__(16) char Bl[16384];
  if (blockIdx.z == 0)
    gemm_body<0, unsigned short>(A, Wk, kb, nullptr, Ck,
                                 blockIdx.x * 128, blockIdx.y * 128, Al, Bl);
  else
    gemm_body<0, unsigned short>(A, Wv, vb, nullptr, Cv,
                                 blockIdx.x * 128, blockIdx.y * 128, Al, Bl);
}

// ---------------------------------------------------------------------------
// 256x256 8-phase GEMM (T2+T3+T4+T5) for the M=16384 projections.
// 512 thr = 8 waves (2M x 4N); per-wave 128x64 out; BK=64 split in kc-halves.
// LDS 128KB: [buf2][A|B][kc2][256 rows][64B]. Raw s_barrier + counted vmcnt.
// Swizzle: 16B-slot ^= (row>>1)&3 (read = 2 lanes/bank = free); staging via
// inverse-swizzled global source, linear gll16 dest.
// Prefetch: ph1->t+1.Ac1, ph2->t+1.Bc1, ph3->t+2.Ac0, ph4->t+2.Bc0;
// vmcnt(4) once per K-tile (leaves t+2's 4 loads in flight).
// ---------------------------------------------------------------------------
template <int MODE, typename OUTT>
__global__ __launch_bounds__(512, 2) void k_gemm256(
    const unsigned short* __restrict__ A, const unsigned short* __restrict__ W,
    const float* __restrict__ bias, OUTT* __restrict__ C) {
  __shared__ __align__(16) char lds[131072];
  const int tid = threadIdx.x;
  const int wv = tid >> 6, lane = tid & 63;
  const int fr = lane & 15, fg = lane >> 4;
  const int wm = wv >> 2, wn = wv & 3;
  const int m0 = blockIdx.x * 256, n0 = blockIdx.y * 256;
  const int srow = tid >> 2, sslot = tid & 3;

  // stage one kc-half (16KB = 2 gll16/thread). colbase = absolute col of half.
  auto stageHalf = [&](const unsigned short* __restrict__ G, int g0, int colbase,
                       int dstBase) {
#pragma unroll
    for (int j = 0; j < 2; ++j) {
      int row = srow + j * 128;
      int gs = sslot ^ ((row >> 1) & 3);
      gll16(G + (size_t)(g0 + row) * DD + colbase + gs * 8,
            lds + dstBase + (tid + j * 512) * 16);
    }
  };
  auto rdA = [&](int mf, int kc, int cb) -> bf16x8 {
    int r = wm * 128 + mf * 16 + fr;
    return *(const bf16x8*)(lds + cb + kc * 16384 + r * 64 +
                            ((fg ^ ((r >> 1) & 3)) << 4));
  };
  auto rdB = [&](int nf, int kc, int cb) -> bf16x8 {
    int r = wn * 64 + nf * 16 + fr;
    return *(const bf16x8*)(lds + cb + 32768 + kc * 16384 + r * 64 +
                            ((fg ^ ((r >> 1) & 3)) << 4));
  };

  f32x4 acc[8][4];
#pragma unroll
  for (int i = 0; i < 8; ++i)
#pragma unroll
    for (int j = 0; j < 4; ++j) acc[i][j] = (f32x4){0.f, 0.f, 0.f, 0.f};
  bf16x8 a[4], b[4];

  // prologue: tile0 full (buf0) + tile1 kc0 halves (buf1) = 12 loads
  stageHalf(A, m0, 0, 0);
  stageHalf(W, n0, 0, 32768);
  stageHalf(A, m0, 32, 16384);
  stageHalf(W, n0, 32, 32768 + 16384);
  stageHalf(A, m0, 64, 65536);
  stageHalf(W, n0, 64, 65536 + 32768);
  asm volatile("s_waitcnt vmcnt(4)" ::: "memory");   // tile0 arrived
  __builtin_amdgcn_s_barrier();

  const int NT = DD / 64;   // 16
  for (int t = 0; t < NT; ++t) {
    const int cb = (t & 1) << 16;
    const int nb = cb ^ 65536;
    const int k1 = (t + 1) * 64, k2 = (t + 2) * 64;

    // ---- phase 1: mf 0-3, kc0 (also loads B kc0, kept through ph2)
#pragma unroll
    for (int i = 0; i < 4; ++i) a[i] = rdA(i, 0, cb);
#pragma unroll
    for (int i = 0; i < 4; ++i) b[i] = rdB(i, 0, cb);
    if (t + 1 < NT) stageHalf(A, m0, k1 + 32, nb + 16384);          // t+1.Ac1
    __builtin_amdgcn_s_barrier();
    asm volatile("s_waitcnt lgkmcnt(0)" ::: "memory");
    __builtin_amdgcn_sched_barrier(0);
    __builtin_amdgcn_s_setprio(1);
#pragma unroll
    for (int mf = 0; mf < 4; ++mf)
#pragma unroll
      for (int nf = 0; nf < 4; ++nf)
        acc[mf][nf] = MFMA16(a[mf], b[nf], acc[mf][nf]);
    __builtin_amdgcn_s_setprio(0);
    __builtin_amdgcn_s_barrier();

    // ---- phase 2: mf 4-7, kc0
#pragma unroll
    for (int i = 0; i < 4; ++i) a[i] = rdA(4 + i, 0, cb);
    if (t + 1 < NT) stageHalf(W, n0, k1 + 32, nb + 32768 + 16384);  // t+1.Bc1
    __builtin_amdgcn_s_barrier();
    asm volatile("s_waitcnt lgkmcnt(0)" ::: "memory");
    __builtin_amdgcn_sched_barrier(0);
    __builtin_amdgcn_s_setprio(1);
#pragma unroll
    for (int mf = 0; mf < 4; ++mf)
#pragma unroll
      for (int nf = 0; nf < 4; ++nf)
        acc[4 + mf][nf] = MFMA16(a[mf], b[nf], acc[4 + mf][nf]);
    __builtin_amdgcn_s_setprio(0);
    __builtin_amdgcn_s_barrier();

    // ---- phase 3: mf 0-3, kc1
#pragma unroll
    for (int i = 0; i < 4; ++i) a[i] = rdA(i, 1, cb);
#pragma unroll
    for (int i = 0; i < 4; ++i) b[i] = rdB(i, 1, cb);
    if (t + 2 < NT) stageHalf(A, m0, k2, cb);                       // t+2.Ac0
    __builtin_amdgcn_s_barrier();
    asm volatile("s_waitcnt lgkmcnt(0)" ::: "memory");
    __builtin_amdgcn_sched_barrier(0);
    __builtin_amdgcn_s_setprio(1);
#pragma unroll
    for (int mf = 0; mf < 4; ++mf)
#pragma unroll
      for (int nf = 0; nf < 4; ++nf)
        acc[mf][nf] = MFMA16(a[mf], b[nf], acc[mf][nf]);
    __builtin_amdgcn_s_setprio(0);
    __builtin_amdgcn_s_barrier();

    // ---- phase 4: mf 4-7, kc1
#pragma unroll
    for (int i = 0; i < 4; ++i) a[i] = rdA(4 + i, 1, cb);
    if (t + 2 < NT) stageHalf(W, n0, k2, cb + 32768);               // t+2.Bc0
    __builtin_amdgcn_s_barrier();
    asm volatile("s_waitcnt lgkmcnt(0)" ::: "memory");
    __builtin_amdgcn_sched_barrier(0);
    __builtin_amdgcn_s_setprio(1);
#pragma unroll
    for (int mf = 0; mf < 4; ++mf)
#pragma unroll
      for (int nf = 0; nf < 4; ++nf)
        acc[4 + mf][nf] = MFMA16(a[mf], b[nf], acc[4 + mf][nf]);
    __builtin_amdgcn_s_setprio(0);
    if (t + 2 < NT) {
      asm volatile("s_waitcnt vmcnt(4)" ::: "memory");   // t+1 fully arrived
    } else if (t + 1 < NT) {
      asm volatile("s_waitcnt vmcnt(0)" ::: "memory");   // drain for last tile
    }
    __builtin_amdgcn_s_barrier();
  }

  float bs[4];
#pragma unroll
  for (int nf = 0; nf < 4; ++nf) bs[nf] = bias[n0 + wn * 64 + nf * 16 + fr];
#pragma unroll
  for (int mf = 0; mf < 8; ++mf)
#pragma unroll
    for (int nf = 0; nf < 4; ++nf) {
      int n = n0 + wn * 64 + nf * 16 + fr;
#pragma unroll
      for (int r = 0; r < 4; ++r) {
        int m = m0 + wm * 128 + mf * 16 + fg * 4 + r;
        float v = acc[mf][nf][r] + bs[nf];
        if (MODE == 1) v *= kScaling;
        if constexpr (sizeof(OUTT) == 2)
          C[(size_t)m * DD + n] = (OUTT)f2bf(v);
        else
          C[(size_t)m * DD + n] = v;
      }
    }
}

// LayerNorm over D=1024; fp32 in -> bf16 out. One block per row.
__global__ __launch_bounds__(256) void k_ln(const float* __restrict__ x,
                                            const float* __restrict__ g,
                                            const float* __restrict__ bb,
                                            unsigned short* __restrict__ y) {
  const int r = blockIdx.x;
  const int tid = threadIdx.x;
  const float* xr = x + (size_t)r * DD;
  float4 v = *(const float4*)(xr + tid * 4);
  float s1 = v.x + v.y + v.z + v.w;
  float s2 = v.x * v.x + v.y * v.y + v.z * v.z + v.w * v.w;
#pragma unroll
  for (int off = 32; off > 0; off >>= 1) {
    s1 += __shfl_down(s1, off);
    s2 += __shfl_down(s2, off);
  }
  __shared__ float w1[4], w2[4];
  if ((tid & 63) == 0) { w1[tid >> 6] = s1; w2[tid >> 6] = s2; }
  __syncthreads();
  float S1 = w1[0] + w1[1] + w1[2] + w1[3];
  float S2 = w2[0] + w2[1] + w2[2] + w2[3];
  float mean = S1 * (1.f / DD);
  float var = S2 * (1.f / DD) - mean * mean;
  float rstd = rsqrtf(var + kEps);
  float4 gv = *(const float4*)(g + tid * 4);
  float4 bv = *(const float4*)(bb + tid * 4);
  short4v o;
  o[0] = (short)f2bf((v.x - mean) * rstd * gv.x + bv.x);
  o[1] = (short)f2bf((v.y - mean) * rstd * gv.y + bv.y);
  o[2] = (short)f2bf((v.z - mean) * rstd * gv.z + bv.z);
  o[3] = (short)f2bf((v.w - mean) * rstd * gv.w + bv.w);
  *(short4v*)(y + (size_t)r * DD + tid * 4) = o;
}

// ---------------------------------------------------------------------------
// Attention (MFMA, flash-style, no max-subtraction -- logits bounded ~|3|).
// Two KV halves of 128 p -> LDS 64KB -> 2 blocks/CU. 8 waves x 16 q-rows.
// ---------------------------------------------------------------------------
__global__ __launch_bounds__(512, 2) void k_attn_mfma(
    const unsigned short* __restrict__ qbf, const unsigned short* __restrict__ kbf,
    const unsigned short* __restrict__ vbf, unsigned short* __restrict__ attn) {
  const int bh = blockIdx.y;
  const int b = bh >> 4, h = bh & 15;
  const int tid = threadIdx.x, wv = tid >> 6, lane = tid & 63;
  const int fr = lane & 15, fg = lane >> 4;
  const int bl0 = blockIdx.x * 128;

  __shared__ __align__(16) char Kl[16384];    // [128p][64d] swz rows of 128B
  __shared__ __align__(16) char Vt[16384];    // 2 chunks of [64 dd][64 p]
  __shared__ __align__(16) char Pl[32768];    // 8 waves x [16 l][128 p] (256B rows)

  const size_t qrow = ((size_t)(bl0 + wv * 16 + fr) * BB + b) * DD + h * HDD;
  bf16x8 qf0 = *(const bf16x8*)(qbf + qrow + fg * 8);
  bf16x8 qf1 = *(const bf16x8*)(qbf + qrow + 32 + fg * 8);

  f32x4 o[4];
#pragma unroll
  for (int dt = 0; dt < 4; ++dt) o[dt] = (f32x4){0.f, 0.f, 0.f, 0.f};
  float psum = 0.f;
  char* Pw = Pl + wv * 4096;

  for (int ph = 0; ph < 2; ++ph) {
    __syncthreads();    // prev PV reads done; LDS safe to overwrite
#pragma unroll
    for (int j = 0; j < 2; ++j) {
      int u = tid + j * 512;
      int p = u >> 3, slot = u & 7;
      gll16(kbf + ((size_t)((ph * 128 + p) * BB + b)) * DD + h * HDD +
                8 * (slot ^ (p & 7)),
            Kl + u * 16);
    }
#pragma unroll
    for (int j = 0; j < 2; ++j) {
      int u = tid + j * 512;
      int p = u >> 3, c8 = u & 7;
      bf16x8 val = *(const bf16x8*)(vbf +
          ((size_t)((ph * 128 + p) * BB + b)) * DD + h * HDD + c8 * 8);
      int pc = p >> 6, pl = p & 63;
#pragma unroll
      for (int i = 0; i < 8; ++i) {
        int dd = c8 * 8 + i;
        *(short*)(Vt + pc * 8192 + dd * 128 +
                  ((((pl >> 3) ^ (dd & 7) ^ (dd >> 3)) & 7) << 4) +
                  ((pl & 7) << 1)) = val[i];
      }
    }
    __syncthreads();    // includes vmcnt(0) drain of gll16

    f32x4 s[8];
    __builtin_amdgcn_s_setprio(1);
#pragma unroll
    for (int pt = 0; pt < 8; ++pt) {
      int pr = pt * 16 + fr;
      bf16x8 a0 = *(const bf16x8*)(Kl + pr * 128 + ((fg ^ (pr & 7)) << 4));
      bf16x8 a1 = *(const bf16x8*)(Kl + pr * 128 + (((4 + fg) ^ (pr & 7)) << 4));
      f32x4 acc = (f32x4){0.f, 0.f, 0.f, 0.f};
      acc = MFMA16(a0, qf0, acc);
      acc = MFMA16(a1, qf1, acc);
      s[pt] = acc;
    }
    __builtin_amdgcn_s_setprio(0);

#pragma unroll
    for (int pt = 0; pt < 8; ++pt) {
      float e0 = __expf(s[pt][0]), e1 = __expf(s[pt][1]);
      float e2 = __expf(s[pt][2]), e3 = __expf(s[pt][3]);
      psum += (e0 + e1) + (e2 + e3);
      short4v pk;
      pk[0] = (short)f2bf(e0); pk[1] = (short)f2bf(e1);
      pk[2] = (short)f2bf(e2); pk[3] = (short)f2bf(e3);
      int pbyte = (pt * 16 + fg * 4) * 2;
      int slot = pbyte >> 4, rem = pbyte & 15;
      *(short4v*)(Pw + fr * 256 + ((slot ^ (fr & 7)) << 4) + rem) = pk;
    }
    asm volatile("s_waitcnt lgkmcnt(0)" ::: "memory");
    __builtin_amdgcn_sched_barrier(0);

    __builtin_amdgcn_s_setprio(1);
#pragma unroll
    for (int kc = 0; kc < 4; ++kc) {
      int slot = kc * 4 + fg;
      bf16x8 pa = *(const bf16x8*)(Pw + fr * 256 + ((slot ^ (fr & 7)) << 4));
      int sl2 = (kc & 1) * 4 + fg;
#pragma unroll
      for (int dt = 0; dt < 4; ++dt) {
        int dd = dt * 16 + fr;
        bf16x8 vb = *(const bf16x8*)(Vt + (kc >> 1) * 8192 + dd * 128 +
                     (((sl2 ^ (dd & 7) ^ (dd >> 3)) & 7) << 4));
        o[dt] = MFMA16(pa, vb, o[dt]);
      }
    }
    __builtin_amdgcn_s_setprio(0);
  }

  psum += __shfl_xor(psum, 16);
  psum += __shfl_xor(psum, 32);

#pragma unroll
  for (int r = 0; r < 4; ++r) {
    int lloc = fg * 4 + r;
    float inv = 1.f / __shfl(psum, lloc);
    unsigned short* op = attn +
        ((size_t)(bl0 + wv * 16 + lloc) * BB + b) * DD + h * HDD;
#pragma unroll
    for (int dt = 0; dt < 4; ++dt)
      op[dt * 16 + fr] = f2bf(o[dt][r] * inv);
  }
}

extern "C" void kernel_launch(void* const* d_in, const int* in_sizes, int n_in,
                              void* d_out, int out_size, void* d_ws, size_t ws_size,
                              hipStream_t stream) {
  const float* query   = (const float*)d_in[0];
  const float* q_w     = (const float*)d_in[1];
  const float* q_b     = (const float*)d_in[2];
  const float* k_w     = (const float*)d_in[3];
  const float* k_b     = (const float*)d_in[4];
  const float* v_w     = (const float*)d_in[5];
  const float* v_b     = (const float*)d_in[6];
  const float* e_weight= (const float*)d_in[7];
  const float* e_out_w = (const float*)d_in[8];
  const float* e_out_b = (const float*)d_in[9];
  const float* ln_g    = (const float*)d_in[10];
  const float* ln_b    = (const float*)d_in[11];
  const float* out_w   = (const float*)d_in[12];
  const float* out_b   = (const float*)d_in[13];
  float* out = (float*)d_out;

  char* w = (char*)d_ws;
  float* parts            = (float*)w;                          // 64 MB, dead after reduce
  unsigned short* q_bf    = (unsigned short*)w;                 // 32 MB (alias, after reduce)
  unsigned short* attn_bf = (unsigned short*)(w + (32u << 20)); // 32 MB (alias, after reduce)
  unsigned short* query_bf= (unsigned short*)(w + (64u << 20)); // 32 MB
  unsigned short* kv_raw  = (unsigned short*)(w + (96u << 20)); // 2 MB
  float* kv_eo            = (float*)(w + (98u << 20));          // 4 MB
  unsigned short* kv_ln   = (unsigned short*)(w + (102u << 20));// 2 MB
  unsigned short* k_buf   = (unsigned short*)(w + (104u << 20));// 2 MB
  unsigned short* v_buf   = (unsigned short*)(w + (106u << 20));// 2 MB
  unsigned short* wq  = (unsigned short*)(w + (108u << 20));
  unsigned short* wk  = (unsigned short*)(w + (110u << 20));
  unsigned short* wv_ = (unsigned short*)(w + (112u << 20));
  unsigned short* weo = (unsigned short*)(w + (114u << 20));
  unsigned short* wo  = (unsigned short*)(w + (116u << 20));
  unsigned short* ewb = (unsigned short*)(w + (118u << 20));    // 0.5 MB

  k_cvt<<<8192, 256, 0, stream>>>(query, query_bf, 2097152);
  k_cvt<<<512, 256, 0, stream>>>(q_w, wq, 131072);
  k_cvt<<<512, 256, 0, stream>>>(k_w, wk, 131072);
  k_cvt<<<512, 256, 0, stream>>>(v_w, wv_, 131072);
  k_cvt<<<512, 256, 0, stream>>>(e_out_w, weo, 131072);
  k_cvt<<<512, 256, 0, stream>>>(out_w, wo, 131072);
  k_cvt<<<128, 256, 0, stream>>>(e_weight, ewb, 32768);

  k_compress_mfma<<<dim3(64, LC), 256, 0, stream>>>(query_bf, ewb, parts);
  k_reduce<<<4096, 256, 0, stream>>>(parts, kv_raw);
  k_gemm_mfma<2, float><<<dim3(8, 8), 256, 0, stream>>>(kv_raw, weo, e_out_b, e_weight, kv_eo);
  k_ln<<<PP * BB, 256, 0, stream>>>(kv_eo, ln_g, ln_b, kv_ln);
  k_gemm256<1, unsigned short><<<dim3(64, 4), 512, 0, stream>>>(query_bf, wq, q_b, q_bf);
  k_gemm_kv<<<dim3(8, 8, 2), 256, 0, stream>>>(kv_ln, wk, wv_, k_b, v_b, k_buf, v_buf);
  k_attn_mfma<<<dim3(32, 64), 512, 0, stream>>>(q_bf, k_buf, v_buf, attn_bf);
  k_gemm256<0, float><<<dim3(64, 4), 512, 0, stream>>>(attn_bf, wo, out_b, out);
}

// Round 8
// 222.341 us; speedup vs baseline: 11.4801x; 1.0707x over previous
//
#include <hip/hip_runtime.h>
#include <hip/hip_bf16.h>
#include <cstdint>
#include <cstddef>

#define LL 4096
#define BB 4
#define DD 1024
#define HH 16
#define PP 256
#define HDD 64
#define LC 16
#define LCHUNK 256

constexpr float kScaling = 0.125f;   // HD^-0.5
constexpr float kEps = 1e-5f;

typedef __attribute__((ext_vector_type(8))) short bf16x8;   // 8 bf16 = 4 VGPR
typedef __attribute__((ext_vector_type(4))) short short4v;
typedef __attribute__((ext_vector_type(4))) float f32x4;

#define MFMA16(a, b, c) __builtin_amdgcn_mfma_f32_16x16x32_bf16((a), (b), (c), 0, 0, 0)

__device__ __forceinline__ unsigned short f2bf(float f) {
  unsigned int u = __builtin_bit_cast(unsigned int, f);
  u += 0x7FFFu + ((u >> 16) & 1u);           // round-to-nearest-even
  return (unsigned short)(u >> 16);
}
__device__ __forceinline__ float bf2f(unsigned short u) {
  return __builtin_bit_cast(float, ((unsigned int)u) << 16);
}

__device__ __forceinline__ void gll16(const void* g, void* l) {
  __builtin_amdgcn_global_load_lds(
      (const __attribute__((address_space(1))) unsigned int*)g,
      (__attribute__((address_space(3))) unsigned int*)l, 16, 0, 0);
}

// ---------------------------------------------------------------------------
// Merged fp32 -> bf16 convert for query + 5 weights + e_weight (one launch).
// Segments (8-elem units): query 2097152 | 5 x 131072 | e_weight 32768.
// ---------------------------------------------------------------------------
__global__ __launch_bounds__(256) void k_cvt_all(
    const float* __restrict__ q,
    const float* __restrict__ w0, const float* __restrict__ w1,
    const float* __restrict__ w2, const float* __restrict__ w3,
    const float* __restrict__ w4, const float* __restrict__ w5,
    unsigned short* __restrict__ dq,
    unsigned short* __restrict__ d0, unsigned short* __restrict__ d1,
    unsigned short* __restrict__ d2, unsigned short* __restrict__ d3,
    unsigned short* __restrict__ d4, unsigned short* __restrict__ d5) {
  int i = blockIdx.x * 256 + threadIdx.x;
  const float* src; unsigned short* dst; int off;
  if (i < 2097152) { src = q; dst = dq; off = i; }
  else {
    int j = i - 2097152; int w = j >> 17; off = j & 131071;
    if (w == 0) { src = w0; dst = d0; }
    else if (w == 1) { src = w1; dst = d1; }
    else if (w == 2) { src = w2; dst = d2; }
    else if (w == 3) { src = w3; dst = d3; }
    else if (w == 4) { src = w4; dst = d4; }
    else { if (off >= 32768) return; src = w5; dst = d5; }
  }
  const float4* s = (const float4*)(src + (size_t)off * 8);
  float4 a = s[0], b = s[1];
  bf16x8 o;
  o[0] = f2bf(a.x); o[1] = f2bf(a.y); o[2] = f2bf(a.z); o[3] = f2bf(a.w);
  o[4] = f2bf(b.x); o[5] = f2bf(b.y); o[6] = f2bf(b.z); o[7] = f2bf(b.w);
  *(bf16x8*)(dst + (size_t)off * 8) = o;
}

// ---------------------------------------------------------------------------
// Compress (MFMA): bf16 partials now (halves parts HBM traffic).
// ---------------------------------------------------------------------------
__global__ __launch_bounds__(256) void k_compress_mfma(
    const unsigned short* __restrict__ qbf, const unsigned short* __restrict__ ewbf,
    unsigned short* __restrict__ parts) {
  const int bh = blockIdx.x, lc = blockIdx.y;
  const int b = bh >> 4, h = bh & 15;
  const int tid = threadIdx.x, wv = tid >> 6, lane = tid & 63;
  const int fr = lane & 15, fg = lane >> 4;

  __shared__ __align__(16) char Xl[8192];    // [l][d] rows of 128B
  __shared__ __align__(16) char Xtl[8192];   // [d][l]
  __shared__ __align__(16) char Pl[32768];   // [p][l] rows of 128B

  bf16x8 ef[4][2];
#pragma unroll
  for (int pt = 0; pt < 4; ++pt)
#pragma unroll
    for (int kc = 0; kc < 2; ++kc)
      ef[pt][kc] = *(const bf16x8*)(ewbf +
          (size_t)((h * PP + wv * 64 + pt * 16 + fr) * HDD) + kc * 32 + fg * 8);

  f32x4 acc[4][4];
#pragma unroll
  for (int i = 0; i < 4; ++i)
#pragma unroll
    for (int j = 0; j < 4; ++j) acc[i][j] = (f32x4){0.f, 0.f, 0.f, 0.f};

  const int l0 = lc * LCHUNK;
  for (int t = 0; t < 4; ++t) {
    __syncthreads();
#pragma unroll
    for (int j = 0; j < 2; ++j) {
      int u = tid + j * 256;
      int l = u >> 3, c8 = u & 7;
      bf16x8 val = *(const bf16x8*)(qbf +
          ((size_t)(l0 + t * 64 + l) * BB + b) * DD + h * HDD + c8 * 8);
      *(bf16x8*)(Xl + l * 128 + ((c8 ^ (l & 7)) << 4)) = val;
#pragma unroll
      for (int i = 0; i < 8; ++i) {
        int dd = c8 * 8 + i;
        *(short*)(Xtl + dd * 128 + ((((l >> 3) ^ (dd & 7) ^ (dd >> 3)) & 7) << 4) +
                  ((l & 7) << 1)) = val[i];
      }
    }
    __syncthreads();
#pragma unroll
    for (int lt = 0; lt < 4; ++lt) {
      int rl = lt * 16 + fr;
      bf16x8 xa0 = *(const bf16x8*)(Xl + rl * 128 + (((0 + fg) ^ (rl & 7)) << 4));
      bf16x8 xa1 = *(const bf16x8*)(Xl + rl * 128 + (((4 + fg) ^ (rl & 7)) << 4));
#pragma unroll
      for (int pt = 0; pt < 4; ++pt) {
        f32x4 s = (f32x4){0.f, 0.f, 0.f, 0.f};
        s = MFMA16(xa0, ef[pt][0], s);
        s = MFMA16(xa1, ef[pt][1], s);
        short4v pk;
#pragma unroll
        for (int r = 0; r < 4; ++r)
          pk[r] = (short)f2bf(fmaxf(s[r] * kScaling, 0.f));
        int p = wv * 64 + pt * 16 + fr;
        int lbase = lt * 16 + fg * 4;
        int slot = lbase >> 3;
        *(short4v*)(Pl + p * 128 + ((slot ^ (p & 7)) << 4) + ((lbase & 7) << 1)) = pk;
      }
    }
    asm volatile("s_waitcnt lgkmcnt(0)" ::: "memory");
    __builtin_amdgcn_sched_barrier(0);
#pragma unroll
    for (int kc = 0; kc < 2; ++kc) {
      bf16x8 pa[4], xb[4];
#pragma unroll
      for (int pt = 0; pt < 4; ++pt) {
        int p = wv * 64 + pt * 16 + fr;
        pa[pt] = *(const bf16x8*)(Pl + p * 128 + (((kc * 4 + fg) ^ (p & 7)) << 4));
      }
#pragma unroll
      for (int dt = 0; dt < 4; ++dt) {
        int dd = dt * 16 + fr;
        xb[dt] = *(const bf16x8*)(Xtl + dd * 128 +
                  ((((kc * 4 + fg) ^ (dd & 7) ^ (dd >> 3)) & 7) << 4));
      }
#pragma unroll
      for (int pt = 0; pt < 4; ++pt)
#pragma unroll
        for (int dt = 0; dt < 4; ++dt)
          acc[pt][dt] = MFMA16(pa[pt], xb[dt], acc[pt][dt]);
    }
  }
  unsigned short* op = parts + (size_t)(lc * 64 + bh) * PP * HDD;
#pragma unroll
  for (int pt = 0; pt < 4; ++pt)
#pragma unroll
    for (int dt = 0; dt < 4; ++dt)
#pragma unroll
      for (int r = 0; r < 4; ++r) {
        int p = wv * 64 + pt * 16 + fg * 4 + r;
        int dd = dt * 16 + fr;
        op[(size_t)p * HDD + dd] = f2bf(acc[pt][dt][r]);
      }
}

// Sum LC bf16 partials -> kv_raw bf16 as (P,B,D)
__global__ __launch_bounds__(256) void k_reduce(const unsigned short* __restrict__ parts,
                                                unsigned short* __restrict__ kv_raw_bf) {
  int i = blockIdx.x * 256 + threadIdx.x;
  float s = 0.f;
#pragma unroll
  for (int lcc = 0; lcc < LC; ++lcc) s += bf2f(parts[(size_t)lcc * (64 * PP * HDD) + i]);
  int d = i & 63, p = (i >> 6) & 255, bh = i >> 14;
  int b = bh >> 4, h = bh & 15;
  kv_raw_bf[(size_t)(p * BB + b) * DD + h * HDD + d] = f2bf(s);
}

// ---------------------------------------------------------------------------
// 128x128 GEMM body (kept for the small P=1024-row GEMMs).
// ---------------------------------------------------------------------------
template <int MODE, typename OUTT>
__device__ __forceinline__ void gemm_body(
    const unsigned short* __restrict__ A, const unsigned short* __restrict__ W,
    const float* __restrict__ bias, const float* __restrict__ ew,
    OUTT* __restrict__ C, int m0, int n0, char* Al, char* Bl) {
  const int tid = threadIdx.x;
  const int wv = tid >> 6, lane = tid & 63;
  const int fr = lane & 15, fg = lane >> 4;
  const int wr = wv >> 1, wc = wv & 1;

  f32x4 acc[4][4];
#pragma unroll
  for (int i = 0; i < 4; ++i)
#pragma unroll
    for (int j = 0; j < 4; ++j) acc[i][j] = (f32x4){0.f, 0.f, 0.f, 0.f};

  for (int k0 = 0; k0 < DD; k0 += 64) {
    __syncthreads();
#pragma unroll
    for (int j = 0; j < 4; ++j) {
      int u = tid + j * 256;
      int row = u >> 3, slot = u & 7;
      size_t gcol = (size_t)(k0 + 8 * (slot ^ (row & 7)));
      gll16(A + (size_t)(m0 + row) * DD + gcol, Al + u * 16);
      gll16(W + (size_t)(n0 + row) * DD + gcol, Bl + u * 16);
    }
    __syncthreads();
#pragma unroll
    for (int kc = 0; kc < 2; ++kc) {
      bf16x8 af[4], bfr[4];
#pragma unroll
      for (int mt = 0; mt < 4; ++mt) {
        int r = wr * 64 + mt * 16 + fr;
        af[mt] = *(const bf16x8*)(Al + r * 128 + (((kc * 4 + fg) ^ (r & 7)) << 4));
      }
#pragma unroll
      for (int nt = 0; nt < 4; ++nt) {
        int r = wc * 64 + nt * 16 + fr;
        bfr[nt] = *(const bf16x8*)(Bl + r * 128 + (((kc * 4 + fg) ^ (r & 7)) << 4));
      }
#pragma unroll
      for (int mt = 0; mt < 4; ++mt)
#pragma unroll
        for (int nt = 0; nt < 4; ++nt)
          acc[mt][nt] = MFMA16(af[mt], bfr[nt], acc[mt][nt]);
    }
  }

  float bs[4];
#pragma unroll
  for (int nt = 0; nt < 4; ++nt) bs[nt] = bias[n0 + wc * 64 + nt * 16 + fr];
#pragma unroll
  for (int mt = 0; mt < 4; ++mt)
#pragma unroll
    for (int nt = 0; nt < 4; ++nt) {
      int n = n0 + wc * 64 + nt * 16 + fr;
#pragma unroll
      for (int r = 0; r < 4; ++r) {
        int m = m0 + wr * 64 + mt * 16 + fg * 4 + r;
        float v = acc[mt][nt][r] + bs[nt];
        if (MODE == 1) v *= kScaling;
        if (MODE == 2) {
          int p = m >> 2, hh = n >> 6, d2 = n & 63;
          v += ew[(size_t)((hh << 8) + p) * HDD + d2];
        }
        if constexpr (sizeof(OUTT) == 2)
          C[(size_t)m * DD + n] = (OUTT)f2bf(v);
        else
          C[(size_t)m * DD + n] = v;
      }
    }
}

template <int MODE, typename OUTT>
__global__ __launch_bounds__(256) void k_gemm_mfma(
    const unsigned short* __restrict__ A, const unsigned short* __restrict__ W,
    const float* __restrict__ bias, const float* __restrict__ ew,
    OUTT* __restrict__ C) {
  __shared__ __align__(16) char Al[16384];
  __shared__ __align__(16) char Bl[16384];
  gemm_body<MODE, OUTT>(A, W, bias, ew, C, blockIdx.x * 128, blockIdx.y * 128, Al, Bl);
}

// K and V projections in one launch (blockIdx.z selects).
__global__ __launch_bounds__(256) void k_gemm_kv(
    const unsigned short* __restrict__ A,
    const unsigned short* __restrict__ Wk, const unsigned short* __restrict__ Wv,
    const float* __restrict__ kb, const float* __restrict__ vb,
    unsigned short* __restrict__ Ck, unsigned short* __restrict__ Cv) {
  __shared__ __align__(16) char Al[16384];
  __shared__ __align__(16) char Bl[16384];
  if (blockIdx.z == 0)
    gemm_body<0, unsigned short>(A, Wk, kb, nullptr, Ck,
                                 blockIdx.x * 128, blockIdx.y * 128, Al, Bl);
  else
    gemm_body<0, unsigned short>(A, Wv, vb, nullptr, Cv,
                                 blockIdx.x * 128, blockIdx.y * 128, Al, Bl);
}

// ---------------------------------------------------------------------------
// 256x256 8-phase GEMM (unchanged from round 7).
// ---------------------------------------------------------------------------
template <int MODE, typename OUTT>
__global__ __launch_bounds__(512, 2) void k_gemm256(
    const unsigned short* __restrict__ A, const unsigned short* __restrict__ W,
    const float* __restrict__ bias, OUTT* __restrict__ C) {
  __shared__ __align__(16) char lds[131072];
  const int tid = threadIdx.x;
  const int wv = tid >> 6, lane = tid & 63;
  const int fr = lane & 15, fg = lane >> 4;
  const int wm = wv >> 2, wn = wv & 3;
  const int m0 = blockIdx.x * 256, n0 = blockIdx.y * 256;
  const int srow = tid >> 2, sslot = tid & 3;

  auto stageHalf = [&](const unsigned short* __restrict__ G, int g0, int colbase,
                       int dstBase) {
#pragma unroll
    for (int j = 0; j < 2; ++j) {
      int row = srow + j * 128;
      int gs = sslot ^ ((row >> 1) & 3);
      gll16(G + (size_t)(g0 + row) * DD + colbase + gs * 8,
            lds + dstBase + (tid + j * 512) * 16);
    }
  };
  auto rdA = [&](int mf, int kc, int cb) -> bf16x8 {
    int r = wm * 128 + mf * 16 + fr;
    return *(const bf16x8*)(lds + cb + kc * 16384 + r * 64 +
                            ((fg ^ ((r >> 1) & 3)) << 4));
  };
  auto rdB = [&](int nf, int kc, int cb) -> bf16x8 {
    int r = wn * 64 + nf * 16 + fr;
    return *(const bf16x8*)(lds + cb + 32768 + kc * 16384 + r * 64 +
                            ((fg ^ ((r >> 1) & 3)) << 4));
  };

  f32x4 acc[8][4];
#pragma unroll
  for (int i = 0; i < 8; ++i)
#pragma unroll
    for (int j = 0; j < 4; ++j) acc[i][j] = (f32x4){0.f, 0.f, 0.f, 0.f};
  bf16x8 a[4], b[4];

  stageHalf(A, m0, 0, 0);
  stageHalf(W, n0, 0, 32768);
  stageHalf(A, m0, 32, 16384);
  stageHalf(W, n0, 32, 32768 + 16384);
  stageHalf(A, m0, 64, 65536);
  stageHalf(W, n0, 64, 65536 + 32768);
  asm volatile("s_waitcnt vmcnt(4)" ::: "memory");
  __builtin_amdgcn_s_barrier();

  const int NT = DD / 64;   // 16
  for (int t = 0; t < NT; ++t) {
    const int cb = (t & 1) << 16;
    const int nb = cb ^ 65536;
    const int k1 = (t + 1) * 64, k2 = (t + 2) * 64;

#pragma unroll
    for (int i = 0; i < 4; ++i) a[i] = rdA(i, 0, cb);
#pragma unroll
    for (int i = 0; i < 4; ++i) b[i] = rdB(i, 0, cb);
    if (t + 1 < NT) stageHalf(A, m0, k1 + 32, nb + 16384);
    __builtin_amdgcn_s_barrier();
    asm volatile("s_waitcnt lgkmcnt(0)" ::: "memory");
    __builtin_amdgcn_sched_barrier(0);
    __builtin_amdgcn_s_setprio(1);
#pragma unroll
    for (int mf = 0; mf < 4; ++mf)
#pragma unroll
      for (int nf = 0; nf < 4; ++nf)
        acc[mf][nf] = MFMA16(a[mf], b[nf], acc[mf][nf]);
    __builtin_amdgcn_s_setprio(0);
    __builtin_amdgcn_s_barrier();

#pragma unroll
    for (int i = 0; i < 4; ++i) a[i] = rdA(4 + i, 0, cb);
    if (t + 1 < NT) stageHalf(W, n0, k1 + 32, nb + 32768 + 16384);
    __builtin_amdgcn_s_barrier();
    asm volatile("s_waitcnt lgkmcnt(0)" ::: "memory");
    __builtin_amdgcn_sched_barrier(0);
    __builtin_amdgcn_s_setprio(1);
#pragma unroll
    for (int mf = 0; mf < 4; ++mf)
#pragma unroll
      for (int nf = 0; nf < 4; ++nf)
        acc[4 + mf][nf] = MFMA16(a[mf], b[nf], acc[4 + mf][nf]);
    __builtin_amdgcn_s_setprio(0);
    __builtin_amdgcn_s_barrier();

#pragma unroll
    for (int i = 0; i < 4; ++i) a[i] = rdA(i, 1, cb);
#pragma unroll
    for (int i = 0; i < 4; ++i) b[i] = rdB(i, 1, cb);
    if (t + 2 < NT) stageHalf(A, m0, k2, cb);
    __builtin_amdgcn_s_barrier();
    asm volatile("s_waitcnt lgkmcnt(0)" ::: "memory");
    __builtin_amdgcn_sched_barrier(0);
    __builtin_amdgcn_s_setprio(1);
#pragma unroll
    for (int mf = 0; mf < 4; ++mf)
#pragma unroll
      for (int nf = 0; nf < 4; ++nf)
        acc[mf][nf] = MFMA16(a[mf], b[nf], acc[mf][nf]);
    __builtin_amdgcn_s_setprio(0);
    __builtin_amdgcn_s_barrier();

#pragma unroll
    for (int i = 0; i < 4; ++i) a[i] = rdA(4 + i, 1, cb);
    if (t + 2 < NT) stageHalf(W, n0, k2, cb + 32768);
    __builtin_amdgcn_s_barrier();
    asm volatile("s_waitcnt lgkmcnt(0)" ::: "memory");
    __builtin_amdgcn_sched_barrier(0);
    __builtin_amdgcn_s_setprio(1);
#pragma unroll
    for (int mf = 0; mf < 4; ++mf)
#pragma unroll
      for (int nf = 0; nf < 4; ++nf)
        acc[4 + mf][nf] = MFMA16(a[mf], b[nf], acc[4 + mf][nf]);
    __builtin_amdgcn_s_setprio(0);
    if (t + 2 < NT) {
      asm volatile("s_waitcnt vmcnt(4)" ::: "memory");
    } else if (t + 1 < NT) {
      asm volatile("s_waitcnt vmcnt(0)" ::: "memory");
    }
    __builtin_amdgcn_s_barrier();
  }

  float bs[4];
#pragma unroll
  for (int nf = 0; nf < 4; ++nf) bs[nf] = bias[n0 + wn * 64 + nf * 16 + fr];
#pragma unroll
  for (int mf = 0; mf < 8; ++mf)
#pragma unroll
    for (int nf = 0; nf < 4; ++nf) {
      int n = n0 + wn * 64 + nf * 16 + fr;
#pragma unroll
      for (int r = 0; r < 4; ++r) {
        int m = m0 + wm * 128 + mf * 16 + fg * 4 + r;
        float v = acc[mf][nf][r] + bs[nf];
        if (MODE == 1) v *= kScaling;
        if constexpr (sizeof(OUTT) == 2)
          C[(size_t)m * DD + n] = (OUTT)f2bf(v);
        else
          C[(size_t)m * DD + n] = v;
      }
    }
}

// LayerNorm over D=1024; fp32 in -> bf16 out. One block per row.
__global__ __launch_bounds__(256) void k_ln(const float* __restrict__ x,
                                            const float* __restrict__ g,
                                            const float* __restrict__ bb,
                                            unsigned short* __restrict__ y) {
  const int r = blockIdx.x;
  const int tid = threadIdx.x;
  const float* xr = x + (size_t)r * DD;
  float4 v = *(const float4*)(xr + tid * 4);
  float s1 = v.x + v.y + v.z + v.w;
  float s2 = v.x * v.x + v.y * v.y + v.z * v.z + v.w * v.w;
#pragma unroll
  for (int off = 32; off > 0; off >>= 1) {
    s1 += __shfl_down(s1, off);
    s2 += __shfl_down(s2, off);
  }
  __shared__ float w1[4], w2[4];
  if ((tid & 63) == 0) { w1[tid >> 6] = s1; w2[tid >> 6] = s2; }
  __syncthreads();
  float S1 = w1[0] + w1[1] + w1[2] + w1[3];
  float S2 = w2[0] + w2[1] + w2[2] + w2[3];
  float mean = S1 * (1.f / DD);
  float var = S2 * (1.f / DD) - mean * mean;
  float rstd = rsqrtf(var + kEps);
  float4 gv = *(const float4*)(g + tid * 4);
  float4 bv = *(const float4*)(bb + tid * 4);
  short4v o;
  o[0] = (short)f2bf((v.x - mean) * rstd * gv.x + bv.x);
  o[1] = (short)f2bf((v.y - mean) * rstd * gv.y + bv.y);
  o[2] = (short)f2bf((v.z - mean) * rstd * gv.z + bv.z);
  o[3] = (short)f2bf((v.w - mean) * rstd * gv.w + bv.w);
  *(short4v*)(y + (size_t)r * DD + tid * 4) = o;
}

// ---------------------------------------------------------------------------
// Attention: QBLK=256 (two q-chunks of 128 reuse each staged K/V half).
// Staging work per (b,h) halves vs round 7. LDS 64KB -> 2 blocks/CU.
// ---------------------------------------------------------------------------
__global__ __launch_bounds__(512, 2) void k_attn_mfma(
    const unsigned short* __restrict__ qbf, const unsigned short* __restrict__ kbf,
    const unsigned short* __restrict__ vbf, unsigned short* __restrict__ attn) {
  const int bh = blockIdx.y;
  const int b = bh >> 4, h = bh & 15;
  const int tid = threadIdx.x, wv = tid >> 6, lane = tid & 63;
  const int fr = lane & 15, fg = lane >> 4;
  const int bl0 = blockIdx.x * 256;

  __shared__ __align__(16) char Kl[16384];    // [128p][64d] swz rows of 128B
  __shared__ __align__(16) char Vt[16384];    // 2 chunks of [64 dd][64 p]
  __shared__ __align__(16) char Pl[32768];    // 8 waves x [16 l][128 p]

  // q fragments for both 128-row chunks
  bf16x8 qf[2][2];
#pragma unroll
  for (int ql = 0; ql < 2; ++ql) {
    const size_t qrow = ((size_t)(bl0 + ql * 128 + wv * 16 + fr) * BB + b) * DD + h * HDD;
    qf[ql][0] = *(const bf16x8*)(qbf + qrow + fg * 8);
    qf[ql][1] = *(const bf16x8*)(qbf + qrow + 32 + fg * 8);
  }

  f32x4 o[2][4];
#pragma unroll
  for (int ql = 0; ql < 2; ++ql)
#pragma unroll
    for (int dt = 0; dt < 4; ++dt) o[ql][dt] = (f32x4){0.f, 0.f, 0.f, 0.f};
  float psum[2] = {0.f, 0.f};
  char* Pw = Pl + wv * 4096;

  for (int ph = 0; ph < 2; ++ph) {
    __syncthreads();    // prev PV reads done; LDS safe to overwrite
#pragma unroll
    for (int j = 0; j < 2; ++j) {
      int u = tid + j * 512;
      int p = u >> 3, slot = u & 7;
      gll16(kbf + ((size_t)((ph * 128 + p) * BB + b)) * DD + h * HDD +
                8 * (slot ^ (p & 7)),
            Kl + u * 16);
    }
#pragma unroll
    for (int j = 0; j < 2; ++j) {
      int u = tid + j * 512;
      int p = u >> 3, c8 = u & 7;
      bf16x8 val = *(const bf16x8*)(vbf +
          ((size_t)((ph * 128 + p) * BB + b)) * DD + h * HDD + c8 * 8);
      int pc = p >> 6, pl = p & 63;
#pragma unroll
      for (int i = 0; i < 8; ++i) {
        int dd = c8 * 8 + i;
        *(short*)(Vt + pc * 8192 + dd * 128 +
                  ((((pl >> 3) ^ (dd & 7) ^ (dd >> 3)) & 7) << 4) +
                  ((pl & 7) << 1)) = val[i];
      }
    }
    __syncthreads();    // includes vmcnt(0) drain of gll16

#pragma unroll
    for (int ql = 0; ql < 2; ++ql) {
      // S^T = K @ Q^T : 8 p-tiles this half
      f32x4 s[8];
      __builtin_amdgcn_s_setprio(1);
#pragma unroll
      for (int pt = 0; pt < 8; ++pt) {
        int pr = pt * 16 + fr;
        bf16x8 a0 = *(const bf16x8*)(Kl + pr * 128 + ((fg ^ (pr & 7)) << 4));
        bf16x8 a1 = *(const bf16x8*)(Kl + pr * 128 + (((4 + fg) ^ (pr & 7)) << 4));
        f32x4 acc = (f32x4){0.f, 0.f, 0.f, 0.f};
        acc = MFMA16(a0, qf[ql][0], acc);
        acc = MFMA16(a1, qf[ql][1], acc);
        s[pt] = acc;
      }
      __builtin_amdgcn_s_setprio(0);

      // ensure prior PV reads of this wave's P region retired before overwrite
      asm volatile("s_waitcnt lgkmcnt(0)" ::: "memory");
      __builtin_amdgcn_sched_barrier(0);
#pragma unroll
      for (int pt = 0; pt < 8; ++pt) {
        float e0 = __expf(s[pt][0]), e1 = __expf(s[pt][1]);
        float e2 = __expf(s[pt][2]), e3 = __expf(s[pt][3]);
        psum[ql] += (e0 + e1) + (e2 + e3);
        short4v pk;
        pk[0] = (short)f2bf(e0); pk[1] = (short)f2bf(e1);
        pk[2] = (short)f2bf(e2); pk[3] = (short)f2bf(e3);
        int pbyte = (pt * 16 + fg * 4) * 2;
        int slot = pbyte >> 4, rem = pbyte & 15;
        *(short4v*)(Pw + fr * 256 + ((slot ^ (fr & 7)) << 4) + rem) = pk;
      }
      asm volatile("s_waitcnt lgkmcnt(0)" ::: "memory");
      __builtin_amdgcn_sched_barrier(0);

      __builtin_amdgcn_s_setprio(1);
#pragma unroll
      for (int kc = 0; kc < 4; ++kc) {
        int slot = kc * 4 + fg;
        bf16x8 pa = *(const bf16x8*)(Pw + fr * 256 + ((slot ^ (fr & 7)) << 4));
        int sl2 = (kc & 1) * 4 + fg;
#pragma unroll
        for (int dt = 0; dt < 4; ++dt) {
          int dd = dt * 16 + fr;
          bf16x8 vb = *(const bf16x8*)(Vt + (kc >> 1) * 8192 + dd * 128 +
                       (((sl2 ^ (dd & 7) ^ (dd >> 3)) & 7) << 4));
          o[ql][dt] = MFMA16(pa, vb, o[ql][dt]);
        }
      }
      __builtin_amdgcn_s_setprio(0);
    }
  }

#pragma unroll
  for (int ql = 0; ql < 2; ++ql) {
    float ps = psum[ql];
    ps += __shfl_xor(ps, 16);
    ps += __shfl_xor(ps, 32);
#pragma unroll
    for (int r = 0; r < 4; ++r) {
      int lloc = fg * 4 + r;
      float inv = 1.f / __shfl(ps, lloc);
      unsigned short* op = attn +
          ((size_t)(bl0 + ql * 128 + wv * 16 + lloc) * BB + b) * DD + h * HDD;
#pragma unroll
      for (int dt = 0; dt < 4; ++dt)
        op[dt * 16 + fr] = f2bf(o[ql][dt][r] * inv);
    }
  }
}

extern "C" void kernel_launch(void* const* d_in, const int* in_sizes, int n_in,
                              void* d_out, int out_size, void* d_ws, size_t ws_size,
                              hipStream_t stream) {
  const float* query   = (const float*)d_in[0];
  const float* q_w     = (const float*)d_in[1];
  const float* q_b     = (const float*)d_in[2];
  const float* k_w     = (const float*)d_in[3];
  const float* k_b     = (const float*)d_in[4];
  const float* v_w     = (const float*)d_in[5];
  const float* v_b     = (const float*)d_in[6];
  const float* e_weight= (const float*)d_in[7];
  const float* e_out_w = (const float*)d_in[8];
  const float* e_out_b = (const float*)d_in[9];
  const float* ln_g    = (const float*)d_in[10];
  const float* ln_b    = (const float*)d_in[11];
  const float* out_w   = (const float*)d_in[12];
  const float* out_b   = (const float*)d_in[13];
  float* out = (float*)d_out;

  char* w = (char*)d_ws;
  unsigned short* parts   = (unsigned short*)w;                 // 32 MB, dead after reduce
  unsigned short* q_bf    = (unsigned short*)w;                 // 32 MB (alias, after reduce)
  unsigned short* attn_bf = (unsigned short*)(w + (32u << 20)); // 32 MB
  unsigned short* query_bf= (unsigned short*)(w + (64u << 20)); // 32 MB
  unsigned short* kv_raw  = (unsigned short*)(w + (96u << 20)); // 2 MB
  float* kv_eo            = (float*)(w + (98u << 20));          // 4 MB
  unsigned short* kv_ln   = (unsigned short*)(w + (102u << 20));// 2 MB
  unsigned short* k_buf   = (unsigned short*)(w + (104u << 20));// 2 MB
  unsigned short* v_buf   = (unsigned short*)(w + (106u << 20));// 2 MB
  unsigned short* wq  = (unsigned short*)(w + (108u << 20));
  unsigned short* wk  = (unsigned short*)(w + (110u << 20));
  unsigned short* wv_ = (unsigned short*)(w + (112u << 20));
  unsigned short* weo = (unsigned short*)(w + (114u << 20));
  unsigned short* wo  = (unsigned short*)(w + (116u << 20));
  unsigned short* ewb = (unsigned short*)(w + (118u << 20));    // 0.5 MB

  // merged cvt: query + q_w/k_w/v_w/e_out_w/out_w + e_weight
  k_cvt_all<<<10880, 256, 0, stream>>>(query, q_w, k_w, v_w, e_out_w, out_w, e_weight,
                                       query_bf, wq, wk, wv_, weo, wo, ewb);

  k_compress_mfma<<<dim3(64, LC), 256, 0, stream>>>(query_bf, ewb, parts);
  k_reduce<<<4096, 256, 0, stream>>>(parts, kv_raw);
  k_gemm_mfma<2, float><<<dim3(8, 8), 256, 0, stream>>>(kv_raw, weo, e_out_b, e_weight, kv_eo);
  k_ln<<<PP * BB, 256, 0, stream>>>(kv_eo, ln_g, ln_b, kv_ln);
  k_gemm256<1, unsigned short><<<dim3(64, 4), 512, 0, stream>>>(query_bf, wq, q_b, q_bf);
  k_gemm_kv<<<dim3(8, 8, 2), 256, 0, stream>>>(kv_ln, wk, wv_, k_b, v_b, k_buf, v_buf);
  k_attn_mfma<<<dim3(16, 64), 512, 0, stream>>>(q_bf, k_buf, v_buf, attn_bf);
  k_gemm256<0, float><<<dim3(64, 4), 512, 0, stream>>>(attn_bf, wo, out_b, out);
}

// Round 9
// 213.151 us; speedup vs baseline: 11.9751x; 1.0431x over previous
//
#include <hip/hip_runtime.h>
#include <hip/hip_bf16.h>
#include <cstdint>
#include <cstddef>

#define LL 4096
#define BB 4
#define DD 1024
#define HH 16
#define PP 256
#define HDD 64
#define LC 16
#define LCHUNK 256

constexpr float kScaling = 0.125f;   // HD^-0.5
constexpr float kEps = 1e-5f;

typedef __attribute__((ext_vector_type(8))) short bf16x8;   // 8 bf16 = 4 VGPR
typedef __attribute__((ext_vector_type(4))) short short4v;
typedef __attribute__((ext_vector_type(4))) float f32x4;

#define MFMA16(a, b, c) __builtin_amdgcn_mfma_f32_16x16x32_bf16((a), (b), (c), 0, 0, 0)

__device__ __forceinline__ unsigned short f2bf(float f) {
  unsigned int u = __builtin_bit_cast(unsigned int, f);
  u += 0x7FFFu + ((u >> 16) & 1u);           // round-to-nearest-even
  return (unsigned short)(u >> 16);
}
__device__ __forceinline__ float bf2f(unsigned short u) {
  return __builtin_bit_cast(float, ((unsigned int)u) << 16);
}

__device__ __forceinline__ void gll16(const void* g, void* l) {
  __builtin_amdgcn_global_load_lds(
      (const __attribute__((address_space(1))) unsigned int*)g,
      (__attribute__((address_space(3))) unsigned int*)l, 16, 0, 0);
}

// ---------------------------------------------------------------------------
// Merged fp32 -> bf16 convert for query + 5 weights + e_weight (one launch).
// ---------------------------------------------------------------------------
__global__ __launch_bounds__(256) void k_cvt_all(
    const float* __restrict__ q,
    const float* __restrict__ w0, const float* __restrict__ w1,
    const float* __restrict__ w2, const float* __restrict__ w3,
    const float* __restrict__ w4, const float* __restrict__ w5,
    unsigned short* __restrict__ dq,
    unsigned short* __restrict__ d0, unsigned short* __restrict__ d1,
    unsigned short* __restrict__ d2, unsigned short* __restrict__ d3,
    unsigned short* __restrict__ d4, unsigned short* __restrict__ d5) {
  int i = blockIdx.x * 256 + threadIdx.x;
  const float* src; unsigned short* dst; int off;
  if (i < 2097152) { src = q; dst = dq; off = i; }
  else {
    int j = i - 2097152; int w = j >> 17; off = j & 131071;
    if (w == 0) { src = w0; dst = d0; }
    else if (w == 1) { src = w1; dst = d1; }
    else if (w == 2) { src = w2; dst = d2; }
    else if (w == 3) { src = w3; dst = d3; }
    else if (w == 4) { src = w4; dst = d4; }
    else { if (off >= 32768) return; src = w5; dst = d5; }
  }
  const float4* s = (const float4*)(src + (size_t)off * 8);
  float4 a = s[0], b = s[1];
  bf16x8 o;
  o[0] = f2bf(a.x); o[1] = f2bf(a.y); o[2] = f2bf(a.z); o[3] = f2bf(a.w);
  o[4] = f2bf(b.x); o[5] = f2bf(b.y); o[6] = f2bf(b.z); o[7] = f2bf(b.w);
  *(bf16x8*)(dst + (size_t)off * 8) = o;
}

// ---------------------------------------------------------------------------
// Compress (MFMA). Xtl transpose staged as packed p-pair ds_write_b32
// (dword-aligned, 2 lanes/bank different dwords = conflict-free-ish).
// ---------------------------------------------------------------------------
__global__ __launch_bounds__(256) void k_compress_mfma(
    const unsigned short* __restrict__ qbf, const unsigned short* __restrict__ ewbf,
    unsigned short* __restrict__ parts) {
  const int bh = blockIdx.x, lc = blockIdx.y;
  const int b = bh >> 4, h = bh & 15;
  const int tid = threadIdx.x, wv = tid >> 6, lane = tid & 63;
  const int fr = lane & 15, fg = lane >> 4;

  __shared__ __align__(16) char Xl[8192];    // [l][d] rows of 128B
  __shared__ __align__(16) char Xtl[8192];   // [d][l]
  __shared__ __align__(16) char Pl[32768];   // [p][l] rows of 128B

  bf16x8 ef[4][2];
#pragma unroll
  for (int pt = 0; pt < 4; ++pt)
#pragma unroll
    for (int kc = 0; kc < 2; ++kc)
      ef[pt][kc] = *(const bf16x8*)(ewbf +
          (size_t)((h * PP + wv * 64 + pt * 16 + fr) * HDD) + kc * 32 + fg * 8);

  f32x4 acc[4][4];
#pragma unroll
  for (int i = 0; i < 4; ++i)
#pragma unroll
    for (int j = 0; j < 4; ++j) acc[i][j] = (f32x4){0.f, 0.f, 0.f, 0.f};

  const int l0 = lc * LCHUNK;
  for (int t = 0; t < 4; ++t) {
    __syncthreads();
    {
      // 256 units: l-pair (2*l2, 2*l2+1) x c8
      int l2 = tid >> 3, c8 = tid & 7;
      int l = 2 * l2;
      const unsigned short* xp = qbf +
          ((size_t)(l0 + t * 64 + l) * BB + b) * DD + h * HDD + c8 * 8;
      bf16x8 v0 = *(const bf16x8*)xp;
      bf16x8 v1 = *(const bf16x8*)(xp + BB * DD);
      *(bf16x8*)(Xl + l * 128 + ((c8 ^ (l & 7)) << 4)) = v0;
      *(bf16x8*)(Xl + (l + 1) * 128 + ((c8 ^ ((l + 1) & 7)) << 4)) = v1;
#pragma unroll
      for (int i = 0; i < 8; ++i) {
        int dd = c8 * 8 + i;
        unsigned int packed = (unsigned int)(unsigned short)v0[i] |
                              ((unsigned int)(unsigned short)v1[i] << 16);
        *(unsigned int*)(Xtl + dd * 128 +
            ((((l >> 3) ^ (dd & 7) ^ (dd >> 3)) & 7) << 4) + ((l & 7) << 1)) = packed;
      }
    }
    __syncthreads();
#pragma unroll
    for (int lt = 0; lt < 4; ++lt) {
      int rl = lt * 16 + fr;
      bf16x8 xa0 = *(const bf16x8*)(Xl + rl * 128 + (((0 + fg) ^ (rl & 7)) << 4));
      bf16x8 xa1 = *(const bf16x8*)(Xl + rl * 128 + (((4 + fg) ^ (rl & 7)) << 4));
#pragma unroll
      for (int pt = 0; pt < 4; ++pt) {
        f32x4 s = (f32x4){0.f, 0.f, 0.f, 0.f};
        s = MFMA16(xa0, ef[pt][0], s);
        s = MFMA16(xa1, ef[pt][1], s);
        short4v pk;
#pragma unroll
        for (int r = 0; r < 4; ++r)
          pk[r] = (short)f2bf(fmaxf(s[r] * kScaling, 0.f));
        int p = wv * 64 + pt * 16 + fr;
        int lbase = lt * 16 + fg * 4;
        int slot = lbase >> 3;
        *(short4v*)(Pl + p * 128 + ((slot ^ (p & 7)) << 4) + ((lbase & 7) << 1)) = pk;
      }
    }
    asm volatile("s_waitcnt lgkmcnt(0)" ::: "memory");
    __builtin_amdgcn_sched_barrier(0);
#pragma unroll
    for (int kc = 0; kc < 2; ++kc) {
      bf16x8 pa[4], xb[4];
#pragma unroll
      for (int pt = 0; pt < 4; ++pt) {
        int p = wv * 64 + pt * 16 + fr;
        pa[pt] = *(const bf16x8*)(Pl + p * 128 + (((kc * 4 + fg) ^ (p & 7)) << 4));
      }
#pragma unroll
      for (int dt = 0; dt < 4; ++dt) {
        int dd = dt * 16 + fr;
        xb[dt] = *(const bf16x8*)(Xtl + dd * 128 +
                  ((((kc * 4 + fg) ^ (dd & 7) ^ (dd >> 3)) & 7) << 4));
      }
#pragma unroll
      for (int pt = 0; pt < 4; ++pt)
#pragma unroll
        for (int dt = 0; dt < 4; ++dt)
          acc[pt][dt] = MFMA16(pa[pt], xb[dt], acc[pt][dt]);
    }
  }
  unsigned short* op = parts + (size_t)(lc * 64 + bh) * PP * HDD;
#pragma unroll
  for (int pt = 0; pt < 4; ++pt)
#pragma unroll
    for (int dt = 0; dt < 4; ++dt)
#pragma unroll
      for (int r = 0; r < 4; ++r) {
        int p = wv * 64 + pt * 16 + fg * 4 + r;
        int dd = dt * 16 + fr;
        op[(size_t)p * HDD + dd] = f2bf(acc[pt][dt][r]);
      }
}

// Sum LC bf16 partials -> kv_raw bf16 as (P,B,D)
__global__ __launch_bounds__(256) void k_reduce(const unsigned short* __restrict__ parts,
                                                unsigned short* __restrict__ kv_raw_bf) {
  int i = blockIdx.x * 256 + threadIdx.x;
  float s = 0.f;
#pragma unroll
  for (int lcc = 0; lcc < LC; ++lcc) s += bf2f(parts[(size_t)lcc * (64 * PP * HDD) + i]);
  int d = i & 63, p = (i >> 6) & 255, bh = i >> 14;
  int b = bh >> 4, h = bh & 15;
  kv_raw_bf[(size_t)(p * BB + b) * DD + h * HDD + d] = f2bf(s);
}

// ---------------------------------------------------------------------------
// 128x128 GEMM body (small P=1024-row GEMMs).
// ---------------------------------------------------------------------------
template <int MODE, typename OUTT>
__device__ __forceinline__ void gemm_body(
    const unsigned short* __restrict__ A, const unsigned short* __restrict__ W,
    const float* __restrict__ bias, const float* __restrict__ ew,
    OUTT* __restrict__ C, int m0, int n0, char* Al, char* Bl) {
  const int tid = threadIdx.x;
  const int wv = tid >> 6, lane = tid & 63;
  const int fr = lane & 15, fg = lane >> 4;
  const int wr = wv >> 1, wc = wv & 1;

  f32x4 acc[4][4];
#pragma unroll
  for (int i = 0; i < 4; ++i)
#pragma unroll
    for (int j = 0; j < 4; ++j) acc[i][j] = (f32x4){0.f, 0.f, 0.f, 0.f};

  for (int k0 = 0; k0 < DD; k0 += 64) {
    __syncthreads();
#pragma unroll
    for (int j = 0; j < 4; ++j) {
      int u = tid + j * 256;
      int row = u >> 3, slot = u & 7;
      size_t gcol = (size_t)(k0 + 8 * (slot ^ (row & 7)));
      gll16(A + (size_t)(m0 + row) * DD + gcol, Al + u * 16);
      gll16(W + (size_t)(n0 + row) * DD + gcol, Bl + u * 16);
    }
    __syncthreads();
#pragma unroll
    for (int kc = 0; kc < 2; ++kc) {
      bf16x8 af[4], bfr[4];
#pragma unroll
      for (int mt = 0; mt < 4; ++mt) {
        int r = wr * 64 + mt * 16 + fr;
        af[mt] = *(const bf16x8*)(Al + r * 128 + (((kc * 4 + fg) ^ (r & 7)) << 4));
      }
#pragma unroll
      for (int nt = 0; nt < 4; ++nt) {
        int r = wc * 64 + nt * 16 + fr;
        bfr[nt] = *(const bf16x8*)(Bl + r * 128 + (((kc * 4 + fg) ^ (r & 7)) << 4));
      }
#pragma unroll
      for (int mt = 0; mt < 4; ++mt)
#pragma unroll
        for (int nt = 0; nt < 4; ++nt)
          acc[mt][nt] = MFMA16(af[mt], bfr[nt], acc[mt][nt]);
    }
  }

  float bs[4];
#pragma unroll
  for (int nt = 0; nt < 4; ++nt) bs[nt] = bias[n0 + wc * 64 + nt * 16 + fr];
#pragma unroll
  for (int mt = 0; mt < 4; ++mt)
#pragma unroll
    for (int nt = 0; nt < 4; ++nt) {
      int n = n0 + wc * 64 + nt * 16 + fr;
#pragma unroll
      for (int r = 0; r < 4; ++r) {
        int m = m0 + wr * 64 + mt * 16 + fg * 4 + r;
        float v = acc[mt][nt][r] + bs[nt];
        if (MODE == 1) v *= kScaling;
        if (MODE == 2) {
          int p = m >> 2, hh = n >> 6, d2 = n & 63;
          v += ew[(size_t)((hh << 8) + p) * HDD + d2];
        }
        if constexpr (sizeof(OUTT) == 2)
          C[(size_t)m * DD + n] = (OUTT)f2bf(v);
        else
          C[(size_t)m * DD + n] = v;
      }
    }
}

template <int MODE, typename OUTT>
__global__ __launch_bounds__(256) void k_gemm_mfma(
    const unsigned short* __restrict__ A, const unsigned short* __restrict__ W,
    const float* __restrict__ bias, const float* __restrict__ ew,
    OUTT* __restrict__ C) {
  __shared__ __align__(16) char Al[16384];
  __shared__ __align__(16) char Bl[16384];
  gemm_body<MODE, OUTT>(A, W, bias, ew, C, blockIdx.x * 128, blockIdx.y * 128, Al, Bl);
}

// K and V projections in one launch (blockIdx.z selects).
__global__ __launch_bounds__(256) void k_gemm_kv(
    const unsigned short* __restrict__ A,
    const unsigned short* __restrict__ Wk, const unsigned short* __restrict__ Wv,
    const float* __restrict__ kb, const float* __restrict__ vb,
    unsigned short* __restrict__ Ck, unsigned short* __restrict__ Cv) {
  __shared__ __align__(16) char Al[16384];
  __shared__ __align__(16) char Bl[16384];
  if (blockIdx.z == 0)
    gemm_body<0, unsigned short>(A, Wk, kb, nullptr, Ck,
                                 blockIdx.x * 128, blockIdx.y * 128, Al, Bl);
  else
    gemm_body<0, unsigned short>(A, Wv, vb, nullptr, Cv,
                                 blockIdx.x * 128, blockIdx.y * 128, Al, Bl);
}

// ---------------------------------------------------------------------------
// 256x256 8-phase GEMM (unchanged).
// ---------------------------------------------------------------------------
template <int MODE, typename OUTT>
__global__ __launch_bounds__(512, 2) void k_gemm256(
    const unsigned short* __restrict__ A, const unsigned short* __restrict__ W,
    const float* __restrict__ bias, OUTT* __restrict__ C) {
  __shared__ __align__(16) char lds[131072];
  const int tid = threadIdx.x;
  const int wv = tid >> 6, lane = tid & 63;
  const int fr = lane & 15, fg = lane >> 4;
  const int wm = wv >> 2, wn = wv & 3;
  const int m0 = blockIdx.x * 256, n0 = blockIdx.y * 256;
  const int srow = tid >> 2, sslot = tid & 3;

  auto stageHalf = [&](const unsigned short* __restrict__ G, int g0, int colbase,
                       int dstBase) {
#pragma unroll
    for (int j = 0; j < 2; ++j) {
      int row = srow + j * 128;
      int gs = sslot ^ ((row >> 1) & 3);
      gll16(G + (size_t)(g0 + row) * DD + colbase + gs * 8,
            lds + dstBase + (tid + j * 512) * 16);
    }
  };
  auto rdA = [&](int mf, int kc, int cb) -> bf16x8 {
    int r = wm * 128 + mf * 16 + fr;
    return *(const bf16x8*)(lds + cb + kc * 16384 + r * 64 +
                            ((fg ^ ((r >> 1) & 3)) << 4));
  };
  auto rdB = [&](int nf, int kc, int cb) -> bf16x8 {
    int r = wn * 64 + nf * 16 + fr;
    return *(const bf16x8*)(lds + cb + 32768 + kc * 16384 + r * 64 +
                            ((fg ^ ((r >> 1) & 3)) << 4));
  };

  f32x4 acc[8][4];
#pragma unroll
  for (int i = 0; i < 8; ++i)
#pragma unroll
    for (int j = 0; j < 4; ++j) acc[i][j] = (f32x4){0.f, 0.f, 0.f, 0.f};
  bf16x8 a[4], b[4];

  stageHalf(A, m0, 0, 0);
  stageHalf(W, n0, 0, 32768);
  stageHalf(A, m0, 32, 16384);
  stageHalf(W, n0, 32, 32768 + 16384);
  stageHalf(A, m0, 64, 65536);
  stageHalf(W, n0, 64, 65536 + 32768);
  asm volatile("s_waitcnt vmcnt(4)" ::: "memory");
  __builtin_amdgcn_s_barrier();

  const int NT = DD / 64;   // 16
  for (int t = 0; t < NT; ++t) {
    const int cb = (t & 1) << 16;
    const int nb = cb ^ 65536;
    const int k1 = (t + 1) * 64, k2 = (t + 2) * 64;

#pragma unroll
    for (int i = 0; i < 4; ++i) a[i] = rdA(i, 0, cb);
#pragma unroll
    for (int i = 0; i < 4; ++i) b[i] = rdB(i, 0, cb);
    if (t + 1 < NT) stageHalf(A, m0, k1 + 32, nb + 16384);
    __builtin_amdgcn_s_barrier();
    asm volatile("s_waitcnt lgkmcnt(0)" ::: "memory");
    __builtin_amdgcn_sched_barrier(0);
    __builtin_amdgcn_s_setprio(1);
#pragma unroll
    for (int mf = 0; mf < 4; ++mf)
#pragma unroll
      for (int nf = 0; nf < 4; ++nf)
        acc[mf][nf] = MFMA16(a[mf], b[nf], acc[mf][nf]);
    __builtin_amdgcn_s_setprio(0);
    __builtin_amdgcn_s_barrier();

#pragma unroll
    for (int i = 0; i < 4; ++i) a[i] = rdA(4 + i, 0, cb);
    if (t + 1 < NT) stageHalf(W, n0, k1 + 32, nb + 32768 + 16384);
    __builtin_amdgcn_s_barrier();
    asm volatile("s_waitcnt lgkmcnt(0)" ::: "memory");
    __builtin_amdgcn_sched_barrier(0);
    __builtin_amdgcn_s_setprio(1);
#pragma unroll
    for (int mf = 0; mf < 4; ++mf)
#pragma unroll
      for (int nf = 0; nf < 4; ++nf)
        acc[4 + mf][nf] = MFMA16(a[mf], b[nf], acc[4 + mf][nf]);
    __builtin_amdgcn_s_setprio(0);
    __builtin_amdgcn_s_barrier();

#pragma unroll
    for (int i = 0; i < 4; ++i) a[i] = rdA(i, 1, cb);
#pragma unroll
    for (int i = 0; i < 4; ++i) b[i] = rdB(i, 1, cb);
    if (t + 2 < NT) stageHalf(A, m0, k2, cb);
    __builtin_amdgcn_s_barrier();
    asm volatile("s_waitcnt lgkmcnt(0)" ::: "memory");
    __builtin_amdgcn_sched_barrier(0);
    __builtin_amdgcn_s_setprio(1);
#pragma unroll
    for (int mf = 0; mf < 4; ++mf)
#pragma unroll
      for (int nf = 0; nf < 4; ++nf)
        acc[mf][nf] = MFMA16(a[mf], b[nf], acc[mf][nf]);
    __builtin_amdgcn_s_setprio(0);
    __builtin_amdgcn_s_barrier();

#pragma unroll
    for (int i = 0; i < 4; ++i) a[i] = rdA(4 + i, 1, cb);
    if (t + 2 < NT) stageHalf(W, n0, k2, cb + 32768);
    __builtin_amdgcn_s_barrier();
    asm volatile("s_waitcnt lgkmcnt(0)" ::: "memory");
    __builtin_amdgcn_sched_barrier(0);
    __builtin_amdgcn_s_setprio(1);
#pragma unroll
    for (int mf = 0; mf < 4; ++mf)
#pragma unroll
      for (int nf = 0; nf < 4; ++nf)
        acc[4 + mf][nf] = MFMA16(a[mf], b[nf], acc[4 + mf][nf]);
    __builtin_amdgcn_s_setprio(0);
    if (t + 2 < NT) {
      asm volatile("s_waitcnt vmcnt(4)" ::: "memory");
    } else if (t + 1 < NT) {
      asm volatile("s_waitcnt vmcnt(0)" ::: "memory");
    }
    __builtin_amdgcn_s_barrier();
  }

  float bs[4];
#pragma unroll
  for (int nf = 0; nf < 4; ++nf) bs[nf] = bias[n0 + wn * 64 + nf * 16 + fr];
#pragma unroll
  for (int mf = 0; mf < 8; ++mf)
#pragma unroll
    for (int nf = 0; nf < 4; ++nf) {
      int n = n0 + wn * 64 + nf * 16 + fr;
#pragma unroll
      for (int r = 0; r < 4; ++r) {
        int m = m0 + wm * 128 + mf * 16 + fg * 4 + r;
        float v = acc[mf][nf][r] + bs[nf];
        if (MODE == 1) v *= kScaling;
        if constexpr (sizeof(OUTT) == 2)
          C[(size_t)m * DD + n] = (OUTT)f2bf(v);
        else
          C[(size_t)m * DD + n] = v;
      }
    }
}

// LayerNorm over D=1024; fp32 in -> bf16 out. One block per row.
__global__ __launch_bounds__(256) void k_ln(const float* __restrict__ x,
                                            const float* __restrict__ g,
                                            const float* __restrict__ bb,
                                            unsigned short* __restrict__ y) {
  const int r = blockIdx.x;
  const int tid = threadIdx.x;
  const float* xr = x + (size_t)r * DD;
  float4 v = *(const float4*)(xr + tid * 4);
  float s1 = v.x + v.y + v.z + v.w;
  float s2 = v.x * v.x + v.y * v.y + v.z * v.z + v.w * v.w;
#pragma unroll
  for (int off = 32; off > 0; off >>= 1) {
    s1 += __shfl_down(s1, off);
    s2 += __shfl_down(s2, off);
  }
  __shared__ float w1[4], w2[4];
  if ((tid & 63) == 0) { w1[tid >> 6] = s1; w2[tid >> 6] = s2; }
  __syncthreads();
  float S1 = w1[0] + w1[1] + w1[2] + w1[3];
  float S2 = w2[0] + w2[1] + w2[2] + w2[3];
  float mean = S1 * (1.f / DD);
  float var = S2 * (1.f / DD) - mean * mean;
  float rstd = rsqrtf(var + kEps);
  float4 gv = *(const float4*)(g + tid * 4);
  float4 bv = *(const float4*)(bb + tid * 4);
  short4v o;
  o[0] = (short)f2bf((v.x - mean) * rstd * gv.x + bv.x);
  o[1] = (short)f2bf((v.y - mean) * rstd * gv.y + bv.y);
  o[2] = (short)f2bf((v.z - mean) * rstd * gv.z + bv.z);
  o[3] = (short)f2bf((v.w - mean) * rstd * gv.w + bv.w);
  *(short4v*)(y + (size_t)r * DD + tid * 4) = o;
}

// ---------------------------------------------------------------------------
// Attention: QBLK=128 (reverted), Vt staged via packed p-pair ds_write_b32.
// Two KV halves of 128 p; LDS 64KB -> 2 blocks/CU. 8 waves x 16 q-rows.
// ---------------------------------------------------------------------------
__global__ __launch_bounds__(512, 2) void k_attn_mfma(
    const unsigned short* __restrict__ qbf, const unsigned short* __restrict__ kbf,
    const unsigned short* __restrict__ vbf, unsigned short* __restrict__ attn) {
  const int bh = blockIdx.y;
  const int b = bh >> 4, h = bh & 15;
  const int tid = threadIdx.x, wv = tid >> 6, lane = tid & 63;
  const int fr = lane & 15, fg = lane >> 4;
  const int bl0 = blockIdx.x * 128;

  __shared__ __align__(16) char Kl[16384];    // [128p][64d] swz rows of 128B
  __shared__ __align__(16) char Vt[16384];    // 2 chunks of [64 dd][64 p]
  __shared__ __align__(16) char Pl[32768];    // 8 waves x [16 l][128 p]

  const size_t qrow = ((size_t)(bl0 + wv * 16 + fr) * BB + b) * DD + h * HDD;
  bf16x8 qf0 = *(const bf16x8*)(qbf + qrow + fg * 8);
  bf16x8 qf1 = *(const bf16x8*)(qbf + qrow + 32 + fg * 8);

  f32x4 o[4];
#pragma unroll
  for (int dt = 0; dt < 4; ++dt) o[dt] = (f32x4){0.f, 0.f, 0.f, 0.f};
  float psum = 0.f;
  char* Pw = Pl + wv * 4096;

  for (int ph = 0; ph < 2; ++ph) {
    __syncthreads();    // prev PV reads done; LDS safe to overwrite
    // stage K half (gll16, pre-swizzled source)
#pragma unroll
    for (int j = 0; j < 2; ++j) {
      int u = tid + j * 512;
      int p = u >> 3, slot = u & 7;
      gll16(kbf + ((size_t)((ph * 128 + p) * BB + b)) * DD + h * HDD +
                8 * (slot ^ (p & 7)),
            Kl + u * 16);
    }
    // stage V^T half: 512 units = p-pair (2p2, 2p2+1) x c8, packed b32 writes
    {
      int p2 = tid >> 3, c8 = tid & 7;
      int p0 = ph * 128 + 2 * p2;
      const unsigned short* vp = vbf + ((size_t)(p0 * BB + b)) * DD + h * HDD + c8 * 8;
      bf16x8 v0 = *(const bf16x8*)vp;
      bf16x8 v1 = *(const bf16x8*)(vp + BB * DD);
      int pl = (2 * p2) & 63, pc = p2 >> 5;
      char* base = Vt + pc * 8192;
#pragma unroll
      for (int i = 0; i < 8; ++i) {
        int dd = c8 * 8 + i;
        unsigned int packed = (unsigned int)(unsigned short)v0[i] |
                              ((unsigned int)(unsigned short)v1[i] << 16);
        *(unsigned int*)(base + dd * 128 +
            ((((pl >> 3) ^ (dd & 7) ^ (dd >> 3)) & 7) << 4) + ((pl & 7) << 1)) = packed;
      }
    }
    __syncthreads();    // includes vmcnt(0)+lgkmcnt(0) drain

    // S^T = K @ Q^T : 8 p-tiles this half
    f32x4 s[8];
    __builtin_amdgcn_s_setprio(1);
#pragma unroll
    for (int pt = 0; pt < 8; ++pt) {
      int pr = pt * 16 + fr;
      bf16x8 a0 = *(const bf16x8*)(Kl + pr * 128 + ((fg ^ (pr & 7)) << 4));
      bf16x8 a1 = *(const bf16x8*)(Kl + pr * 128 + (((4 + fg) ^ (pr & 7)) << 4));
      f32x4 acc = (f32x4){0.f, 0.f, 0.f, 0.f};
      acc = MFMA16(a0, qf0, acc);
      acc = MFMA16(a1, qf1, acc);
      s[pt] = acc;
    }
    __builtin_amdgcn_s_setprio(0);

    // exp + unnormalized P -> own-wave LDS; fp32 row-sum accumulates
#pragma unroll
    for (int pt = 0; pt < 8; ++pt) {
      float e0 = __expf(s[pt][0]), e1 = __expf(s[pt][1]);
      float e2 = __expf(s[pt][2]), e3 = __expf(s[pt][3]);
      psum += (e0 + e1) + (e2 + e3);
      short4v pk;
      pk[0] = (short)f2bf(e0); pk[1] = (short)f2bf(e1);
      pk[2] = (short)f2bf(e2); pk[3] = (short)f2bf(e3);
      int pbyte = (pt * 16 + fg * 4) * 2;
      int slot = pbyte >> 4, rem = pbyte & 15;
      *(short4v*)(Pw + fr * 256 + ((slot ^ (fr & 7)) << 4) + rem) = pk;
    }
    asm volatile("s_waitcnt lgkmcnt(0)" ::: "memory");
    __builtin_amdgcn_sched_barrier(0);

    // O += P @ V^T : K = 128 p in 4 chunks
    __builtin_amdgcn_s_setprio(1);
#pragma unroll
    for (int kc = 0; kc < 4; ++kc) {
      int slot = kc * 4 + fg;
      bf16x8 pa = *(const bf16x8*)(Pw + fr * 256 + ((slot ^ (fr & 7)) << 4));
      int sl2 = (kc & 1) * 4 + fg;
#pragma unroll
      for (int dt = 0; dt < 4; ++dt) {
        int dd = dt * 16 + fr;
        bf16x8 vb = *(const bf16x8*)(Vt + (kc >> 1) * 8192 + dd * 128 +
                     (((sl2 ^ (dd & 7) ^ (dd >> 3)) & 7) << 4));
        o[dt] = MFMA16(pa, vb, o[dt]);
      }
    }
    __builtin_amdgcn_s_setprio(0);
  }

  psum += __shfl_xor(psum, 16);
  psum += __shfl_xor(psum, 32);

#pragma unroll
  for (int r = 0; r < 4; ++r) {
    int lloc = fg * 4 + r;
    float inv = 1.f / __shfl(psum, lloc);
    unsigned short* op = attn +
        ((size_t)(bl0 + wv * 16 + lloc) * BB + b) * DD + h * HDD;
#pragma unroll
    for (int dt = 0; dt < 4; ++dt)
      op[dt * 16 + fr] = f2bf(o[dt][r] * inv);
  }
}

extern "C" void kernel_launch(void* const* d_in, const int* in_sizes, int n_in,
                              void* d_out, int out_size, void* d_ws, size_t ws_size,
                              hipStream_t stream) {
  const float* query   = (const float*)d_in[0];
  const float* q_w     = (const float*)d_in[1];
  const float* q_b     = (const float*)d_in[2];
  const float* k_w     = (const float*)d_in[3];
  const float* k_b     = (const float*)d_in[4];
  const float* v_w     = (const float*)d_in[5];
  const float* v_b     = (const float*)d_in[6];
  const float* e_weight= (const float*)d_in[7];
  const float* e_out_w = (const float*)d_in[8];
  const float* e_out_b = (const float*)d_in[9];
  const float* ln_g    = (const float*)d_in[10];
  const float* ln_b    = (const float*)d_in[11];
  const float* out_w   = (const float*)d_in[12];
  const float* out_b   = (const float*)d_in[13];
  float* out = (float*)d_out;

  char* w = (char*)d_ws;
  unsigned short* parts   = (unsigned short*)w;                 // 32 MB, dead after reduce
  unsigned short* q_bf    = (unsigned short*)w;                 // 32 MB (alias, after reduce)
  unsigned short* attn_bf = (unsigned short*)(w + (32u << 20)); // 32 MB
  unsigned short* query_bf= (unsigned short*)(w + (64u << 20)); // 32 MB
  unsigned short* kv_raw  = (unsigned short*)(w + (96u << 20)); // 2 MB
  float* kv_eo            = (float*)(w + (98u << 20));          // 4 MB
  unsigned short* kv_ln   = (unsigned short*)(w + (102u << 20));// 2 MB
  unsigned short* k_buf   = (unsigned short*)(w + (104u << 20));// 2 MB
  unsigned short* v_buf   = (unsigned short*)(w + (106u << 20));// 2 MB
  unsigned short* wq  = (unsigned short*)(w + (108u << 20));
  unsigned short* wk  = (unsigned short*)(w + (110u << 20));
  unsigned short* wv_ = (unsigned short*)(w + (112u << 20));
  unsigned short* weo = (unsigned short*)(w + (114u << 20));
  unsigned short* wo  = (unsigned short*)(w + (116u << 20));
  unsigned short* ewb = (unsigned short*)(w + (118u << 20));    // 0.5 MB

  k_cvt_all<<<10880, 256, 0, stream>>>(query, q_w, k_w, v_w, e_out_w, out_w, e_weight,
                                       query_bf, wq, wk, wv_, weo, wo, ewb);

  k_compress_mfma<<<dim3(64, LC), 256, 0, stream>>>(query_bf, ewb, parts);
  k_reduce<<<4096, 256, 0, stream>>>(parts, kv_raw);
  k_gemm_mfma<2, float><<<dim3(8, 8), 256, 0, stream>>>(kv_raw, weo, e_out_b, e_weight, kv_eo);
  k_ln<<<PP * BB, 256, 0, stream>>>(kv_eo, ln_g, ln_b, kv_ln);
  k_gemm256<1, unsigned short><<<dim3(64, 4), 512, 0, stream>>>(query_bf, wq, q_b, q_bf);
  k_gemm_kv<<<dim3(8, 8, 2), 256, 0, stream>>>(kv_ln, wk, wv_, k_b, v_b, k_buf, v_buf);
  k_attn_mfma<<<dim3(32, 64), 512, 0, stream>>>(q_bf, k_buf, v_buf, attn_bf);
  k_gemm256<0, float><<<dim3(64, 4), 512, 0, stream>>>(attn_bf, wo, out_b, out);
}

// Round 10
// 212.980 us; speedup vs baseline: 11.9847x; 1.0008x over previous
//
#include <hip/hip_runtime.h>
#include <hip/hip_bf16.h>
#include <cstdint>
#include <cstddef>

#define LL 4096
#define BB 4
#define DD 1024
#define HH 16
#define PP 256
#define HDD 64
#define LC 16
#define LCHUNK 256

constexpr float kScaling = 0.125f;   // HD^-0.5
constexpr float kEps = 1e-5f;

typedef __attribute__((ext_vector_type(8))) short bf16x8;   // 8 bf16 = 4 VGPR
typedef __attribute__((ext_vector_type(4))) short short4v;
typedef __attribute__((ext_vector_type(4))) float f32x4;

#define MFMA16(a, b, c) __builtin_amdgcn_mfma_f32_16x16x32_bf16((a), (b), (c), 0, 0, 0)

__device__ __forceinline__ unsigned short f2bf(float f) {
  unsigned int u = __builtin_bit_cast(unsigned int, f);
  u += 0x7FFFu + ((u >> 16) & 1u);           // round-to-nearest-even
  return (unsigned short)(u >> 16);
}
__device__ __forceinline__ float bf2f(unsigned short u) {
  return __builtin_bit_cast(float, ((unsigned int)u) << 16);
}

__device__ __forceinline__ void gll16(const void* g, void* l) {
  __builtin_amdgcn_global_load_lds(
      (const __attribute__((address_space(1))) unsigned int*)g,
      (__attribute__((address_space(3))) unsigned int*)l, 16, 0, 0);
}

// ---------------------------------------------------------------------------
// Merged fp32 -> bf16 convert for query + 5 weights + e_weight (one launch).
// ---------------------------------------------------------------------------
__global__ __launch_bounds__(256) void k_cvt_all(
    const float* __restrict__ q,
    const float* __restrict__ w0, const float* __restrict__ w1,
    const float* __restrict__ w2, const float* __restrict__ w3,
    const float* __restrict__ w4, const float* __restrict__ w5,
    unsigned short* __restrict__ dq,
    unsigned short* __restrict__ d0, unsigned short* __restrict__ d1,
    unsigned short* __restrict__ d2, unsigned short* __restrict__ d3,
    unsigned short* __restrict__ d4, unsigned short* __restrict__ d5) {
  int i = blockIdx.x * 256 + threadIdx.x;
  const float* src; unsigned short* dst; int off;
  if (i < 2097152) { src = q; dst = dq; off = i; }
  else {
    int j = i - 2097152; int w = j >> 17; off = j & 131071;
    if (w == 0) { src = w0; dst = d0; }
    else if (w == 1) { src = w1; dst = d1; }
    else if (w == 2) { src = w2; dst = d2; }
    else if (w == 3) { src = w3; dst = d3; }
    else if (w == 4) { src = w4; dst = d4; }
    else { if (off >= 32768) return; src = w5; dst = d5; }
  }
  const float4* s = (const float4*)(src + (size_t)off * 8);
  float4 a = s[0], b = s[1];
  bf16x8 o;
  o[0] = f2bf(a.x); o[1] = f2bf(a.y); o[2] = f2bf(a.z); o[3] = f2bf(a.w);
  o[4] = f2bf(b.x); o[5] = f2bf(b.y); o[6] = f2bf(b.z); o[7] = f2bf(b.w);
  *(bf16x8*)(dst + (size_t)off * 8) = o;
}

// ---------------------------------------------------------------------------
// Compress (MFMA). Xtl transpose staged as packed p-pair ds_write_b32.
// ---------------------------------------------------------------------------
__global__ __launch_bounds__(256) void k_compress_mfma(
    const unsigned short* __restrict__ qbf, const unsigned short* __restrict__ ewbf,
    unsigned short* __restrict__ parts) {
  const int bh = blockIdx.x, lc = blockIdx.y;
  const int b = bh >> 4, h = bh & 15;
  const int tid = threadIdx.x, wv = tid >> 6, lane = tid & 63;
  const int fr = lane & 15, fg = lane >> 4;

  __shared__ __align__(16) char Xl[8192];    // [l][d] rows of 128B
  __shared__ __align__(16) char Xtl[8192];   // [d][l]
  __shared__ __align__(16) char Pl[32768];   // [p][l] rows of 128B

  bf16x8 ef[4][2];
#pragma unroll
  for (int pt = 0; pt < 4; ++pt)
#pragma unroll
    for (int kc = 0; kc < 2; ++kc)
      ef[pt][kc] = *(const bf16x8*)(ewbf +
          (size_t)((h * PP + wv * 64 + pt * 16 + fr) * HDD) + kc * 32 + fg * 8);

  f32x4 acc[4][4];
#pragma unroll
  for (int i = 0; i < 4; ++i)
#pragma unroll
    for (int j = 0; j < 4; ++j) acc[i][j] = (f32x4){0.f, 0.f, 0.f, 0.f};

  const int l0 = lc * LCHUNK;
  for (int t = 0; t < 4; ++t) {
    __syncthreads();
    {
      int l2 = tid >> 3, c8 = tid & 7;
      int l = 2 * l2;
      const unsigned short* xp = qbf +
          ((size_t)(l0 + t * 64 + l) * BB + b) * DD + h * HDD + c8 * 8;
      bf16x8 v0 = *(const bf16x8*)xp;
      bf16x8 v1 = *(const bf16x8*)(xp + BB * DD);
      *(bf16x8*)(Xl + l * 128 + ((c8 ^ (l & 7)) << 4)) = v0;
      *(bf16x8*)(Xl + (l + 1) * 128 + ((c8 ^ ((l + 1) & 7)) << 4)) = v1;
#pragma unroll
      for (int i = 0; i < 8; ++i) {
        int dd = c8 * 8 + i;
        unsigned int packed = (unsigned int)(unsigned short)v0[i] |
                              ((unsigned int)(unsigned short)v1[i] << 16);
        *(unsigned int*)(Xtl + dd * 128 +
            ((((l >> 3) ^ (dd & 7) ^ (dd >> 3)) & 7) << 4) + ((l & 7) << 1)) = packed;
      }
    }
    __syncthreads();
#pragma unroll
    for (int lt = 0; lt < 4; ++lt) {
      int rl = lt * 16 + fr;
      bf16x8 xa0 = *(const bf16x8*)(Xl + rl * 128 + (((0 + fg) ^ (rl & 7)) << 4));
      bf16x8 xa1 = *(const bf16x8*)(Xl + rl * 128 + (((4 + fg) ^ (rl & 7)) << 4));
#pragma unroll
      for (int pt = 0; pt < 4; ++pt) {
        f32x4 s = (f32x4){0.f, 0.f, 0.f, 0.f};
        s = MFMA16(xa0, ef[pt][0], s);
        s = MFMA16(xa1, ef[pt][1], s);
        short4v pk;
#pragma unroll
        for (int r = 0; r < 4; ++r)
          pk[r] = (short)f2bf(fmaxf(s[r] * kScaling, 0.f));
        int p = wv * 64 + pt * 16 + fr;
        int lbase = lt * 16 + fg * 4;
        int slot = lbase >> 3;
        *(short4v*)(Pl + p * 128 + ((slot ^ (p & 7)) << 4) + ((lbase & 7) << 1)) = pk;
      }
    }
    asm volatile("s_waitcnt lgkmcnt(0)" ::: "memory");
    __builtin_amdgcn_sched_barrier(0);
#pragma unroll
    for (int kc = 0; kc < 2; ++kc) {
      bf16x8 pa[4], xb[4];
#pragma unroll
      for (int pt = 0; pt < 4; ++pt) {
        int p = wv * 64 + pt * 16 + fr;
        pa[pt] = *(const bf16x8*)(Pl + p * 128 + (((kc * 4 + fg) ^ (p & 7)) << 4));
      }
#pragma unroll
      for (int dt = 0; dt < 4; ++dt) {
        int dd = dt * 16 + fr;
        xb[dt] = *(const bf16x8*)(Xtl + dd * 128 +
                  ((((kc * 4 + fg) ^ (dd & 7) ^ (dd >> 3)) & 7) << 4));
      }
#pragma unroll
      for (int pt = 0; pt < 4; ++pt)
#pragma unroll
        for (int dt = 0; dt < 4; ++dt)
          acc[pt][dt] = MFMA16(pa[pt], xb[dt], acc[pt][dt]);
    }
  }
  unsigned short* op = parts + (size_t)(lc * 64 + bh) * PP * HDD;
#pragma unroll
  for (int pt = 0; pt < 4; ++pt)
#pragma unroll
    for (int dt = 0; dt < 4; ++dt)
#pragma unroll
      for (int r = 0; r < 4; ++r) {
        int p = wv * 64 + pt * 16 + fg * 4 + r;
        int dd = dt * 16 + fr;
        op[(size_t)p * HDD + dd] = f2bf(acc[pt][dt][r]);
      }
}

// Sum LC bf16 partials -> kv_raw bf16 as (P,B,D)
__global__ __launch_bounds__(256) void k_reduce(const unsigned short* __restrict__ parts,
                                                unsigned short* __restrict__ kv_raw_bf) {
  int i = blockIdx.x * 256 + threadIdx.x;
  float s = 0.f;
#pragma unroll
  for (int lcc = 0; lcc < LC; ++lcc) s += bf2f(parts[(size_t)lcc * (64 * PP * HDD) + i]);
  int d = i & 63, p = (i >> 6) & 255, bh = i >> 14;
  int b = bh >> 4, h = bh & 15;
  kv_raw_bf[(size_t)(p * BB + b) * DD + h * HDD + d] = f2bf(s);
}

// ---------------------------------------------------------------------------
// 128x128 GEMM body (small P=1024-row GEMMs).
// ---------------------------------------------------------------------------
template <int MODE, typename OUTT>
__device__ __forceinline__ void gemm_body(
    const unsigned short* __restrict__ A, const unsigned short* __restrict__ W,
    const float* __restrict__ bias, const float* __restrict__ ew,
    OUTT* __restrict__ C, int m0, int n0, char* Al, char* Bl) {
  const int tid = threadIdx.x;
  const int wv = tid >> 6, lane = tid & 63;
  const int fr = lane & 15, fg = lane >> 4;
  const int wr = wv >> 1, wc = wv & 1;

  f32x4 acc[4][4];
#pragma unroll
  for (int i = 0; i < 4; ++i)
#pragma unroll
    for (int j = 0; j < 4; ++j) acc[i][j] = (f32x4){0.f, 0.f, 0.f, 0.f};

  for (int k0 = 0; k0 < DD; k0 += 64) {
    __syncthreads();
#pragma unroll
    for (int j = 0; j < 4; ++j) {
      int u = tid + j * 256;
      int row = u >> 3, slot = u & 7;
      size_t gcol = (size_t)(k0 + 8 * (slot ^ (row & 7)));
      gll16(A + (size_t)(m0 + row) * DD + gcol, Al + u * 16);
      gll16(W + (size_t)(n0 + row) * DD + gcol, Bl + u * 16);
    }
    __syncthreads();
#pragma unroll
    for (int kc = 0; kc < 2; ++kc) {
      bf16x8 af[4], bfr[4];
#pragma unroll
      for (int mt = 0; mt < 4; ++mt) {
        int r = wr * 64 + mt * 16 + fr;
        af[mt] = *(const bf16x8*)(Al + r * 128 + (((kc * 4 + fg) ^ (r & 7)) << 4));
      }
#pragma unroll
      for (int nt = 0; nt < 4; ++nt) {
        int r = wc * 64 + nt * 16 + fr;
        bfr[nt] = *(const bf16x8*)(Bl + r * 128 + (((kc * 4 + fg) ^ (r & 7)) << 4));
      }
#pragma unroll
      for (int mt = 0; mt < 4; ++mt)
#pragma unroll
        for (int nt = 0; nt < 4; ++nt)
          acc[mt][nt] = MFMA16(af[mt], bfr[nt], acc[mt][nt]);
    }
  }

  float bs[4];
#pragma unroll
  for (int nt = 0; nt < 4; ++nt) bs[nt] = bias[n0 + wc * 64 + nt * 16 + fr];
#pragma unroll
  for (int mt = 0; mt < 4; ++mt)
#pragma unroll
    for (int nt = 0; nt < 4; ++nt) {
      int n = n0 + wc * 64 + nt * 16 + fr;
#pragma unroll
      for (int r = 0; r < 4; ++r) {
        int m = m0 + wr * 64 + mt * 16 + fg * 4 + r;
        float v = acc[mt][nt][r] + bs[nt];
        if (MODE == 1) v *= kScaling;
        if (MODE == 2) {
          int p = m >> 2, hh = n >> 6, d2 = n & 63;
          v += ew[(size_t)((hh << 8) + p) * HDD + d2];
        }
        if constexpr (sizeof(OUTT) == 2)
          C[(size_t)m * DD + n] = (OUTT)f2bf(v);
        else
          C[(size_t)m * DD + n] = v;
      }
    }
}

template <int MODE, typename OUTT>
__global__ __launch_bounds__(256) void k_gemm_mfma(
    const unsigned short* __restrict__ A, const unsigned short* __restrict__ W,
    const float* __restrict__ bias, const float* __restrict__ ew,
    OUTT* __restrict__ C) {
  __shared__ __align__(16) char Al[16384];
  __shared__ __align__(16) char Bl[16384];
  gemm_body<MODE, OUTT>(A, W, bias, ew, C, blockIdx.x * 128, blockIdx.y * 128, Al, Bl);
}

// K and V projections in one launch (blockIdx.z selects).
__global__ __launch_bounds__(256) void k_gemm_kv(
    const unsigned short* __restrict__ A,
    const unsigned short* __restrict__ Wk, const unsigned short* __restrict__ Wv,
    const float* __restrict__ kb, const float* __restrict__ vb,
    unsigned short* __restrict__ Ck, unsigned short* __restrict__ Cv) {
  __shared__ __align__(16) char Al[16384];
  __shared__ __align__(16) char Bl[16384];
  if (blockIdx.z == 0)
    gemm_body<0, unsigned short>(A, Wk, kb, nullptr, Ck,
                                 blockIdx.x * 128, blockIdx.y * 128, Al, Bl);
  else
    gemm_body<0, unsigned short>(A, Wv, vb, nullptr, Cv,
                                 blockIdx.x * 128, blockIdx.y * 128, Al, Bl);
}

// ---------------------------------------------------------------------------
// 256x256 GEMM, minimal-barrier schedule: 2 s_barrier + 2 lgkm drains +
// 1 counted vmcnt per K-tile (was 8 barriers). Region-race analysis:
//  - half1 reads cb.kc0; stages nb.kc1 (last read before prev end-barrier)
//  - mid barrier: all waves past kc0 reads -> half2 may stage cb.kc0
//  - half2 reads cb.kc1; stages cb.kc0 (for t+2); vmcnt(4) leaves half2's
//    4 loads in flight, drains half1's (t+1 data fully arrived)
// MFMA order per acc element unchanged (kc0 then kc1) -> bitwise identical.
// ---------------------------------------------------------------------------
template <int MODE, typename OUTT>
__global__ __launch_bounds__(512, 2) void k_gemm256(
    const unsigned short* __restrict__ A, const unsigned short* __restrict__ W,
    const float* __restrict__ bias, OUTT* __restrict__ C) {
  __shared__ __align__(16) char lds[131072];
  const int tid = threadIdx.x;
  const int wv = tid >> 6, lane = tid & 63;
  const int fr = lane & 15, fg = lane >> 4;
  const int wm = wv >> 2, wn = wv & 3;
  const int m0 = blockIdx.x * 256, n0 = blockIdx.y * 256;
  const int srow = tid >> 2, sslot = tid & 3;

  auto stageHalf = [&](const unsigned short* __restrict__ G, int g0, int colbase,
                       int dstBase) {
#pragma unroll
    for (int j = 0; j < 2; ++j) {
      int row = srow + j * 128;
      int gs = sslot ^ ((row >> 1) & 3);
      gll16(G + (size_t)(g0 + row) * DD + colbase + gs * 8,
            lds + dstBase + (tid + j * 512) * 16);
    }
  };
  auto rdA = [&](int mf, int kc, int cb) -> bf16x8 {
    int r = wm * 128 + mf * 16 + fr;
    return *(const bf16x8*)(lds + cb + kc * 16384 + r * 64 +
                            ((fg ^ ((r >> 1) & 3)) << 4));
  };
  auto rdB = [&](int nf, int kc, int cb) -> bf16x8 {
    int r = wn * 64 + nf * 16 + fr;
    return *(const bf16x8*)(lds + cb + 32768 + kc * 16384 + r * 64 +
                            ((fg ^ ((r >> 1) & 3)) << 4));
  };

  f32x4 acc[8][4];
#pragma unroll
  for (int i = 0; i < 8; ++i)
#pragma unroll
    for (int j = 0; j < 4; ++j) acc[i][j] = (f32x4){0.f, 0.f, 0.f, 0.f};
  bf16x8 a[8], b[4];

  // prologue: tile0 full (buf0) + tile1 kc0 halves (buf1)
  stageHalf(A, m0, 0, 0);
  stageHalf(W, n0, 0, 32768);
  stageHalf(A, m0, 32, 16384);
  stageHalf(W, n0, 32, 32768 + 16384);
  stageHalf(A, m0, 64, 65536);
  stageHalf(W, n0, 64, 65536 + 32768);
  asm volatile("s_waitcnt vmcnt(4)" ::: "memory");   // tile0 arrived
  __builtin_amdgcn_s_barrier();

  const int NT = DD / 64;   // 16
  for (int t = 0; t < NT; ++t) {
    const int cb = (t & 1) << 16;
    const int nb = cb ^ 65536;
    const int k1 = (t + 1) * 64, k2 = (t + 2) * 64;

    // ---- half 1: kc0 (all mf), stage t+1.kc1 into nb
#pragma unroll
    for (int i = 0; i < 8; ++i) a[i] = rdA(i, 0, cb);
#pragma unroll
    for (int i = 0; i < 4; ++i) b[i] = rdB(i, 0, cb);
    if (t + 1 < NT) {
      stageHalf(A, m0, k1 + 32, nb + 16384);
      stageHalf(W, n0, k1 + 32, nb + 32768 + 16384);
    }
    asm volatile("s_waitcnt lgkmcnt(0)" ::: "memory");
    __builtin_amdgcn_sched_barrier(0);
    __builtin_amdgcn_s_setprio(1);
#pragma unroll
    for (int mf = 0; mf < 8; ++mf)
#pragma unroll
      for (int nf = 0; nf < 4; ++nf)
        acc[mf][nf] = MFMA16(a[mf], b[nf], acc[mf][nf]);
    __builtin_amdgcn_s_setprio(0);
    __builtin_amdgcn_s_barrier();   // mid: kc0 reads done across waves

    // ---- half 2: kc1 (all mf), stage t+2.kc0 into cb
#pragma unroll
    for (int i = 0; i < 8; ++i) a[i] = rdA(i, 1, cb);
#pragma unroll
    for (int i = 0; i < 4; ++i) b[i] = rdB(i, 1, cb);
    if (t + 2 < NT) {
      stageHalf(A, m0, k2, cb);
      stageHalf(W, n0, k2, cb + 32768);
    }
    asm volatile("s_waitcnt lgkmcnt(0)" ::: "memory");
    __builtin_amdgcn_sched_barrier(0);
    __builtin_amdgcn_s_setprio(1);
#pragma unroll
    for (int mf = 0; mf < 8; ++mf)
#pragma unroll
      for (int nf = 0; nf < 4; ++nf)
        acc[mf][nf] = MFMA16(a[mf], b[nf], acc[mf][nf]);
    __builtin_amdgcn_s_setprio(0);
    if (t + 2 < NT) {
      asm volatile("s_waitcnt vmcnt(4)" ::: "memory");   // t+1 fully arrived
    } else if (t + 1 < NT) {
      asm volatile("s_waitcnt vmcnt(0)" ::: "memory");   // drain for last tile
    }
    __builtin_amdgcn_s_barrier();   // end of tile
  }

  float bs[4];
#pragma unroll
  for (int nf = 0; nf < 4; ++nf) bs[nf] = bias[n0 + wn * 64 + nf * 16 + fr];
#pragma unroll
  for (int mf = 0; mf < 8; ++mf)
#pragma unroll
    for (int nf = 0; nf < 4; ++nf) {
      int n = n0 + wn * 64 + nf * 16 + fr;
#pragma unroll
      for (int r = 0; r < 4; ++r) {
        int m = m0 + wm * 128 + mf * 16 + fg * 4 + r;
        float v = acc[mf][nf][r] + bs[nf];
        if (MODE == 1) v *= kScaling;
        if constexpr (sizeof(OUTT) == 2)
          C[(size_t)m * DD + n] = (OUTT)f2bf(v);
        else
          C[(size_t)m * DD + n] = v;
      }
    }
}

// LayerNorm over D=1024; fp32 in -> bf16 out. One block per row.
__global__ __launch_bounds__(256) void k_ln(const float* __restrict__ x,
                                            const float* __restrict__ g,
                                            const float* __restrict__ bb,
                                            unsigned short* __restrict__ y) {
  const int r = blockIdx.x;
  const int tid = threadIdx.x;
  const float* xr = x + (size_t)r * DD;
  float4 v = *(const float4*)(xr + tid * 4);
  float s1 = v.x + v.y + v.z + v.w;
  float s2 = v.x * v.x + v.y * v.y + v.z * v.z + v.w * v.w;
#pragma unroll
  for (int off = 32; off > 0; off >>= 1) {
    s1 += __shfl_down(s1, off);
    s2 += __shfl_down(s2, off);
  }
  __shared__ float w1[4], w2[4];
  if ((tid & 63) == 0) { w1[tid >> 6] = s1; w2[tid >> 6] = s2; }
  __syncthreads();
  float S1 = w1[0] + w1[1] + w1[2] + w1[3];
  float S2 = w2[0] + w2[1] + w2[2] + w2[3];
  float mean = S1 * (1.f / DD);
  float var = S2 * (1.f / DD) - mean * mean;
  float rstd = rsqrtf(var + kEps);
  float4 gv = *(const float4*)(g + tid * 4);
  float4 bv = *(const float4*)(bb + tid * 4);
  short4v o;
  o[0] = (short)f2bf((v.x - mean) * rstd * gv.x + bv.x);
  o[1] = (short)f2bf((v.y - mean) * rstd * gv.y + bv.y);
  o[2] = (short)f2bf((v.z - mean) * rstd * gv.z + bv.z);
  o[3] = (short)f2bf((v.w - mean) * rstd * gv.w + bv.w);
  *(short4v*)(y + (size_t)r * DD + tid * 4) = o;
}

// ---------------------------------------------------------------------------
// Attention: QBLK=128, Vt staged via packed p-pair ds_write_b32.
// Two KV halves of 128 p; LDS 64KB -> 2 blocks/CU. 8 waves x 16 q-rows.
// ---------------------------------------------------------------------------
__global__ __launch_bounds__(512, 2) void k_attn_mfma(
    const unsigned short* __restrict__ qbf, const unsigned short* __restrict__ kbf,
    const unsigned short* __restrict__ vbf, unsigned short* __restrict__ attn) {
  const int bh = blockIdx.y;
  const int b = bh >> 4, h = bh & 15;
  const int tid = threadIdx.x, wv = tid >> 6, lane = tid & 63;
  const int fr = lane & 15, fg = lane >> 4;
  const int bl0 = blockIdx.x * 128;

  __shared__ __align__(16) char Kl[16384];    // [128p][64d] swz rows of 128B
  __shared__ __align__(16) char Vt[16384];    // 2 chunks of [64 dd][64 p]
  __shared__ __align__(16) char Pl[32768];    // 8 waves x [16 l][128 p]

  const size_t qrow = ((size_t)(bl0 + wv * 16 + fr) * BB + b) * DD + h * HDD;
  bf16x8 qf0 = *(const bf16x8*)(qbf + qrow + fg * 8);
  bf16x8 qf1 = *(const bf16x8*)(qbf + qrow + 32 + fg * 8);

  f32x4 o[4];
#pragma unroll
  for (int dt = 0; dt < 4; ++dt) o[dt] = (f32x4){0.f, 0.f, 0.f, 0.f};
  float psum = 0.f;
  char* Pw = Pl + wv * 4096;

  for (int ph = 0; ph < 2; ++ph) {
    __syncthreads();    // prev PV reads done; LDS safe to overwrite
#pragma unroll
    for (int j = 0; j < 2; ++j) {
      int u = tid + j * 512;
      int p = u >> 3, slot = u & 7;
      gll16(kbf + ((size_t)((ph * 128 + p) * BB + b)) * DD + h * HDD +
                8 * (slot ^ (p & 7)),
            Kl + u * 16);
    }
    {
      int p2 = tid >> 3, c8 = tid & 7;
      int p0 = ph * 128 + 2 * p2;
      const unsigned short* vp = vbf + ((size_t)(p0 * BB + b)) * DD + h * HDD + c8 * 8;
      bf16x8 v0 = *(const bf16x8*)vp;
      bf16x8 v1 = *(const bf16x8*)(vp + BB * DD);
      int pl = (2 * p2) & 63, pc = p2 >> 5;
      char* base = Vt + pc * 8192;
#pragma unroll
      for (int i = 0; i < 8; ++i) {
        int dd = c8 * 8 + i;
        unsigned int packed = (unsigned int)(unsigned short)v0[i] |
                              ((unsigned int)(unsigned short)v1[i] << 16);
        *(unsigned int*)(base + dd * 128 +
            ((((pl >> 3) ^ (dd & 7) ^ (dd >> 3)) & 7) << 4) + ((pl & 7) << 1)) = packed;
      }
    }
    __syncthreads();    // includes vmcnt(0)+lgkmcnt(0) drain

    f32x4 s[8];
    __builtin_amdgcn_s_setprio(1);
#pragma unroll
    for (int pt = 0; pt < 8; ++pt) {
      int pr = pt * 16 + fr;
      bf16x8 a0 = *(const bf16x8*)(Kl + pr * 128 + ((fg ^ (pr & 7)) << 4));
      bf16x8 a1 = *(const bf16x8*)(Kl + pr * 128 + (((4 + fg) ^ (pr & 7)) << 4));
      f32x4 acc = (f32x4){0.f, 0.f, 0.f, 0.f};
      acc = MFMA16(a0, qf0, acc);
      acc = MFMA16(a1, qf1, acc);
      s[pt] = acc;
    }
    __builtin_amdgcn_s_setprio(0);

#pragma unroll
    for (int pt = 0; pt < 8; ++pt) {
      float e0 = __expf(s[pt][0]), e1 = __expf(s[pt][1]);
      float e2 = __expf(s[pt][2]), e3 = __expf(s[pt][3]);
      psum += (e0 + e1) + (e2 + e3);
      short4v pk;
      pk[0] = (short)f2bf(e0); pk[1] = (short)f2bf(e1);
      pk[2] = (short)f2bf(e2); pk[3] = (short)f2bf(e3);
      int pbyte = (pt * 16 + fg * 4) * 2;
      int slot = pbyte >> 4, rem = pbyte & 15;
      *(short4v*)(Pw + fr * 256 + ((slot ^ (fr & 7)) << 4) + rem) = pk;
    }
    asm volatile("s_waitcnt lgkmcnt(0)" ::: "memory");
    __builtin_amdgcn_sched_barrier(0);

    __builtin_amdgcn_s_setprio(1);
#pragma unroll
    for (int kc = 0; kc < 4; ++kc) {
      int slot = kc * 4 + fg;
      bf16x8 pa = *(const bf16x8*)(Pw + fr * 256 + ((slot ^ (fr & 7)) << 4));
      int sl2 = (kc & 1) * 4 + fg;
#pragma unroll
      for (int dt = 0; dt < 4; ++dt) {
        int dd = dt * 16 + fr;
        bf16x8 vb = *(const bf16x8*)(Vt + (kc >> 1) * 8192 + dd * 128 +
                     (((sl2 ^ (dd & 7) ^ (dd >> 3)) & 7) << 4));
        o[dt] = MFMA16(pa, vb, o[dt]);
      }
    }
    __builtin_amdgcn_s_setprio(0);
  }

  psum += __shfl_xor(psum, 16);
  psum += __shfl_xor(psum, 32);

#pragma unroll
  for (int r = 0; r < 4; ++r) {
    int lloc = fg * 4 + r;
    float inv = 1.f / __shfl(psum, lloc);
    unsigned short* op = attn +
        ((size_t)(bl0 + wv * 16 + lloc) * BB + b) * DD + h * HDD;
#pragma unroll
    for (int dt = 0; dt < 4; ++dt)
      op[dt * 16 + fr] = f2bf(o[dt][r] * inv);
  }
}

extern "C" void kernel_launch(void* const* d_in, const int* in_sizes, int n_in,
                              void* d_out, int out_size, void* d_ws, size_t ws_size,
                              hipStream_t stream) {
  const float* query   = (const float*)d_in[0];
  const float* q_w     = (const float*)d_in[1];
  const float* q_b     = (const float*)d_in[2];
  const float* k_w     = (const float*)d_in[3];
  const float* k_b     = (const float*)d_in[4];
  const float* v_w     = (const float*)d_in[5];
  const float* v_b     = (const float*)d_in[6];
  const float* e_weight= (const float*)d_in[7];
  const float* e_out_w = (const float*)d_in[8];
  const float* e_out_b = (const float*)d_in[9];
  const float* ln_g    = (const float*)d_in[10];
  const float* ln_b    = (const float*)d_in[11];
  const float* out_w   = (const float*)d_in[12];
  const float* out_b   = (const float*)d_in[13];
  float* out = (float*)d_out;

  char* w = (char*)d_ws;
  unsigned short* parts   = (unsigned short*)w;                 // 32 MB, dead after reduce
  unsigned short* q_bf    = (unsigned short*)w;                 // 32 MB (alias, after reduce)
  unsigned short* attn_bf = (unsigned short*)(w + (32u << 20)); // 32 MB
  unsigned short* query_bf= (unsigned short*)(w + (64u << 20)); // 32 MB
  unsigned short* kv_raw  = (unsigned short*)(w + (96u << 20)); // 2 MB
  float* kv_eo            = (float*)(w + (98u << 20));          // 4 MB
  unsigned short* kv_ln   = (unsigned short*)(w + (102u << 20));// 2 MB
  unsigned short* k_buf   = (unsigned short*)(w + (104u << 20));// 2 MB
  unsigned short* v_buf   = (unsigned short*)(w + (106u << 20));// 2 MB
  unsigned short* wq  = (unsigned short*)(w + (108u << 20));
  unsigned short* wk  = (unsigned short*)(w + (110u << 20));
  unsigned short* wv_ = (unsigned short*)(w + (112u << 20));
  unsigned short* weo = (unsigned short*)(w + (114u << 20));
  unsigned short* wo  = (unsigned short*)(w + (116u << 20));
  unsigned short* ewb = (unsigned short*)(w + (118u << 20));    // 0.5 MB

  k_cvt_all<<<10880, 256, 0, stream>>>(query, q_w, k_w, v_w, e_out_w, out_w, e_weight,
                                       query_bf, wq, wk, wv_, weo, wo, ewb);

  k_compress_mfma<<<dim3(64, LC), 256, 0, stream>>>(query_bf, ewb, parts);
  k_reduce<<<4096, 256, 0, stream>>>(parts, kv_raw);
  k_gemm_mfma<2, float><<<dim3(8, 8), 256, 0, stream>>>(kv_raw, weo, e_out_b, e_weight, kv_eo);
  k_ln<<<PP * BB, 256, 0, stream>>>(kv_eo, ln_g, ln_b, kv_ln);
  k_gemm256<1, unsigned short><<<dim3(64, 4), 512, 0, stream>>>(query_bf, wq, q_b, q_bf);
  k_gemm_kv<<<dim3(8, 8, 2), 256, 0, stream>>>(kv_ln, wk, wv_, k_b, v_b, k_buf, v_buf);
  k_attn_mfma<<<dim3(32, 64), 512, 0, stream>>>(q_bf, k_buf, v_buf, attn_bf);
  k_gemm256<0, float><<<dim3(64, 4), 512, 0, stream>>>(attn_bf, wo, out_b, out);
}

// Round 11
// 209.788 us; speedup vs baseline: 12.1670x; 1.0152x over previous
//
#include <hip/hip_runtime.h>
#include <hip/hip_bf16.h>
#include <cstdint>
#include <cstddef>

#define LL 4096
#define BB 4
#define DD 1024
#define HH 16
#define PP 256
#define HDD 64
#define LC 16
#define LCHUNK 256

constexpr float kScaling = 0.125f;   // HD^-0.5
constexpr float kEps = 1e-5f;

typedef __attribute__((ext_vector_type(8))) short bf16x8;   // 8 bf16 = 4 VGPR
typedef __attribute__((ext_vector_type(4))) short short4v;
typedef __attribute__((ext_vector_type(4))) float f32x4;

#define MFMA16(a, b, c) __builtin_amdgcn_mfma_f32_16x16x32_bf16((a), (b), (c), 0, 0, 0)

__device__ __forceinline__ unsigned short f2bf(float f) {
  unsigned int u = __builtin_bit_cast(unsigned int, f);
  u += 0x7FFFu + ((u >> 16) & 1u);           // round-to-nearest-even
  return (unsigned short)(u >> 16);
}
__device__ __forceinline__ float bf2f(unsigned short u) {
  return __builtin_bit_cast(float, ((unsigned int)u) << 16);
}

__device__ __forceinline__ void gll16(const void* g, void* l) {
  __builtin_amdgcn_global_load_lds(
      (const __attribute__((address_space(1))) unsigned int*)g,
      (__attribute__((address_space(3))) unsigned int*)l, 16, 0, 0);
}

// ---------------------------------------------------------------------------
// Weights-only fp32 -> bf16 convert (query cvt now lives inside compress).
// Units of 8 elems: 5 x 131072 (1024x1024 weights) + 32768 (e_weight).
// ---------------------------------------------------------------------------
__global__ __launch_bounds__(256) void k_cvt_w(
    const float* __restrict__ w0, const float* __restrict__ w1,
    const float* __restrict__ w2, const float* __restrict__ w3,
    const float* __restrict__ w4, const float* __restrict__ w5,
    unsigned short* __restrict__ d0, unsigned short* __restrict__ d1,
    unsigned short* __restrict__ d2, unsigned short* __restrict__ d3,
    unsigned short* __restrict__ d4, unsigned short* __restrict__ d5) {
  int i = blockIdx.x * 256 + threadIdx.x;
  int w = i >> 17, off = i & 131071;
  const float* src; unsigned short* dst;
  if (w == 0) { src = w0; dst = d0; }
  else if (w == 1) { src = w1; dst = d1; }
  else if (w == 2) { src = w2; dst = d2; }
  else if (w == 3) { src = w3; dst = d3; }
  else if (w == 4) { src = w4; dst = d4; }
  else { if (off >= 32768) return; src = w5; dst = d5; }
  const float4* s = (const float4*)(src + (size_t)off * 8);
  float4 a = s[0], b = s[1];
  bf16x8 o;
  o[0] = f2bf(a.x); o[1] = f2bf(a.y); o[2] = f2bf(a.z); o[3] = f2bf(a.w);
  o[4] = f2bf(b.x); o[5] = f2bf(b.y); o[6] = f2bf(b.z); o[7] = f2bf(b.w);
  *(bf16x8*)(dst + (size_t)off * 8) = o;
}

// ---------------------------------------------------------------------------
// Compress (MFMA) + inline query fp32->bf16 cvt (writes query_bf for q-proj).
// Xtl transpose staged as packed p-pair ds_write_b32.
// ---------------------------------------------------------------------------
__global__ __launch_bounds__(256) void k_compress_mfma(
    const float* __restrict__ q32, const unsigned short* __restrict__ ewbf,
    unsigned short* __restrict__ qbf_out, unsigned short* __restrict__ parts) {
  const int bh = blockIdx.x, lc = blockIdx.y;
  const int b = bh >> 4, h = bh & 15;
  const int tid = threadIdx.x, wv = tid >> 6, lane = tid & 63;
  const int fr = lane & 15, fg = lane >> 4;

  __shared__ __align__(16) char Xl[8192];    // [l][d] rows of 128B
  __shared__ __align__(16) char Xtl[8192];   // [d][l]
  __shared__ __align__(16) char Pl[32768];   // [p][l] rows of 128B

  bf16x8 ef[4][2];
#pragma unroll
  for (int pt = 0; pt < 4; ++pt)
#pragma unroll
    for (int kc = 0; kc < 2; ++kc)
      ef[pt][kc] = *(const bf16x8*)(ewbf +
          (size_t)((h * PP + wv * 64 + pt * 16 + fr) * HDD) + kc * 32 + fg * 8);

  f32x4 acc[4][4];
#pragma unroll
  for (int i = 0; i < 4; ++i)
#pragma unroll
    for (int j = 0; j < 4; ++j) acc[i][j] = (f32x4){0.f, 0.f, 0.f, 0.f};

  const int l0 = lc * LCHUNK;
  for (int t = 0; t < 4; ++t) {
    __syncthreads();
    {
      int l2 = tid >> 3, c8 = tid & 7;
      int l = 2 * l2;
      size_t rowbase = ((size_t)(l0 + t * 64 + l) * BB + b) * DD + h * HDD + c8 * 8;
      const float* xp = q32 + rowbase;
      float4 a0 = *(const float4*)xp;
      float4 a1 = *(const float4*)(xp + 4);
      float4 b0 = *(const float4*)(xp + BB * DD);
      float4 b1 = *(const float4*)(xp + BB * DD + 4);
      bf16x8 v0, v1;
      v0[0] = f2bf(a0.x); v0[1] = f2bf(a0.y); v0[2] = f2bf(a0.z); v0[3] = f2bf(a0.w);
      v0[4] = f2bf(a1.x); v0[5] = f2bf(a1.y); v0[6] = f2bf(a1.z); v0[7] = f2bf(a1.w);
      v1[0] = f2bf(b0.x); v1[1] = f2bf(b0.y); v1[2] = f2bf(b0.z); v1[3] = f2bf(b0.w);
      v1[4] = f2bf(b1.x); v1[5] = f2bf(b1.y); v1[6] = f2bf(b1.z); v1[7] = f2bf(b1.w);
      // global bf16 copy for q-proj (each (l,b,h,d) written exactly once)
      *(bf16x8*)(qbf_out + rowbase) = v0;
      *(bf16x8*)(qbf_out + rowbase + BB * DD) = v1;
      // LDS tiles (unchanged layout)
      *(bf16x8*)(Xl + l * 128 + ((c8 ^ (l & 7)) << 4)) = v0;
      *(bf16x8*)(Xl + (l + 1) * 128 + ((c8 ^ ((l + 1) & 7)) << 4)) = v1;
#pragma unroll
      for (int i = 0; i < 8; ++i) {
        int dd = c8 * 8 + i;
        unsigned int packed = (unsigned int)(unsigned short)v0[i] |
                              ((unsigned int)(unsigned short)v1[i] << 16);
        *(unsigned int*)(Xtl + dd * 128 +
            ((((l >> 3) ^ (dd & 7) ^ (dd >> 3)) & 7) << 4) + ((l & 7) << 1)) = packed;
      }
    }
    __syncthreads();
#pragma unroll
    for (int lt = 0; lt < 4; ++lt) {
      int rl = lt * 16 + fr;
      bf16x8 xa0 = *(const bf16x8*)(Xl + rl * 128 + (((0 + fg) ^ (rl & 7)) << 4));
      bf16x8 xa1 = *(const bf16x8*)(Xl + rl * 128 + (((4 + fg) ^ (rl & 7)) << 4));
#pragma unroll
      for (int pt = 0; pt < 4; ++pt) {
        f32x4 s = (f32x4){0.f, 0.f, 0.f, 0.f};
        s = MFMA16(xa0, ef[pt][0], s);
        s = MFMA16(xa1, ef[pt][1], s);
        short4v pk;
#pragma unroll
        for (int r = 0; r < 4; ++r)
          pk[r] = (short)f2bf(fmaxf(s[r] * kScaling, 0.f));
        int p = wv * 64 + pt * 16 + fr;
        int lbase = lt * 16 + fg * 4;
        int slot = lbase >> 3;
        *(short4v*)(Pl + p * 128 + ((slot ^ (p & 7)) << 4) + ((lbase & 7) << 1)) = pk;
      }
    }
    asm volatile("s_waitcnt lgkmcnt(0)" ::: "memory");
    __builtin_amdgcn_sched_barrier(0);
#pragma unroll
    for (int kc = 0; kc < 2; ++kc) {
      bf16x8 pa[4], xb[4];
#pragma unroll
      for (int pt = 0; pt < 4; ++pt) {
        int p = wv * 64 + pt * 16 + fr;
        pa[pt] = *(const bf16x8*)(Pl + p * 128 + (((kc * 4 + fg) ^ (p & 7)) << 4));
      }
#pragma unroll
      for (int dt = 0; dt < 4; ++dt) {
        int dd = dt * 16 + fr;
        xb[dt] = *(const bf16x8*)(Xtl + dd * 128 +
                  ((((kc * 4 + fg) ^ (dd & 7) ^ (dd >> 3)) & 7) << 4));
      }
#pragma unroll
      for (int pt = 0; pt < 4; ++pt)
#pragma unroll
        for (int dt = 0; dt < 4; ++dt)
          acc[pt][dt] = MFMA16(pa[pt], xb[dt], acc[pt][dt]);
    }
  }
  unsigned short* op = parts + (size_t)(lc * 64 + bh) * PP * HDD;
#pragma unroll
  for (int pt = 0; pt < 4; ++pt)
#pragma unroll
    for (int dt = 0; dt < 4; ++dt)
#pragma unroll
      for (int r = 0; r < 4; ++r) {
        int p = wv * 64 + pt * 16 + fg * 4 + r;
        int dd = dt * 16 + fr;
        op[(size_t)p * HDD + dd] = f2bf(acc[pt][dt][r]);
      }
}

// Sum LC bf16 partials -> kv_raw bf16 as (P,B,D); vectorized x8.
__global__ __launch_bounds__(256) void k_reduce(const unsigned short* __restrict__ parts,
                                                unsigned short* __restrict__ kv_raw_bf) {
  int u = blockIdx.x * 256 + threadIdx.x;     // 131072 units of 8 elems
  size_t off = (size_t)u * 8;
  float s[8] = {0.f, 0.f, 0.f, 0.f, 0.f, 0.f, 0.f, 0.f};
#pragma unroll
  for (int lcc = 0; lcc < LC; ++lcc) {
    bf16x8 v = *(const bf16x8*)(parts + (size_t)lcc * (64 * PP * HDD) + off);
#pragma unroll
    for (int j = 0; j < 8; ++j) s[j] += bf2f((unsigned short)v[j]);
  }
  int i = (int)off;
  int d = i & 63, p = (i >> 6) & 255, bh = i >> 14;
  int b = bh >> 4, h = bh & 15;
  bf16x8 o;
#pragma unroll
  for (int j = 0; j < 8; ++j) o[j] = (short)f2bf(s[j]);
  *(bf16x8*)(kv_raw_bf + (size_t)(p * BB + b) * DD + h * HDD + d) = o;
}

// ---------------------------------------------------------------------------
// 128x128 GEMM body (small P=1024-row GEMMs).
// ---------------------------------------------------------------------------
template <int MODE, typename OUTT>
__device__ __forceinline__ void gemm_body(
    const unsigned short* __restrict__ A, const unsigned short* __restrict__ W,
    const float* __restrict__ bias, const float* __restrict__ ew,
    OUTT* __restrict__ C, int m0, int n0, char* Al, char* Bl) {
  const int tid = threadIdx.x;
  const int wv = tid >> 6, lane = tid & 63;
  const int fr = lane & 15, fg = lane >> 4;
  const int wr = wv >> 1, wc = wv & 1;

  f32x4 acc[4][4];
#pragma unroll
  for (int i = 0; i < 4; ++i)
#pragma unroll
    for (int j = 0; j < 4; ++j) acc[i][j] = (f32x4){0.f, 0.f, 0.f, 0.f};

  for (int k0 = 0; k0 < DD; k0 += 64) {
    __syncthreads();
#pragma unroll
    for (int j = 0; j < 4; ++j) {
      int u = tid + j * 256;
      int row = u >> 3, slot = u & 7;
      size_t gcol = (size_t)(k0 + 8 * (slot ^ (row & 7)));
      gll16(A + (size_t)(m0 + row) * DD + gcol, Al + u * 16);
      gll16(W + (size_t)(n0 + row) * DD + gcol, Bl + u * 16);
    }
    __syncthreads();
#pragma unroll
    for (int kc = 0; kc < 2; ++kc) {
      bf16x8 af[4], bfr[4];
#pragma unroll
      for (int mt = 0; mt < 4; ++mt) {
        int r = wr * 64 + mt * 16 + fr;
        af[mt] = *(const bf16x8*)(Al + r * 128 + (((kc * 4 + fg) ^ (r & 7)) << 4));
      }
#pragma unroll
      for (int nt = 0; nt < 4; ++nt) {
        int r = wc * 64 + nt * 16 + fr;
        bfr[nt] = *(const bf16x8*)(Bl + r * 128 + (((kc * 4 + fg) ^ (r & 7)) << 4));
      }
#pragma unroll
      for (int mt = 0; mt < 4; ++mt)
#pragma unroll
        for (int nt = 0; nt < 4; ++nt)
          acc[mt][nt] = MFMA16(af[mt], bfr[nt], acc[mt][nt]);
    }
  }

  float bs[4];
#pragma unroll
  for (int nt = 0; nt < 4; ++nt) bs[nt] = bias[n0 + wc * 64 + nt * 16 + fr];
#pragma unroll
  for (int mt = 0; mt < 4; ++mt)
#pragma unroll
    for (int nt = 0; nt < 4; ++nt) {
      int n = n0 + wc * 64 + nt * 16 + fr;
#pragma unroll
      for (int r = 0; r < 4; ++r) {
        int m = m0 + wr * 64 + mt * 16 + fg * 4 + r;
        float v = acc[mt][nt][r] + bs[nt];
        if (MODE == 1) v *= kScaling;
        if (MODE == 2) {
          int p = m >> 2, hh = n >> 6, d2 = n & 63;
          v += ew[(size_t)((hh << 8) + p) * HDD + d2];
        }
        if constexpr (sizeof(OUTT) == 2)
          C[(size_t)m * DD + n] = (OUTT)f2bf(v);
        else
          C[(size_t)m * DD + n] = v;
      }
    }
}

template <int MODE, typename OUTT>
__global__ __launch_bounds__(256) void k_gemm_mfma(
    const unsigned short* __restrict__ A, const unsigned short* __restrict__ W,
    const float* __restrict__ bias, const float* __restrict__ ew,
    OUTT* __restrict__ C) {
  __shared__ __align__(16) char Al[16384];
  __shared__ __align__(16) char Bl[16384];
  gemm_body<MODE, OUTT>(A, W, bias, ew, C, blockIdx.x * 128, blockIdx.y * 128, Al, Bl);
}

// K and V projections in one launch (blockIdx.z selects).
__global__ __launch_bounds__(256) void k_gemm_kv(
    const unsigned short* __restrict__ A,
    const unsigned short* __restrict__ Wk, const unsigned short* __restrict__ Wv,
    const float* __restrict__ kb, const float* __restrict__ vb,
    unsigned short* __restrict__ Ck, unsigned short* __restrict__ Cv) {
  __shared__ __align__(16) char Al[16384];
  __shared__ __align__(16) char Bl[16384];
  if (blockIdx.z == 0)
    gemm_body<0, unsigned short>(A, Wk, kb, nullptr, Ck,
                                 blockIdx.x * 128, blockIdx.y * 128, Al, Bl);
  else
    gemm_body<0, unsigned short>(A, Wv, vb, nullptr, Cv,
                                 blockIdx.x * 128, blockIdx.y * 128, Al, Bl);
}

// ---------------------------------------------------------------------------
// 256x256 GEMM, minimal-barrier schedule (unchanged from round 10).
// ---------------------------------------------------------------------------
template <int MODE, typename OUTT>
__global__ __launch_bounds__(512, 2) void k_gemm256(
    const unsigned short* __restrict__ A, const unsigned short* __restrict__ W,
    const float* __restrict__ bias, OUTT* __restrict__ C) {
  __shared__ __align__(16) char lds[131072];
  const int tid = threadIdx.x;
  const int wv = tid >> 6, lane = tid & 63;
  const int fr = lane & 15, fg = lane >> 4;
  const int wm = wv >> 2, wn = wv & 3;
  const int m0 = blockIdx.x * 256, n0 = blockIdx.y * 256;
  const int srow = tid >> 2, sslot = tid & 3;

  auto stageHalf = [&](const unsigned short* __restrict__ G, int g0, int colbase,
                       int dstBase) {
#pragma unroll
    for (int j = 0; j < 2; ++j) {
      int row = srow + j * 128;
      int gs = sslot ^ ((row >> 1) & 3);
      gll16(G + (size_t)(g0 + row) * DD + colbase + gs * 8,
            lds + dstBase + (tid + j * 512) * 16);
    }
  };
  auto rdA = [&](int mf, int kc, int cb) -> bf16x8 {
    int r = wm * 128 + mf * 16 + fr;
    return *(const bf16x8*)(lds + cb + kc * 16384 + r * 64 +
                            ((fg ^ ((r >> 1) & 3)) << 4));
  };
  auto rdB = [&](int nf, int kc, int cb) -> bf16x8 {
    int r = wn * 64 + nf * 16 + fr;
    return *(const bf16x8*)(lds + cb + 32768 + kc * 16384 + r * 64 +
                            ((fg ^ ((r >> 1) & 3)) << 4));
  };

  f32x4 acc[8][4];
#pragma unroll
  for (int i = 0; i < 8; ++i)
#pragma unroll
    for (int j = 0; j < 4; ++j) acc[i][j] = (f32x4){0.f, 0.f, 0.f, 0.f};
  bf16x8 a[8], b[4];

  stageHalf(A, m0, 0, 0);
  stageHalf(W, n0, 0, 32768);
  stageHalf(A, m0, 32, 16384);
  stageHalf(W, n0, 32, 32768 + 16384);
  stageHalf(A, m0, 64, 65536);
  stageHalf(W, n0, 64, 65536 + 32768);
  asm volatile("s_waitcnt vmcnt(4)" ::: "memory");   // tile0 arrived
  __builtin_amdgcn_s_barrier();

  const int NT = DD / 64;   // 16
  for (int t = 0; t < NT; ++t) {
    const int cb = (t & 1) << 16;
    const int nb = cb ^ 65536;
    const int k1 = (t + 1) * 64, k2 = (t + 2) * 64;

    // ---- half 1: kc0 (all mf), stage t+1.kc1 into nb
#pragma unroll
    for (int i = 0; i < 8; ++i) a[i] = rdA(i, 0, cb);
#pragma unroll
    for (int i = 0; i < 4; ++i) b[i] = rdB(i, 0, cb);
    if (t + 1 < NT) {
      stageHalf(A, m0, k1 + 32, nb + 16384);
      stageHalf(W, n0, k1 + 32, nb + 32768 + 16384);
    }
    asm volatile("s_waitcnt lgkmcnt(0)" ::: "memory");
    __builtin_amdgcn_sched_barrier(0);
    __builtin_amdgcn_s_setprio(1);
#pragma unroll
    for (int mf = 0; mf < 8; ++mf)
#pragma unroll
      for (int nf = 0; nf < 4; ++nf)
        acc[mf][nf] = MFMA16(a[mf], b[nf], acc[mf][nf]);
    __builtin_amdgcn_s_setprio(0);
    __builtin_amdgcn_s_barrier();   // mid: kc0 reads done across waves

    // ---- half 2: kc1 (all mf), stage t+2.kc0 into cb
#pragma unroll
    for (int i = 0; i < 8; ++i) a[i] = rdA(i, 1, cb);
#pragma unroll
    for (int i = 0; i < 4; ++i) b[i] = rdB(i, 1, cb);
    if (t + 2 < NT) {
      stageHalf(A, m0, k2, cb);
      stageHalf(W, n0, k2, cb + 32768);
    }
    asm volatile("s_waitcnt lgkmcnt(0)" ::: "memory");
    __builtin_amdgcn_sched_barrier(0);
    __builtin_amdgcn_s_setprio(1);
#pragma unroll
    for (int mf = 0; mf < 8; ++mf)
#pragma unroll
      for (int nf = 0; nf < 4; ++nf)
        acc[mf][nf] = MFMA16(a[mf], b[nf], acc[mf][nf]);
    __builtin_amdgcn_s_setprio(0);
    if (t + 2 < NT) {
      asm volatile("s_waitcnt vmcnt(4)" ::: "memory");   // t+1 fully arrived
    } else if (t + 1 < NT) {
      asm volatile("s_waitcnt vmcnt(0)" ::: "memory");   // drain for last tile
    }
    __builtin_amdgcn_s_barrier();   // end of tile
  }

  float bs[4];
#pragma unroll
  for (int nf = 0; nf < 4; ++nf) bs[nf] = bias[n0 + wn * 64 + nf * 16 + fr];
#pragma unroll
  for (int mf = 0; mf < 8; ++mf)
#pragma unroll
    for (int nf = 0; nf < 4; ++nf) {
      int n = n0 + wn * 64 + nf * 16 + fr;
#pragma unroll
      for (int r = 0; r < 4; ++r) {
        int m = m0 + wm * 128 + mf * 16 + fg * 4 + r;
        float v = acc[mf][nf][r] + bs[nf];
        if (MODE == 1) v *= kScaling;
        if constexpr (sizeof(OUTT) == 2)
          C[(size_t)m * DD + n] = (OUTT)f2bf(v);
        else
          C[(size_t)m * DD + n] = v;
      }
    }
}

// LayerNorm over D=1024; fp32 in -> bf16 out. One block per row.
__global__ __launch_bounds__(256) void k_ln(const float* __restrict__ x,
                                            const float* __restrict__ g,
                                            const float* __restrict__ bb,
                                            unsigned short* __restrict__ y) {
  const int r = blockIdx.x;
  const int tid = threadIdx.x;
  const float* xr = x + (size_t)r * DD;
  float4 v = *(const float4*)(xr + tid * 4);
  float s1 = v.x + v.y + v.z + v.w;
  float s2 = v.x * v.x + v.y * v.y + v.z * v.z + v.w * v.w;
#pragma unroll
  for (int off = 32; off > 0; off >>= 1) {
    s1 += __shfl_down(s1, off);
    s2 += __shfl_down(s2, off);
  }
  __shared__ float w1[4], w2[4];
  if ((tid & 63) == 0) { w1[tid >> 6] = s1; w2[tid >> 6] = s2; }
  __syncthreads();
  float S1 = w1[0] + w1[1] + w1[2] + w1[3];
  float S2 = w2[0] + w2[1] + w2[2] + w2[3];
  float mean = S1 * (1.f / DD);
  float var = S2 * (1.f / DD) - mean * mean;
  float rstd = rsqrtf(var + kEps);
  float4 gv = *(const float4*)(g + tid * 4);
  float4 bv = *(const float4*)(bb + tid * 4);
  short4v o;
  o[0] = (short)f2bf((v.x - mean) * rstd * gv.x + bv.x);
  o[1] = (short)f2bf((v.y - mean) * rstd * gv.y + bv.y);
  o[2] = (short)f2bf((v.z - mean) * rstd * gv.z + bv.z);
  o[3] = (short)f2bf((v.w - mean) * rstd * gv.w + bv.w);
  *(short4v*)(y + (size_t)r * DD + tid * 4) = o;
}

// ---------------------------------------------------------------------------
// Attention: QBLK=128, Vt staged via packed p-pair ds_write_b32.
// Two KV halves of 128 p; LDS 64KB -> 2 blocks/CU. 8 waves x 16 q-rows.
// ---------------------------------------------------------------------------
__global__ __launch_bounds__(512, 2) void k_attn_mfma(
    const unsigned short* __restrict__ qbf, const unsigned short* __restrict__ kbf,
    const unsigned short* __restrict__ vbf, unsigned short* __restrict__ attn) {
  const int bh = blockIdx.y;
  const int b = bh >> 4, h = bh & 15;
  const int tid = threadIdx.x, wv = tid >> 6, lane = tid & 63;
  const int fr = lane & 15, fg = lane >> 4;
  const int bl0 = blockIdx.x * 128;

  __shared__ __align__(16) char Kl[16384];    // [128p][64d] swz rows of 128B
  __shared__ __align__(16) char Vt[16384];    // 2 chunks of [64 dd][64 p]
  __shared__ __align__(16) char Pl[32768];    // 8 waves x [16 l][128 p]

  const size_t qrow = ((size_t)(bl0 + wv * 16 + fr) * BB + b) * DD + h * HDD;
  bf16x8 qf0 = *(const bf16x8*)(qbf + qrow + fg * 8);
  bf16x8 qf1 = *(const bf16x8*)(qbf + qrow + 32 + fg * 8);

  f32x4 o[4];
#pragma unroll
  for (int dt = 0; dt < 4; ++dt) o[dt] = (f32x4){0.f, 0.f, 0.f, 0.f};
  float psum = 0.f;
  char* Pw = Pl + wv * 4096;

  for (int ph = 0; ph < 2; ++ph) {
    __syncthreads();    // prev PV reads done; LDS safe to overwrite
#pragma unroll
    for (int j = 0; j < 2; ++j) {
      int u = tid + j * 512;
      int p = u >> 3, slot = u & 7;
      gll16(kbf + ((size_t)((ph * 128 + p) * BB + b)) * DD + h * HDD +
                8 * (slot ^ (p & 7)),
            Kl + u * 16);
    }
    {
      int p2 = tid >> 3, c8 = tid & 7;
      int p0 = ph * 128 + 2 * p2;
      const unsigned short* vp = vbf + ((size_t)(p0 * BB + b)) * DD + h * HDD + c8 * 8;
      bf16x8 v0 = *(const bf16x8*)vp;
      bf16x8 v1 = *(const bf16x8*)(vp + BB * DD);
      int pl = (2 * p2) & 63, pc = p2 >> 5;
      char* base = Vt + pc * 8192;
#pragma unroll
      for (int i = 0; i < 8; ++i) {
        int dd = c8 * 8 + i;
        unsigned int packed = (unsigned int)(unsigned short)v0[i] |
                              ((unsigned int)(unsigned short)v1[i] << 16);
        *(unsigned int*)(base + dd * 128 +
            ((((pl >> 3) ^ (dd & 7) ^ (dd >> 3)) & 7) << 4) + ((pl & 7) << 1)) = packed;
      }
    }
    __syncthreads();    // includes vmcnt(0)+lgkmcnt(0) drain

    f32x4 s[8];
    __builtin_amdgcn_s_setprio(1);
#pragma unroll
    for (int pt = 0; pt < 8; ++pt) {
      int pr = pt * 16 + fr;
      bf16x8 a0 = *(const bf16x8*)(Kl + pr * 128 + ((fg ^ (pr & 7)) << 4));
      bf16x8 a1 = *(const bf16x8*)(Kl + pr * 128 + (((4 + fg) ^ (pr & 7)) << 4));
      f32x4 acc = (f32x4){0.f, 0.f, 0.f, 0.f};
      acc = MFMA16(a0, qf0, acc);
      acc = MFMA16(a1, qf1, acc);
      s[pt] = acc;
    }
    __builtin_amdgcn_s_setprio(0);

#pragma unroll
    for (int pt = 0; pt < 8; ++pt) {
      float e0 = __expf(s[pt][0]), e1 = __expf(s[pt][1]);
      float e2 = __expf(s[pt][2]), e3 = __expf(s[pt][3]);
      psum += (e0 + e1) + (e2 + e3);
      short4v pk;
      pk[0] = (short)f2bf(e0); pk[1] = (short)f2bf(e1);
      pk[2] = (short)f2bf(e2); pk[3] = (short)f2bf(e3);
      int pbyte = (pt * 16 + fg * 4) * 2;
      int slot = pbyte >> 4, rem = pbyte & 15;
      *(short4v*)(Pw + fr * 256 + ((slot ^ (fr & 7)) << 4) + rem) = pk;
    }
    asm volatile("s_waitcnt lgkmcnt(0)" ::: "memory");
    __builtin_amdgcn_sched_barrier(0);

    __builtin_amdgcn_s_setprio(1);
#pragma unroll
    for (int kc = 0; kc < 4; ++kc) {
      int slot = kc * 4 + fg;
      bf16x8 pa = *(const bf16x8*)(Pw + fr * 256 + ((slot ^ (fr & 7)) << 4));
      int sl2 = (kc & 1) * 4 + fg;
#pragma unroll
      for (int dt = 0; dt < 4; ++dt) {
        int dd = dt * 16 + fr;
        bf16x8 vb = *(const bf16x8*)(Vt + (kc >> 1) * 8192 + dd * 128 +
                     (((sl2 ^ (dd & 7) ^ (dd >> 3)) & 7) << 4));
        o[dt] = MFMA16(pa, vb, o[dt]);
      }
    }
    __builtin_amdgcn_s_setprio(0);
  }

  psum += __shfl_xor(psum, 16);
  psum += __shfl_xor(psum, 32);

#pragma unroll
  for (int r = 0; r < 4; ++r) {
    int lloc = fg * 4 + r;
    float inv = 1.f / __shfl(psum, lloc);
    unsigned short* op = attn +
        ((size_t)(bl0 + wv * 16 + lloc) * BB + b) * DD + h * HDD;
#pragma unroll
    for (int dt = 0; dt < 4; ++dt)
      op[dt * 16 + fr] = f2bf(o[dt][r] * inv);
  }
}

extern "C" void kernel_launch(void* const* d_in, const int* in_sizes, int n_in,
                              void* d_out, int out_size, void* d_ws, size_t ws_size,
                              hipStream_t stream) {
  const float* query   = (const float*)d_in[0];
  const float* q_w     = (const float*)d_in[1];
  const float* q_b     = (const float*)d_in[2];
  const float* k_w     = (const float*)d_in[3];
  const float* k_b     = (const float*)d_in[4];
  const float* v_w     = (const float*)d_in[5];
  const float* v_b     = (const float*)d_in[6];
  const float* e_weight= (const float*)d_in[7];
  const float* e_out_w = (const float*)d_in[8];
  const float* e_out_b = (const float*)d_in[9];
  const float* ln_g    = (const float*)d_in[10];
  const float* ln_b    = (const float*)d_in[11];
  const float* out_w   = (const float*)d_in[12];
  const float* out_b   = (const float*)d_in[13];
  float* out = (float*)d_out;

  char* w = (char*)d_ws;
  unsigned short* parts   = (unsigned short*)w;                 // 32 MB, dead after reduce
  unsigned short* q_bf    = (unsigned short*)w;                 // 32 MB (alias, after reduce)
  unsigned short* attn_bf = (unsigned short*)(w + (32u << 20)); // 32 MB
  unsigned short* query_bf= (unsigned short*)(w + (64u << 20)); // 32 MB
  unsigned short* kv_raw  = (unsigned short*)(w + (96u << 20)); // 2 MB
  float* kv_eo            = (float*)(w + (98u << 20));          // 4 MB
  unsigned short* kv_ln   = (unsigned short*)(w + (102u << 20));// 2 MB
  unsigned short* k_buf   = (unsigned short*)(w + (104u << 20));// 2 MB
  unsigned short* v_buf   = (unsigned short*)(w + (106u << 20));// 2 MB
  unsigned short* wq  = (unsigned short*)(w + (108u << 20));
  unsigned short* wk  = (unsigned short*)(w + (110u << 20));
  unsigned short* wv_ = (unsigned short*)(w + (112u << 20));
  unsigned short* weo = (unsigned short*)(w + (114u << 20));
  unsigned short* wo  = (unsigned short*)(w + (116u << 20));
  unsigned short* ewb = (unsigned short*)(w + (118u << 20));    // 0.5 MB

  // weights-only cvt (query cvt fused into compress)
  k_cvt_w<<<2688, 256, 0, stream>>>(q_w, k_w, v_w, e_out_w, out_w, e_weight,
                                    wq, wk, wv_, weo, wo, ewb);

  k_compress_mfma<<<dim3(64, LC), 256, 0, stream>>>(query, ewb, query_bf, parts);
  k_reduce<<<512, 256, 0, stream>>>(parts, kv_raw);
  k_gemm_mfma<2, float><<<dim3(8, 8), 256, 0, stream>>>(kv_raw, weo, e_out_b, e_weight, kv_eo);
  k_ln<<<PP * BB, 256, 0, stream>>>(kv_eo, ln_g, ln_b, kv_ln);
  k_gemm256<1, unsigned short><<<dim3(64, 4), 512, 0, stream>>>(query_bf, wq, q_b, q_bf);
  k_gemm_kv<<<dim3(8, 8, 2), 256, 0, stream>>>(kv_ln, wk, wv_, k_b, v_b, k_buf, v_buf);
  k_attn_mfma<<<dim3(32, 64), 512, 0, stream>>>(q_bf, k_buf, v_buf, attn_bf);
  k_gemm256<0, float><<<dim3(64, 4), 512, 0, stream>>>(attn_bf, wo, out_b, out);
}